// Round 8
// baseline (684.115 us; speedup 1.0000x reference)
//
#include <hip/hip_runtime.h>
#include <hip/hip_fp16.h>
#include <math.h>

#ifndef M_PI
#define M_PI 3.14159265358979323846
#endif

// ---------------------------------------------------------------------------
// TensorNet interaction. fp32 math, fp16 LDS activations, MFMA fp16 GEMMs.
// Compressed irreducible rep per (n,f): u[9] =
//   { lam, a01, a02, a12, s00, s01, s02, s11, s12 }   (s22 = -s00-s11)
// Slab layout for node tensors: [9][N][F] (F contiguous).
//
// ws (~153 MB): A slab (U->T fp32), B slab (msg->U2->V), TgP (3 fp16 comp
// pairs), Tg456 (half4), Wf (fp16 MFMA frags), CSR ints.
//
// Round-8 changes:
//  * message gather BATCHED: 16 (8 for wave2) T-loads issued back-to-back
//    into registers before the accumulate pass -> 8-16x memory-level
//    parallelism (the loop was latency-bound at ~1 load in flight).
//  * wave2 reads comps {4,5,6} via one 8B uint2 (Tg456); waves 1/3 read a
//    single rf (their comp pairs share the rf component).
//  * k_scan: 32 elems/thread + single 1024-wide scan = 20 barriers vs ~500.
// ---------------------------------------------------------------------------

typedef _Float16 f16x8 __attribute__((ext_vector_type(8)));
typedef float f32x4 __attribute__((ext_vector_type(4)));

#define AROW 216        // halfs per activation row (432 B = 27*16)
#define MLPFRAGS 34816  // 68 frags * 512 halfs
#define WLFRAG 4096     // halfs per Wl matrix (8 frags * 512)

__device__ __forceinline__ float silu_f(float x) {
    return x / (1.0f + __expf(-x));
}

__device__ __forceinline__ void recon(const float u[9], float M[9]) {
    M[0] =  u[0] + u[4];
    M[1] =  u[1] + u[5];
    M[2] =  u[2] + u[6];
    M[3] = -u[1] + u[5];
    M[4] =  u[0] + u[7];
    M[5] =  u[3] + u[8];
    M[6] = -u[2] + u[6];
    M[7] = -u[3] + u[8];
    M[8] =  u[0] - u[4] - u[7];
}

// ---------------------------------------------------------------------------
// K1: per (n,f): Xn = X/(|X|^2+1), decompose -> U slabs [9][N][64]
// ---------------------------------------------------------------------------
__global__ __launch_bounds__(256) void k_node_prep(
    const float* __restrict__ X, float* __restrict__ U, int N)
{
    __shared__ float s_x[2304];
    int tid = threadIdx.x;
    size_t base = (size_t)blockIdx.x * 2304;
    size_t total = (size_t)N * 576;
    for (int idx = tid; idx < 2304; idx += 256) {
        size_t gi = base + idx;
        s_x[idx] = (gi < total) ? X[gi] : 0.f;
    }
    __syncthreads();
    int w = tid >> 6, f = tid & 63;
    int n = blockIdx.x * 4 + w;
    if (n >= N) return;
    float m[9]; float n2 = 0.f;
#pragma unroll
    for (int i = 0; i < 9; ++i) { m[i] = s_x[w * 576 + f * 9 + i]; n2 += m[i] * m[i]; }
    float inv = 1.0f / (n2 + 1.0f);
#pragma unroll
    for (int i = 0; i < 9; ++i) m[i] *= inv;
    float lam = (m[0] + m[4] + m[8]) * (1.f / 3.f);
    size_t slab = (size_t)N * 64;
    size_t t = (size_t)n * 64 + f;
    U[0 * slab + t] = lam;
    U[1 * slab + t] = 0.5f * (m[1] - m[3]);
    U[2 * slab + t] = 0.5f * (m[2] - m[6]);
    U[3 * slab + t] = 0.5f * (m[5] - m[7]);
    U[4 * slab + t] = m[0] - lam;
    U[5 * slab + t] = 0.5f * (m[1] + m[3]);
    U[6 * slab + t] = 0.5f * (m[2] + m[6]);
    U[7 * slab + t] = m[4] - lam;
    U[8 * slab + t] = 0.5f * (m[5] + m[7]);
}

// ---------------------------------------------------------------------------
// Weight -> fp16 MFMA-fragment conversion (once per launch).
// Fragment element (lane l, j) = W[ct*16+(l&15)][ks*32+(l>>4)*8+j].
// ---------------------------------------------------------------------------
__global__ __launch_bounds__(256) void k_wcvt(
    const float* __restrict__ W1, const float* __restrict__ W2,
    const float* __restrict__ W3,
    const float* __restrict__ Wl0, const float* __restrict__ Wl1,
    const float* __restrict__ Wl2, const float* __restrict__ Wl3,
    const float* __restrict__ Wl4, const float* __restrict__ Wl5,
    __half* __restrict__ Wf)
{
    int idx = blockIdx.x * 256 + threadIdx.x;
    if (idx >= MLPFRAGS + 6 * WLFRAG) return;
    float v;
    if (idx < MLPFRAGS) {
        int frag = idx >> 9;
        int r = idx & 511;
        int l = r >> 3, j = r & 7;
        int l15 = l & 15, lg = l >> 4;
        if (frag < 4) {
            int ct = frag;
            v = W1[(ct * 16 + l15) * 32 + (lg * 8 + j)];
        } else if (frag < 20) {
            int f2 = frag - 4;
            int ct = f2 >> 1, ks = f2 & 1;
            v = W2[(ct * 16 + l15) * 64 + (ks * 32 + lg * 8 + j)];
        } else {
            int f3 = frag - 20;
            int ct = f3 >> 2, ks = f3 & 3;
            v = W3[(ct * 16 + l15) * 128 + (ks * 32 + lg * 8 + j)];
        }
    } else {
        int r2 = idx - MLPFRAGS;
        int wIdx = r2 >> 12;           // /4096
        int rr = r2 & 4095;
        int f = rr >> 9;               // ct*2+ks
        int ct = f >> 1, ks = f & 1;
        int elem = rr & 511;
        int l = elem >> 3, j = elem & 7;
        int l15 = l & 15, lg = l >> 4;
        const float* W = (wIdx == 0) ? Wl0 : (wIdx == 1) ? Wl1 : (wIdx == 2) ? Wl2
                       : (wIdx == 3) ? Wl3 : (wIdx == 4) ? Wl4 : Wl5;
        v = W[(ct * 16 + l15) * 64 + (ks * 32 + lg * 8 + j)];
    }
    Wf[idx] = __float2half(v);
}

// ---------------------------------------------------------------------------
// Comp GEMM on MFMA (in-place safe). out[row][g] = sum_f in[row][f]*W[g][f],
// row = c*N+n; weight set selected by block-uniform comp group.
// Boundary blocks (cross weight-group) take the fp32 scalar path.
// ---------------------------------------------------------------------------
__global__ __launch_bounds__(256) void k_comp_gemm_m(
    const float* in, float* out, const __half* __restrict__ Wfrag,
    const float* __restrict__ Wa, const float* __restrict__ Wb,
    const float* __restrict__ Wc, int R, int N)
{
    __shared__ float s_f[64 * 68];
    __half* s_h = (__half*)s_f;           // staged fp16 [row][72]
    int tid = threadIdx.x;
    int r0 = blockIdx.x * 64;
    int cA = r0 / N;
    int rlast = min(r0 + 63, R - 1);
    int cB = rlast / N;
    int gA = (cA == 0) ? 0 : (cA < 4 ? 1 : 2);
    int gB = (cB == 0) ? 0 : (cB < 4 ? 1 : 2);

    if (gA == gB) {
        for (int idx = tid; idx < 1024; idx += 256) {
            int row = idx >> 4;
            int k4 = (idx & 15) << 2;
            int gr = r0 + row;
            float4 v = make_float4(0.f, 0.f, 0.f, 0.f);
            if (gr < R) v = *(const float4*)(in + (size_t)gr * 64 + k4);
            __half2* dst = (__half2*)&s_h[row * 72 + k4];
            dst[0] = __floats2half2_rn(v.x, v.y);
            dst[1] = __floats2half2_rn(v.z, v.w);
        }
        __syncthreads();
        int wv = tid >> 6, lane = tid & 63;
        int l15 = lane & 15, lg = lane >> 4;
        const f16x8* WF = (const f16x8*)(Wfrag + gA * WLFRAG);
        f16x8 a0 = *(const f16x8*)&s_h[(wv * 16 + l15) * 72 + lg * 8];
        f16x8 a1 = *(const f16x8*)&s_h[(wv * 16 + l15) * 72 + 32 + lg * 8];
        const f32x4 z = {0.f, 0.f, 0.f, 0.f};
        f32x4 acc[4];
#pragma unroll
        for (int ct = 0; ct < 4; ++ct) {
            acc[ct] = __builtin_amdgcn_mfma_f32_16x16x32_f16(a0, WF[(ct * 2 + 0) * 64 + lane], z, 0, 0, 0);
            acc[ct] = __builtin_amdgcn_mfma_f32_16x16x32_f16(a1, WF[(ct * 2 + 1) * 64 + lane], acc[ct], 0, 0, 0);
        }
        __syncthreads();
        // epilogue bounce: s_f[col][row] for coalesced float4 stores
#pragma unroll
        for (int ct = 0; ct < 4; ++ct)
#pragma unroll
            for (int r = 0; r < 4; ++r)
                s_f[(ct * 16 + l15) * 68 + wv * 16 + lg * 4 + r] = acc[ct][r];
        __syncthreads();
        for (int idx = tid; idx < 1024; idx += 256) {
            int row = idx >> 4;
            int c4 = (idx & 15) << 2;
            int gr = r0 + row;
            if (gr < R) {
                float4 o = make_float4(s_f[(c4 + 0) * 68 + row],
                                       s_f[(c4 + 1) * 68 + row],
                                       s_f[(c4 + 2) * 68 + row],
                                       s_f[(c4 + 3) * 68 + row]);
                *(float4*)(out + (size_t)gr * 64 + c4) = o;
            }
        }
    } else {
        // boundary path: fp32 scalar, stage [k][row] stride 68
        for (int idx = tid; idx < 1024; idx += 256) {
            int row = idx >> 4;
            int k4 = (idx & 15) << 2;
            int gr = r0 + row;
            float4 v = make_float4(0.f, 0.f, 0.f, 0.f);
            if (gr < R) v = *(const float4*)(in + (size_t)gr * 64 + k4);
            s_f[(k4 + 0) * 68 + row] = v.x;
            s_f[(k4 + 1) * 68 + row] = v.y;
            s_f[(k4 + 2) * 68 + row] = v.z;
            s_f[(k4 + 3) * 68 + row] = v.w;
        }
        __syncthreads();
        int et = tid >> 4, ct = tid & 15;
        int c0 = ct * 4;
        int rbase = r0 + et * 4;
        float4 acc[4];
#pragma unroll
        for (int cc = 0; cc < 4; ++cc) acc[cc] = make_float4(0.f, 0.f, 0.f, 0.f);
        const float* Wi[4];
#pragma unroll
        for (int i = 0; i < 4; ++i) {
            int r = min(rbase + i, R - 1);
            int c = r / N;
            int g = (c == 0) ? 0 : (c < 4 ? 1 : 2);
            Wi[i] = (g == 0) ? Wa : (g == 1 ? Wb : Wc);
        }
        for (int k = 0; k < 64; ++k) {
            float a0 = s_f[k * 68 + et * 4 + 0];
            float a1 = s_f[k * 68 + et * 4 + 1];
            float a2 = s_f[k * 68 + et * 4 + 2];
            float a3 = s_f[k * 68 + et * 4 + 3];
#pragma unroll
            for (int cc = 0; cc < 4; ++cc) {
                acc[cc].x += Wi[0][(c0 + cc) * 64 + k] * a0;
                acc[cc].y += Wi[1][(c0 + cc) * 64 + k] * a1;
                acc[cc].z += Wi[2][(c0 + cc) * 64 + k] * a2;
                acc[cc].w += Wi[3][(c0 + cc) * 64 + k] * a3;
            }
        }
        if (rbase + 0 < R) {
            float4 o = make_float4(acc[0].x, acc[1].x, acc[2].x, acc[3].x);
            *(float4*)(out + (size_t)(rbase + 0) * 64 + c0) = o;
        }
        if (rbase + 1 < R) {
            float4 o = make_float4(acc[0].y, acc[1].y, acc[2].y, acc[3].y);
            *(float4*)(out + (size_t)(rbase + 1) * 64 + c0) = o;
        }
        if (rbase + 2 < R) {
            float4 o = make_float4(acc[0].z, acc[1].z, acc[2].z, acc[3].z);
            *(float4*)(out + (size_t)(rbase + 2) * 64 + c0) = o;
        }
        if (rbase + 3 < R) {
            float4 o = make_float4(acc[0].w, acc[1].w, acc[2].w, acc[3].w);
            *(float4*)(out + (size_t)(rbase + 3) * 64 + c0) = o;
        }
    }
}

// ---------------------------------------------------------------------------
// T -> fp16 gather layouts: TgP[pr][n][f] = half2 pairs (0,1),(2,3),(7,8);
// Tg456[n][f] = half4 {T4, T5, T6, 0} as uint2.
// ---------------------------------------------------------------------------
__global__ __launch_bounds__(256) void k_tcvt(
    const float* __restrict__ T, __half2* __restrict__ TgP,
    uint2* __restrict__ Tg456, int N)
{
    int t = blockIdx.x * 256 + threadIdx.x;
    if (t >= N * 64) return;
    size_t slab = (size_t)N * 64;
    const int pa[3] = {0, 2, 7};
#pragma unroll
    for (int pr = 0; pr < 3; ++pr) {
        float va = T[(size_t)pa[pr] * slab + t];
        float vb = T[((size_t)pa[pr] + 1) * slab + t];
        TgP[(size_t)pr * slab + t] = __floats2half2_rn(va, vb);
    }
    __half2 lo = __floats2half2_rn(T[4 * slab + t], T[5 * slab + t]);
    __half2 hi = __floats2half2_rn(T[6 * slab + t], 0.f);
    uint2 pk;
    pk.x = *(unsigned int*)&lo;
    pk.y = *(unsigned int*)&hi;
    Tg456[t] = pk;
}

// ---------------------------------------------------------------------------
// CSR sort of edges by src: histogram -> scan -> ranked placement.
// ---------------------------------------------------------------------------
__global__ __launch_bounds__(256) void k_hist(
    const int* __restrict__ pair, int* __restrict__ count, int E)
{
    int e = blockIdx.x * 256 + threadIdx.x;
    if (e < E) atomicAdd(&count[pair[e]], 1);
}

// fast scan: 32 elems/thread serial + one 1024-wide Hillis-Steele pass
__global__ __launch_bounds__(1024) void k_scan(
    const int* __restrict__ count, int* __restrict__ off,
    int* __restrict__ cursor, int N, int E)
{
    __shared__ int s[1024];
    __shared__ int s_carry;
    int tid = threadIdx.x;
    if (tid == 0) s_carry = 0;
    __syncthreads();
    const int CH = 32;
    for (int base = 0; base < N; base += 1024 * CH) {
        int b0 = base + tid * CH;
        int local[CH]; int sum = 0;
#pragma unroll
        for (int i = 0; i < CH; ++i) {
            int idx = b0 + i;
            int v = (idx < N) ? count[idx] : 0;
            local[i] = sum; sum += v;
        }
        s[tid] = sum;
        __syncthreads();
        for (int d = 1; d < 1024; d <<= 1) {
            int t2 = (tid >= d) ? s[tid - d] : 0;
            __syncthreads();
            s[tid] += t2;
            __syncthreads();
        }
        int excl0 = s_carry + s[tid] - sum;
#pragma unroll
        for (int i = 0; i < CH; ++i) {
            int idx = b0 + i;
            if (idx < N) { int e = excl0 + local[i]; off[idx] = e; cursor[idx] = e; }
        }
        __syncthreads();
        if (tid == 1023) s_carry += s[1023];
        __syncthreads();
    }
    if (tid == 0) off[N] = E;
}

__global__ __launch_bounds__(256) void k_scatter_sort(
    const int* __restrict__ pair, int* __restrict__ cursor,
    int* __restrict__ eOf, int* __restrict__ dstp, int* __restrict__ srcp, int E)
{
    int e = blockIdx.x * 256 + threadIdx.x;
    if (e < E) {
        int s = pair[e];
        int d = pair[(size_t)E + e];
        int pos = atomicAdd(&cursor[s], 1);
        eOf[pos] = e;
        dstp[pos] = d;
        srcp[pos] = s;
    }
}

// ---------------------------------------------------------------------------
// K2: fused edge MLP on MFMA + batched run-accumulated message pass.
// 64 sorted positions/block, 4 waves. Message phase: wave -> comps
// {0,1}/{2,3}/{4,5,6}/{7,8}; T gathers batched 16 (8) deep into registers.
// ---------------------------------------------------------------------------
__global__ __launch_bounds__(256) void k_edge_sorted(
    const float* __restrict__ radial, const float* __restrict__ d_ij,
    const int* __restrict__ eOf, const int* __restrict__ dstp,
    const int* __restrict__ srcp,
    const __half* __restrict__ Wf,
    const float* __restrict__ b1, const float* __restrict__ b2,
    const float* __restrict__ b3,
    const __half2* __restrict__ TgP, const uint2* __restrict__ Tg456,
    float* __restrict__ msg, int E, int N)
{
    __shared__ __half s_act[64 * AROW];
    __shared__ float s_C[64];
    __shared__ int s_e[64];
    __shared__ int s_src[64];
    __shared__ int s_dst[64];
    int tid = threadIdx.x;
    int p0 = blockIdx.x * 64;

    if (tid < 64) {
        int p = p0 + tid;
        int e = -1, s = 0, d = 0; float C = 0.f;
        if (p < E) {
            e = eOf[p];
            s = srcp[p];
            d = dstp[p];
            float dd = d_ij[e];
            C = (dd < 5.0f) ? 0.5f * (cosf((float)M_PI * dd * 0.2f) + 1.0f) : 0.0f;
        }
        s_e[tid] = e; s_src[tid] = s; s_dst[tid] = d; s_C[tid] = C;
    }
    __syncthreads();

    {   // stage rbf: s_act[j][k], fp16
        int j = tid >> 2;
        int kk = (tid & 3) * 8;
        int e = s_e[j];
        float4 v0 = make_float4(0.f, 0.f, 0.f, 0.f), v1 = v0;
        if (e >= 0) {
            v0 = *(const float4*)(radial + (size_t)e * 32 + kk);
            v1 = *(const float4*)(radial + (size_t)e * 32 + kk + 4);
        }
        __half2* dst = (__half2*)&s_act[j * AROW + kk];
        dst[0] = __floats2half2_rn(v0.x, v0.y);
        dst[1] = __floats2half2_rn(v0.z, v0.w);
        dst[2] = __floats2half2_rn(v1.x, v1.y);
        dst[3] = __floats2half2_rn(v1.z, v1.w);
    }
    __syncthreads();

    int w = tid >> 6;
    int lane = tid & 63;
    int l15 = lane & 15, lg = lane >> 4;
    const int row0 = w * 16;
    const int arow = (row0 + l15) * AROW;
    const int orow = (row0 + lg * 4) * AROW;
    const f16x8* WF = (const f16x8*)Wf;
    const f32x4 zacc = {0.f, 0.f, 0.f, 0.f};

    // ---- layer 1: 32 -> 64
    {
        f16x8 a = *(const f16x8*)&s_act[arow + lg * 8];
        f32x4 acc[4];
#pragma unroll
        for (int ct = 0; ct < 4; ++ct)
            acc[ct] = __builtin_amdgcn_mfma_f32_16x16x32_f16(a, WF[ct * 64 + lane], zacc, 0, 0, 0);
        __syncthreads();
#pragma unroll
        for (int ct = 0; ct < 4; ++ct) {
            int o = ct * 16 + l15;
            float bias = b1[o];
#pragma unroll
            for (int r = 0; r < 4; ++r)
                s_act[orow + r * AROW + o] = __float2half(silu_f(acc[ct][r] + bias));
        }
        __syncthreads();
    }

    // ---- layer 2: 64 -> 128
    {
        f16x8 a0 = *(const f16x8*)&s_act[arow + 0 * 32 + lg * 8];
        f16x8 a1 = *(const f16x8*)&s_act[arow + 1 * 32 + lg * 8];
        f32x4 acc[8];
#pragma unroll
        for (int ct = 0; ct < 8; ++ct) {
            acc[ct] = __builtin_amdgcn_mfma_f32_16x16x32_f16(a0, WF[(4 + ct * 2 + 0) * 64 + lane], zacc, 0, 0, 0);
            acc[ct] = __builtin_amdgcn_mfma_f32_16x16x32_f16(a1, WF[(4 + ct * 2 + 1) * 64 + lane], acc[ct], 0, 0, 0);
        }
        __syncthreads();
#pragma unroll
        for (int ct = 0; ct < 8; ++ct) {
            int o = ct * 16 + l15;
            float bias = b2[o];
#pragma unroll
            for (int r = 0; r < 4; ++r)
                s_act[orow + r * AROW + o] = __float2half(silu_f(acc[ct][r] + bias));
        }
        __syncthreads();
    }

    // ---- layer 3: 128 -> 192 (raw col o -> stored col (o%3)*64 + o/3)
    {
        f16x8 a[4];
#pragma unroll
        for (int ks = 0; ks < 4; ++ks)
            a[ks] = *(const f16x8*)&s_act[arow + ks * 32 + lg * 8];
        float Cr[4];
#pragma unroll
        for (int r = 0; r < 4; ++r) Cr[r] = s_C[row0 + lg * 4 + r];
        __syncthreads();
#pragma unroll
        for (int ct = 0; ct < 12; ++ct) {
            f32x4 acc = zacc;
#pragma unroll
            for (int ks = 0; ks < 4; ++ks)
                acc = __builtin_amdgcn_mfma_f32_16x16x32_f16(a[ks], WF[(20 + ct * 4 + ks) * 64 + lane], acc, 0, 0, 0);
            int o = ct * 16 + l15;
            float bias = b3[o];
            int f = o / 3;
            int cmp = o - f * 3;
            int col = cmp * 64 + f;
#pragma unroll
            for (int r = 0; r < 4; ++r)
                s_act[orow + r * AROW + col] = __float2half(silu_f(acc[r] + bias) * Cr[r]);
        }
        __syncthreads();
    }

    // ---- message pass over sorted runs, batched T prefetch.
    {
        int wv = __builtin_amdgcn_readfirstlane(w);
        size_t slab = (size_t)N * 64;
        int jmax = min(64, E - p0);

        if (wv == 2) {
            // comps 4,5,6 from one uint2 (half4); rf2 at col 128+lane
            float a0 = 0.f, a1 = 0.f, a2 = 0.f;
            int cur = -1, jstart = 0;
            auto flushW = [&](int jend) {
                if (cur < 0) return;
                long ps = (long)p0 + jstart, pe = (long)p0 + jend;
                bool lb = (ps == 0) || (srcp[ps - 1] != cur);
                bool rb = (pe >= (long)E) || (srcp[pe] != cur);
                size_t b = (size_t)cur * 64 + lane;
                if (lb && rb) {
                    msg[4 * slab + b] = a0;
                    msg[5 * slab + b] = a1;
                    msg[6 * slab + b] = a2;
                } else {
                    atomicAdd(&msg[4 * slab + b], a0);
                    atomicAdd(&msg[5 * slab + b], a1);
                    atomicAdd(&msg[6 * slab + b], a2);
                }
                a0 = a1 = a2 = 0.f;
            };
            for (int jb = 0; jb < jmax; jb += 8) {
                int nb = min(8, jmax - jb);
                uint2 tvr[8];
#pragma unroll
                for (int t = 0; t < 8; ++t)
                    if (t < nb) tvr[t] = Tg456[(size_t)s_dst[jb + t] * 64 + lane];
                for (int t = 0; t < nb; ++t) {
                    int j = jb + t;
                    int s = s_src[j];
                    if (s != cur) { flushW(j); cur = s; jstart = j; }
                    float rf = __half2float(s_act[j * AROW + 128 + lane]);
                    __half2 lo = *(__half2*)&tvr[t].x;
                    __half2 hi = *(__half2*)&tvr[t].y;
                    float2 lof = __half22float2(lo);
                    a0 += rf * lof.x;
                    a1 += rf * lof.y;
                    a2 += rf * __half2float(hi.x);
                }
            }
            flushW(jmax);
        } else {
            int pr = (wv == 3) ? 2 : wv;
            int c0 = (wv == 0) ? 0 : ((wv == 1) ? 2 : 7);
            int c1 = c0 + 1;
            // rf columns: wave0 reads rf0(col0)+rf1(col64); wave1 rf1 only;
            // wave3 rf2 only (comp pairs share the rf component).
            int offA = (wv == 0) ? lane : ((wv == 1) ? (64 + lane) : (128 + lane));
            int offB = 64 + lane;   // only used by wave0
            const unsigned int* TP = (const unsigned int*)TgP + (size_t)pr * slab;
            float a0 = 0.f, a1 = 0.f;
            int cur = -1, jstart = 0;
            auto flushW = [&](int jend) {
                if (cur < 0) return;
                long ps = (long)p0 + jstart, pe = (long)p0 + jend;
                bool lb = (ps == 0) || (srcp[ps - 1] != cur);
                bool rb = (pe >= (long)E) || (srcp[pe] != cur);
                size_t b = (size_t)cur * 64 + lane;
                if (lb && rb) {
                    msg[(size_t)c0 * slab + b] = a0;
                    msg[(size_t)c1 * slab + b] = a1;
                } else {
                    atomicAdd(&msg[(size_t)c0 * slab + b], a0);
                    atomicAdd(&msg[(size_t)c1 * slab + b], a1);
                }
                a0 = a1 = 0.f;
            };
            for (int jb = 0; jb < jmax; jb += 16) {
                int nb = min(16, jmax - jb);
                unsigned int tvr[16];
#pragma unroll
                for (int t = 0; t < 16; ++t)
                    if (t < nb) tvr[t] = TP[(size_t)s_dst[jb + t] * 64 + lane];
                for (int t = 0; t < nb; ++t) {
                    int j = jb + t;
                    int s = s_src[j];
                    if (s != cur) { flushW(j); cur = s; jstart = j; }
                    __half2 tv = *(__half2*)&tvr[t];
                    float2 tvf = __half22float2(tv);
                    float rfA = __half2float(s_act[j * AROW + offA]);
                    float rfB = (wv == 0) ? __half2float(s_act[j * AROW + offB]) : rfA;
                    a0 += rfA * tvf.x;
                    a1 += rfB * tvf.y;
                }
            }
            flushW(jmax);
        }
    }
}

// ---------------------------------------------------------------------------
// K4a (in-place safe): M=recon(msg), Y=recon(T), P=scale*(MY+YM),
// decompose+normalize -> U2
// ---------------------------------------------------------------------------
__global__ __launch_bounds__(256) void k_node_mix(
    const float* msg, const float* __restrict__ T,
    const float* __restrict__ charges, float* U2, int N)
{
    int t = blockIdx.x * 256 + threadIdx.x;
    if (t >= N * 64) return;
    int n = t >> 6;
    size_t slab = (size_t)N * 64;
    float um[9], uy[9];
#pragma unroll
    for (int c = 0; c < 9; ++c) { um[c] = msg[c * slab + t]; uy[c] = T[c * slab + t]; }
    float M[9], Y[9];
    recon(um, M);
    recon(uy, Y);
    float P[9];
#pragma unroll
    for (int i = 0; i < 3; ++i)
#pragma unroll
        for (int j = 0; j < 3; ++j) {
            float s = 0.f;
#pragma unroll
            for (int k = 0; k < 3; ++k)
                s += M[i * 3 + k] * Y[k * 3 + j] + Y[i * 3 + k] * M[k * 3 + j];
            P[i * 3 + j] = s;
        }
    float sc = 1.0f + 0.1f * charges[n];
    float nrm = 0.f;
#pragma unroll
    for (int i = 0; i < 9; ++i) { P[i] *= sc; nrm += P[i] * P[i]; }
    float inv = 1.0f / (nrm + 1.0f);
    float lam = (P[0] + P[4] + P[8]) * (1.f / 3.f);
    U2[0 * slab + t] = lam * inv;
    U2[1 * slab + t] = 0.5f * (P[1] - P[3]) * inv;
    U2[2 * slab + t] = 0.5f * (P[2] - P[6]) * inv;
    U2[3 * slab + t] = 0.5f * (P[5] - P[7]) * inv;
    U2[4 * slab + t] = (P[0] - lam) * inv;
    U2[5 * slab + t] = 0.5f * (P[1] + P[3]) * inv;
    U2[6 * slab + t] = 0.5f * (P[2] + P[6]) * inv;
    U2[7 * slab + t] = (P[4] - lam) * inv;
    U2[8 * slab + t] = 0.5f * (P[5] + P[7]) * inv;
}

// ---------------------------------------------------------------------------
// Output: out = Xn + dX + scale * dX@dX   (Xn recomputed; dX = recon(V))
// ---------------------------------------------------------------------------
__global__ __launch_bounds__(256) void k_out(
    const float* __restrict__ V, const float* __restrict__ X,
    const float* __restrict__ charges, float* __restrict__ out, int N)
{
    __shared__ float s_x[2304];
    __shared__ float s_o[2304];
    int tid = threadIdx.x;
    int blk = blockIdx.x;
    size_t base = (size_t)blk * 2304;
    size_t total = (size_t)N * 576;
    for (int idx = tid; idx < 2304; idx += 256) {
        size_t gi = base + idx;
        s_x[idx] = (gi < total) ? X[gi] : 0.f;
    }
    __syncthreads();
    int t = blk * 256 + tid;
    if (t < N * 64) {
        int n = t >> 6;
        int w = tid >> 6, f = tid & 63;
        size_t slab = (size_t)N * 64;
        float m[9]; float n2 = 0.f;
#pragma unroll
        for (int i = 0; i < 9; ++i) { m[i] = s_x[w * 576 + f * 9 + i]; n2 += m[i] * m[i]; }
        float invn = 1.0f / (n2 + 1.0f);
#pragma unroll
        for (int i = 0; i < 9; ++i) m[i] *= invn;
        float uv[9];
#pragma unroll
        for (int c = 0; c < 9; ++c) uv[c] = V[c * slab + t];
        float dX[9];
        recon(uv, dX);
        float sc = 1.0f + 0.1f * charges[n];
#pragma unroll
        for (int i = 0; i < 3; ++i)
#pragma unroll
            for (int j = 0; j < 3; ++j) {
                float s = 0.f;
#pragma unroll
                for (int k = 0; k < 3; ++k) s += dX[i * 3 + k] * dX[k * 3 + j];
                s_o[w * 576 + f * 9 + i * 3 + j] = m[i * 3 + j] + dX[i * 3 + j] + sc * s;
            }
    }
    __syncthreads();
    for (int idx = tid; idx < 2304; idx += 256) {
        size_t gi = base + idx;
        if (gi < total) out[gi] = s_o[idx];
    }
}

// ---------------------------------------------------------------------------
extern "C" void kernel_launch(void* const* d_in, const int* in_sizes, int n_in,
                              void* d_out, int out_size, void* d_ws, size_t ws_size,
                              hipStream_t stream)
{
    const float* X       = (const float*)d_in[0];
    const int*   pair    = (const int*)d_in[1];
    const float* dij     = (const float*)d_in[2];
    const float* radial  = (const float*)d_in[3];
    const float* charges = (const float*)d_in[4];
    const float* W1  = (const float*)d_in[5];
    const float* b1  = (const float*)d_in[6];
    const float* W2  = (const float*)d_in[7];
    const float* b2  = (const float*)d_in[8];
    const float* W3  = (const float*)d_in[9];
    const float* b3  = (const float*)d_in[10];
    const float* Wl0 = (const float*)d_in[11];
    const float* Wl1 = (const float*)d_in[12];
    const float* Wl2 = (const float*)d_in[13];
    const float* Wl3 = (const float*)d_in[14];
    const float* Wl4 = (const float*)d_in[15];
    const float* Wl5 = (const float*)d_in[16];

    int N = in_sizes[4];
    int E = in_sizes[2];
    int R = 9 * N;
    int nb_gemm = (R + 63) / 64;
    int nb_node4 = (N + 3) / 4;
    int nb_edge = (E + 63) / 64;
    size_t slab = (size_t)N * 64;
    size_t slab9 = slab * 9;

    float* A = (float*)d_ws;               // U -> T (in-place GEMM)
    float* B = A + slab9;                  // msg -> U2 -> V (in-place chain)
    __half2* TgP = (__half2*)(B + slab9);  // 3*slab half2
    uint2* Tg456 = (uint2*)(TgP + 3 * slab);
    __half* Wf  = (__half*)(Tg456 + slab);
    int* ints   = (int*)(Wf + MLPFRAGS + 6 * WLFRAG);
    int* count  = ints;
    int* off    = count + N;
    int* cursor = off + N + 1;
    int* eOf    = cursor + N;
    int* dstp   = eOf + E;
    int* srcp   = dstp + E;

    hipMemsetAsync(count, 0, (size_t)N * sizeof(int), stream);
    hipMemsetAsync(B, 0, slab9 * sizeof(float), stream);

    int nWf = MLPFRAGS + 6 * WLFRAG;
    k_wcvt<<<(nWf + 255) / 256, 256, 0, stream>>>(W1, W2, W3,
                                                  Wl0, Wl1, Wl2, Wl3, Wl4, Wl5, Wf);
    k_node_prep<<<nb_node4, 256, 0, stream>>>(X, A, N);
    k_comp_gemm_m<<<nb_gemm, 256, 0, stream>>>(A, A, Wf + MLPFRAGS,
                                               Wl0, Wl1, Wl2, R, N);
    k_tcvt<<<(N * 64 + 255) / 256, 256, 0, stream>>>(A, TgP, Tg456, N);

    k_hist<<<(E + 255) / 256, 256, 0, stream>>>(pair, count, E);
    k_scan<<<1, 1024, 0, stream>>>(count, off, cursor, N, E);
    k_scatter_sort<<<(E + 255) / 256, 256, 0, stream>>>(pair, cursor, eOf, dstp, srcp, E);

    k_edge_sorted<<<nb_edge, 256, 0, stream>>>(radial, dij, eOf, dstp, srcp,
                                               Wf, b1, b2, b3, TgP, Tg456, B, E, N);

    k_node_mix<<<(N * 64 + 255) / 256, 256, 0, stream>>>(B, A, charges, B, N);
    k_comp_gemm_m<<<nb_gemm, 256, 0, stream>>>(B, B, Wf + MLPFRAGS + 3 * WLFRAG,
                                               Wl3, Wl4, Wl5, R, N);
    k_out<<<(N * 64 + 255) / 256, 256, 0, stream>>>(B, X, charges, (float*)d_out, N);
}

// Round 9
// 470.525 us; speedup vs baseline: 1.4539x; 1.4539x over previous
//
#include <hip/hip_runtime.h>
#include <hip/hip_fp16.h>
#include <math.h>

#ifndef M_PI
#define M_PI 3.14159265358979323846
#endif

// ---------------------------------------------------------------------------
// TensorNet interaction. fp32 math, fp16 LDS activations, MFMA fp16 GEMMs.
// Compressed irreducible rep per (n,f): u[9] =
//   { lam, a01, a02, a12, s00, s01, s02, s11, s12 }   (s22 = -s00-s11)
// Slab layout for node tensors: [9][N][F] (F contiguous).
//
// ws (~149 MB): A slab (U->T fp32), B slab (msg), Tg (4 fp16 comp pairs),
// Tg6, Wf (fp16 MFMA frags), CSR ints.
//
// Round-9 changes:
//  * message gather: 4 independent per-wave streams (named scalars, no
//    arrays -> no scratch spill) -> 4-8 loads in flight per wave.
//  * k_tail fuses node_mix + comp-GEMM#2 + out into one kernel (U2/V fp16
//    staged in LDS, MFMA GEMM): 460 -> 230 MB traffic, -2 launches.
// ---------------------------------------------------------------------------

typedef _Float16 f16x8 __attribute__((ext_vector_type(8)));
typedef float f32x4 __attribute__((ext_vector_type(4)));

#define AROW 216        // halfs per activation row (432 B = 27*16)
#define MLPFRAGS 34816  // 68 frags * 512 halfs
#define WLFRAG 4096     // halfs per Wl matrix (8 frags * 512)

__device__ __forceinline__ float silu_f(float x) {
    return x / (1.0f + __expf(-x));
}

__device__ __forceinline__ void recon(const float u[9], float M[9]) {
    M[0] =  u[0] + u[4];
    M[1] =  u[1] + u[5];
    M[2] =  u[2] + u[6];
    M[3] = -u[1] + u[5];
    M[4] =  u[0] + u[7];
    M[5] =  u[3] + u[8];
    M[6] = -u[2] + u[6];
    M[7] = -u[3] + u[8];
    M[8] =  u[0] - u[4] - u[7];
}

// ---------------------------------------------------------------------------
// K1: per (n,f): Xn = X/(|X|^2+1), decompose -> U slabs [9][N][64]
// ---------------------------------------------------------------------------
__global__ __launch_bounds__(256) void k_node_prep(
    const float* __restrict__ X, float* __restrict__ U, int N)
{
    __shared__ float s_x[2304];
    int tid = threadIdx.x;
    size_t base = (size_t)blockIdx.x * 2304;
    size_t total = (size_t)N * 576;
    for (int idx = tid; idx < 2304; idx += 256) {
        size_t gi = base + idx;
        s_x[idx] = (gi < total) ? X[gi] : 0.f;
    }
    __syncthreads();
    int w = tid >> 6, f = tid & 63;
    int n = blockIdx.x * 4 + w;
    if (n >= N) return;
    float m[9]; float n2 = 0.f;
#pragma unroll
    for (int i = 0; i < 9; ++i) { m[i] = s_x[w * 576 + f * 9 + i]; n2 += m[i] * m[i]; }
    float inv = 1.0f / (n2 + 1.0f);
#pragma unroll
    for (int i = 0; i < 9; ++i) m[i] *= inv;
    float lam = (m[0] + m[4] + m[8]) * (1.f / 3.f);
    size_t slab = (size_t)N * 64;
    size_t t = (size_t)n * 64 + f;
    U[0 * slab + t] = lam;
    U[1 * slab + t] = 0.5f * (m[1] - m[3]);
    U[2 * slab + t] = 0.5f * (m[2] - m[6]);
    U[3 * slab + t] = 0.5f * (m[5] - m[7]);
    U[4 * slab + t] = m[0] - lam;
    U[5 * slab + t] = 0.5f * (m[1] + m[3]);
    U[6 * slab + t] = 0.5f * (m[2] + m[6]);
    U[7 * slab + t] = m[4] - lam;
    U[8 * slab + t] = 0.5f * (m[5] + m[7]);
}

// ---------------------------------------------------------------------------
// Weight -> fp16 MFMA-fragment conversion (once per launch).
// Fragment element (lane l, j) = W[ct*16+(l&15)][ks*32+(l>>4)*8+j].
// ---------------------------------------------------------------------------
__global__ __launch_bounds__(256) void k_wcvt(
    const float* __restrict__ W1, const float* __restrict__ W2,
    const float* __restrict__ W3,
    const float* __restrict__ Wl0, const float* __restrict__ Wl1,
    const float* __restrict__ Wl2, const float* __restrict__ Wl3,
    const float* __restrict__ Wl4, const float* __restrict__ Wl5,
    __half* __restrict__ Wf)
{
    int idx = blockIdx.x * 256 + threadIdx.x;
    if (idx >= MLPFRAGS + 6 * WLFRAG) return;
    float v;
    if (idx < MLPFRAGS) {
        int frag = idx >> 9;
        int r = idx & 511;
        int l = r >> 3, j = r & 7;
        int l15 = l & 15, lg = l >> 4;
        if (frag < 4) {
            int ct = frag;
            v = W1[(ct * 16 + l15) * 32 + (lg * 8 + j)];
        } else if (frag < 20) {
            int f2 = frag - 4;
            int ct = f2 >> 1, ks = f2 & 1;
            v = W2[(ct * 16 + l15) * 64 + (ks * 32 + lg * 8 + j)];
        } else {
            int f3 = frag - 20;
            int ct = f3 >> 2, ks = f3 & 3;
            v = W3[(ct * 16 + l15) * 128 + (ks * 32 + lg * 8 + j)];
        }
    } else {
        int r2 = idx - MLPFRAGS;
        int wIdx = r2 >> 12;           // /4096
        int rr = r2 & 4095;
        int f = rr >> 9;               // ct*2+ks
        int ct = f >> 1, ks = f & 1;
        int elem = rr & 511;
        int l = elem >> 3, j = elem & 7;
        int l15 = l & 15, lg = l >> 4;
        const float* W = (wIdx == 0) ? Wl0 : (wIdx == 1) ? Wl1 : (wIdx == 2) ? Wl2
                       : (wIdx == 3) ? Wl3 : (wIdx == 4) ? Wl4 : Wl5;
        v = W[(ct * 16 + l15) * 64 + (ks * 32 + lg * 8 + j)];
    }
    Wf[idx] = __float2half(v);
}

// ---------------------------------------------------------------------------
// Comp GEMM #1 on MFMA (in-place safe). out[row][g] = sum_f in[row][f]*W[g][f]
// ---------------------------------------------------------------------------
__global__ __launch_bounds__(256) void k_comp_gemm_m(
    const float* in, float* out, const __half* __restrict__ Wfrag,
    const float* __restrict__ Wa, const float* __restrict__ Wb,
    const float* __restrict__ Wc, int R, int N)
{
    __shared__ float s_f[64 * 68];
    __half* s_h = (__half*)s_f;           // staged fp16 [row][72]
    int tid = threadIdx.x;
    int r0 = blockIdx.x * 64;
    int cA = r0 / N;
    int rlast = min(r0 + 63, R - 1);
    int cB = rlast / N;
    int gA = (cA == 0) ? 0 : (cA < 4 ? 1 : 2);
    int gB = (cB == 0) ? 0 : (cB < 4 ? 1 : 2);

    if (gA == gB) {
        for (int idx = tid; idx < 1024; idx += 256) {
            int row = idx >> 4;
            int k4 = (idx & 15) << 2;
            int gr = r0 + row;
            float4 v = make_float4(0.f, 0.f, 0.f, 0.f);
            if (gr < R) v = *(const float4*)(in + (size_t)gr * 64 + k4);
            __half2* dst = (__half2*)&s_h[row * 72 + k4];
            dst[0] = __floats2half2_rn(v.x, v.y);
            dst[1] = __floats2half2_rn(v.z, v.w);
        }
        __syncthreads();
        int wv = tid >> 6, lane = tid & 63;
        int l15 = lane & 15, lg = lane >> 4;
        const f16x8* WF = (const f16x8*)(Wfrag + gA * WLFRAG);
        f16x8 a0 = *(const f16x8*)&s_h[(wv * 16 + l15) * 72 + lg * 8];
        f16x8 a1 = *(const f16x8*)&s_h[(wv * 16 + l15) * 72 + 32 + lg * 8];
        const f32x4 z = {0.f, 0.f, 0.f, 0.f};
        f32x4 acc[4];
#pragma unroll
        for (int ct = 0; ct < 4; ++ct) {
            acc[ct] = __builtin_amdgcn_mfma_f32_16x16x32_f16(a0, WF[(ct * 2 + 0) * 64 + lane], z, 0, 0, 0);
            acc[ct] = __builtin_amdgcn_mfma_f32_16x16x32_f16(a1, WF[(ct * 2 + 1) * 64 + lane], acc[ct], 0, 0, 0);
        }
        __syncthreads();
#pragma unroll
        for (int ct = 0; ct < 4; ++ct)
#pragma unroll
            for (int r = 0; r < 4; ++r)
                s_f[(ct * 16 + l15) * 68 + wv * 16 + lg * 4 + r] = acc[ct][r];
        __syncthreads();
        for (int idx = tid; idx < 1024; idx += 256) {
            int row = idx >> 4;
            int c4 = (idx & 15) << 2;
            int gr = r0 + row;
            if (gr < R) {
                float4 o = make_float4(s_f[(c4 + 0) * 68 + row],
                                       s_f[(c4 + 1) * 68 + row],
                                       s_f[(c4 + 2) * 68 + row],
                                       s_f[(c4 + 3) * 68 + row]);
                *(float4*)(out + (size_t)gr * 64 + c4) = o;
            }
        }
    } else {
        for (int idx = tid; idx < 1024; idx += 256) {
            int row = idx >> 4;
            int k4 = (idx & 15) << 2;
            int gr = r0 + row;
            float4 v = make_float4(0.f, 0.f, 0.f, 0.f);
            if (gr < R) v = *(const float4*)(in + (size_t)gr * 64 + k4);
            s_f[(k4 + 0) * 68 + row] = v.x;
            s_f[(k4 + 1) * 68 + row] = v.y;
            s_f[(k4 + 2) * 68 + row] = v.z;
            s_f[(k4 + 3) * 68 + row] = v.w;
        }
        __syncthreads();
        int et = tid >> 4, ct = tid & 15;
        int c0 = ct * 4;
        int rbase = r0 + et * 4;
        float4 acc[4];
#pragma unroll
        for (int cc = 0; cc < 4; ++cc) acc[cc] = make_float4(0.f, 0.f, 0.f, 0.f);
        const float* Wi[4];
#pragma unroll
        for (int i = 0; i < 4; ++i) {
            int r = min(rbase + i, R - 1);
            int c = r / N;
            int g = (c == 0) ? 0 : (c < 4 ? 1 : 2);
            Wi[i] = (g == 0) ? Wa : (g == 1 ? Wb : Wc);
        }
        for (int k = 0; k < 64; ++k) {
            float a0 = s_f[k * 68 + et * 4 + 0];
            float a1 = s_f[k * 68 + et * 4 + 1];
            float a2 = s_f[k * 68 + et * 4 + 2];
            float a3 = s_f[k * 68 + et * 4 + 3];
#pragma unroll
            for (int cc = 0; cc < 4; ++cc) {
                acc[cc].x += Wi[0][(c0 + cc) * 64 + k] * a0;
                acc[cc].y += Wi[1][(c0 + cc) * 64 + k] * a1;
                acc[cc].z += Wi[2][(c0 + cc) * 64 + k] * a2;
                acc[cc].w += Wi[3][(c0 + cc) * 64 + k] * a3;
            }
        }
        if (rbase + 0 < R) {
            float4 o = make_float4(acc[0].x, acc[1].x, acc[2].x, acc[3].x);
            *(float4*)(out + (size_t)(rbase + 0) * 64 + c0) = o;
        }
        if (rbase + 1 < R) {
            float4 o = make_float4(acc[0].y, acc[1].y, acc[2].y, acc[3].y);
            *(float4*)(out + (size_t)(rbase + 1) * 64 + c0) = o;
        }
        if (rbase + 2 < R) {
            float4 o = make_float4(acc[0].z, acc[1].z, acc[2].z, acc[3].z);
            *(float4*)(out + (size_t)(rbase + 2) * 64 + c0) = o;
        }
        if (rbase + 3 < R) {
            float4 o = make_float4(acc[0].w, acc[1].w, acc[2].w, acc[3].w);
            *(float4*)(out + (size_t)(rbase + 3) * 64 + c0) = o;
        }
    }
}

// ---------------------------------------------------------------------------
// T -> fp16 gather layout (round-7): Tg[pr][n][f] = half2 pairs
// (0,1),(2,3),(4,5),(7,8); Tg6[n][f] = half.
// ---------------------------------------------------------------------------
__global__ __launch_bounds__(256) void k_tcvt(
    const float* __restrict__ T, __half2* __restrict__ Tg,
    __half* __restrict__ Tg6, int N)
{
    int t = blockIdx.x * 256 + threadIdx.x;
    if (t >= N * 64) return;
    size_t slab = (size_t)N * 64;
    const int pa[4] = {0, 2, 4, 7};
#pragma unroll
    for (int pr = 0; pr < 4; ++pr) {
        float va = T[(size_t)pa[pr] * slab + t];
        float vb = T[((size_t)pa[pr] + 1) * slab + t];
        Tg[(size_t)pr * slab + t] = __floats2half2_rn(va, vb);
    }
    Tg6[t] = __float2half(T[6 * slab + t]);
}

// ---------------------------------------------------------------------------
// CSR sort of edges by src: histogram -> scan -> ranked placement.
// ---------------------------------------------------------------------------
__global__ __launch_bounds__(256) void k_hist(
    const int* __restrict__ pair, int* __restrict__ count, int E)
{
    int e = blockIdx.x * 256 + threadIdx.x;
    if (e < E) atomicAdd(&count[pair[e]], 1);
}

__global__ __launch_bounds__(1024) void k_scan(
    const int* __restrict__ count, int* __restrict__ off,
    int* __restrict__ cursor, int N, int E)
{
    __shared__ int s[1024];
    __shared__ int s_carry;
    int tid = threadIdx.x;
    if (tid == 0) s_carry = 0;
    __syncthreads();
    const int CH = 32;
    for (int base = 0; base < N; base += 1024 * CH) {
        int b0 = base + tid * CH;
        int local[CH]; int sum = 0;
#pragma unroll
        for (int i = 0; i < CH; ++i) {
            int idx = b0 + i;
            int v = (idx < N) ? count[idx] : 0;
            local[i] = sum; sum += v;
        }
        s[tid] = sum;
        __syncthreads();
        for (int d = 1; d < 1024; d <<= 1) {
            int t2 = (tid >= d) ? s[tid - d] : 0;
            __syncthreads();
            s[tid] += t2;
            __syncthreads();
        }
        int excl0 = s_carry + s[tid] - sum;
#pragma unroll
        for (int i = 0; i < CH; ++i) {
            int idx = b0 + i;
            if (idx < N) { int e = excl0 + local[i]; off[idx] = e; cursor[idx] = e; }
        }
        __syncthreads();
        if (tid == 1023) s_carry += s[1023];
        __syncthreads();
    }
    if (tid == 0) off[N] = E;
}

__global__ __launch_bounds__(256) void k_scatter_sort(
    const int* __restrict__ pair, int* __restrict__ cursor,
    int* __restrict__ eOf, int* __restrict__ dstp, int* __restrict__ srcp, int E)
{
    int e = blockIdx.x * 256 + threadIdx.x;
    if (e < E) {
        int s = pair[e];
        int d = pair[(size_t)E + e];
        int pos = atomicAdd(&cursor[s], 1);
        eOf[pos] = e;
        dstp[pos] = d;
        srcp[pos] = s;
    }
}

// ---------------------------------------------------------------------------
// K2: fused edge MLP on MFMA + 4-stream run-accumulated message pass.
// ---------------------------------------------------------------------------
__global__ __launch_bounds__(256) void k_edge_sorted(
    const float* __restrict__ radial, const float* __restrict__ d_ij,
    const int* __restrict__ eOf, const int* __restrict__ dstp,
    const int* __restrict__ srcp,
    const __half* __restrict__ Wf,
    const float* __restrict__ b1, const float* __restrict__ b2,
    const float* __restrict__ b3,
    const __half2* __restrict__ Tg, const __half* __restrict__ Tg6,
    float* __restrict__ msg, int E, int N)
{
    __shared__ __half s_act[64 * AROW];
    __shared__ float s_C[64];
    __shared__ int s_e[64];
    __shared__ int s_src[64];
    __shared__ int s_dst[64];
    int tid = threadIdx.x;
    int p0 = blockIdx.x * 64;

    if (tid < 64) {
        int p = p0 + tid;
        int e = -1, s = 0, d = 0; float C = 0.f;
        if (p < E) {
            e = eOf[p];
            s = srcp[p];
            d = dstp[p];
            float dd = d_ij[e];
            C = (dd < 5.0f) ? 0.5f * (cosf((float)M_PI * dd * 0.2f) + 1.0f) : 0.0f;
        }
        s_e[tid] = e; s_src[tid] = s; s_dst[tid] = d; s_C[tid] = C;
    }
    __syncthreads();

    {   // stage rbf: s_act[j][k], fp16
        int j = tid >> 2;
        int kk = (tid & 3) * 8;
        int e = s_e[j];
        float4 v0 = make_float4(0.f, 0.f, 0.f, 0.f), v1 = v0;
        if (e >= 0) {
            v0 = *(const float4*)(radial + (size_t)e * 32 + kk);
            v1 = *(const float4*)(radial + (size_t)e * 32 + kk + 4);
        }
        __half2* dst = (__half2*)&s_act[j * AROW + kk];
        dst[0] = __floats2half2_rn(v0.x, v0.y);
        dst[1] = __floats2half2_rn(v0.z, v0.w);
        dst[2] = __floats2half2_rn(v1.x, v1.y);
        dst[3] = __floats2half2_rn(v1.z, v1.w);
    }
    __syncthreads();

    int w = tid >> 6;
    int lane = tid & 63;
    int l15 = lane & 15, lg = lane >> 4;
    const int row0 = w * 16;
    const int arow = (row0 + l15) * AROW;
    const int orow = (row0 + lg * 4) * AROW;
    const f16x8* WF = (const f16x8*)Wf;
    const f32x4 zacc = {0.f, 0.f, 0.f, 0.f};

    // ---- layer 1: 32 -> 64
    {
        f16x8 a = *(const f16x8*)&s_act[arow + lg * 8];
        f32x4 acc[4];
#pragma unroll
        for (int ct = 0; ct < 4; ++ct)
            acc[ct] = __builtin_amdgcn_mfma_f32_16x16x32_f16(a, WF[ct * 64 + lane], zacc, 0, 0, 0);
        __syncthreads();
#pragma unroll
        for (int ct = 0; ct < 4; ++ct) {
            int o = ct * 16 + l15;
            float bias = b1[o];
#pragma unroll
            for (int r = 0; r < 4; ++r)
                s_act[orow + r * AROW + o] = __float2half(silu_f(acc[ct][r] + bias));
        }
        __syncthreads();
    }

    // ---- layer 2: 64 -> 128
    {
        f16x8 a0 = *(const f16x8*)&s_act[arow + 0 * 32 + lg * 8];
        f16x8 a1 = *(const f16x8*)&s_act[arow + 1 * 32 + lg * 8];
        f32x4 acc[8];
#pragma unroll
        for (int ct = 0; ct < 8; ++ct) {
            acc[ct] = __builtin_amdgcn_mfma_f32_16x16x32_f16(a0, WF[(4 + ct * 2 + 0) * 64 + lane], zacc, 0, 0, 0);
            acc[ct] = __builtin_amdgcn_mfma_f32_16x16x32_f16(a1, WF[(4 + ct * 2 + 1) * 64 + lane], acc[ct], 0, 0, 0);
        }
        __syncthreads();
#pragma unroll
        for (int ct = 0; ct < 8; ++ct) {
            int o = ct * 16 + l15;
            float bias = b2[o];
#pragma unroll
            for (int r = 0; r < 4; ++r)
                s_act[orow + r * AROW + o] = __float2half(silu_f(acc[ct][r] + bias));
        }
        __syncthreads();
    }

    // ---- layer 3: 128 -> 192 (raw col o -> stored col (o%3)*64 + o/3)
    {
        f16x8 a[4];
#pragma unroll
        for (int ks = 0; ks < 4; ++ks)
            a[ks] = *(const f16x8*)&s_act[arow + ks * 32 + lg * 8];
        float Cr[4];
#pragma unroll
        for (int r = 0; r < 4; ++r) Cr[r] = s_C[row0 + lg * 4 + r];
        __syncthreads();
#pragma unroll
        for (int ct = 0; ct < 12; ++ct) {
            f32x4 acc = zacc;
#pragma unroll
            for (int ks = 0; ks < 4; ++ks)
                acc = __builtin_amdgcn_mfma_f32_16x16x32_f16(a[ks], WF[(20 + ct * 4 + ks) * 64 + lane], acc, 0, 0, 0);
            int o = ct * 16 + l15;
            float bias = b3[o];
            int f = o / 3;
            int cmp = o - f * 3;
            int col = cmp * 64 + f;
#pragma unroll
            for (int r = 0; r < 4; ++r)
                s_act[orow + r * AROW + col] = __float2half(silu_f(acc[r] + bias) * Cr[r]);
        }
        __syncthreads();
    }

    // ---- message pass: 4 independent streams per wave (quarters of 16).
    {
        int wv = __builtin_amdgcn_readfirstlane(w);
        size_t slab = (size_t)N * 64;
        int jmax = min(64, E - p0);

        if (wv == 2) {
            // comps {4,5} via Tg pair 2, comp 6 via Tg6; rf2 at col 128+lane
            const unsigned int* TP = (const unsigned int*)Tg + 2 * slab;
            const unsigned short* T6 = (const unsigned short*)Tg6;
            auto flush3 = [&](int cur, int gs, int ge, float a0, float a1, float a2) {
                bool lb = (gs == 0) || (srcp[gs - 1] != cur);
                bool rb = (ge >= E) || (srcp[ge] != cur);
                size_t b = (size_t)cur * 64 + lane;
                if (lb && rb) {
                    msg[4 * slab + b] = a0;
                    msg[5 * slab + b] = a1;
                    msg[6 * slab + b] = a2;
                } else {
                    atomicAdd(&msg[4 * slab + b], a0);
                    atomicAdd(&msg[5 * slab + b], a1);
                    atomicAdd(&msg[6 * slab + b], a2);
                }
            };
            float A00 = 0.f, A01 = 0.f, A02 = 0.f, A10 = 0.f, A11 = 0.f, A12 = 0.f;
            float A20 = 0.f, A21 = 0.f, A22 = 0.f, A30 = 0.f, A31 = 0.f, A32 = 0.f;
            int cur0 = -1, cur1 = -1, cur2 = -1, cur3 = -1;
            int js0 = 0, js1 = 0, js2 = 0, js3 = 0;
            unsigned int tv0 = 0, tv1 = 0, tv2 = 0, tv3 = 0;
            unsigned short t60 = 0, t61 = 0, t62 = 0, t63 = 0;
            if (0 < jmax)  { int d = s_dst[0];  tv0 = TP[(size_t)d * 64 + lane]; t60 = T6[(size_t)d * 64 + lane]; }
            if (16 < jmax) { int d = s_dst[16]; tv1 = TP[(size_t)d * 64 + lane]; t61 = T6[(size_t)d * 64 + lane]; }
            if (32 < jmax) { int d = s_dst[32]; tv2 = TP[(size_t)d * 64 + lane]; t62 = T6[(size_t)d * 64 + lane]; }
            if (48 < jmax) { int d = s_dst[48]; tv3 = TP[(size_t)d * 64 + lane]; t63 = T6[(size_t)d * 64 + lane]; }
#define MS3(BASE, CUR, JS, A0, A1, A2, TV, T6R) { \
            int j = (BASE) + t; \
            if (j < jmax) { \
                unsigned int tvc = TV; unsigned short t6c = T6R; \
                int jn = j + 1; \
                if (jn < (BASE) + 16 && jn < jmax) { int dn = s_dst[jn]; \
                    TV = TP[(size_t)dn * 64 + lane]; T6R = T6[(size_t)dn * 64 + lane]; } \
                int s = s_src[j]; \
                if (s != CUR) { if (CUR >= 0) flush3(CUR, p0 + JS, p0 + j, A0, A1, A2); \
                                CUR = s; JS = j; A0 = 0.f; A1 = 0.f; A2 = 0.f; } \
                float rf = __half2float(s_act[j * AROW + 128 + lane]); \
                float2 tvf = __half22float2(*(__half2*)&tvc); \
                A0 += rf * tvf.x; A1 += rf * tvf.y; \
                A2 += rf * __half2float(*(__half*)&t6c); \
            } }
            for (int t = 0; t < 16; ++t) {
                MS3(0,  cur0, js0, A00, A01, A02, tv0, t60)
                MS3(16, cur1, js1, A10, A11, A12, tv1, t61)
                MS3(32, cur2, js2, A20, A21, A22, tv2, t62)
                MS3(48, cur3, js3, A30, A31, A32, tv3, t63)
            }
#undef MS3
            if (cur0 >= 0) flush3(cur0, p0 + js0, p0 + min(16, jmax), A00, A01, A02);
            if (cur1 >= 0) flush3(cur1, p0 + js1, p0 + min(32, jmax), A10, A11, A12);
            if (cur2 >= 0) flush3(cur2, p0 + js2, p0 + min(48, jmax), A20, A21, A22);
            if (cur3 >= 0) flush3(cur3, p0 + js3, p0 + min(64, jmax), A30, A31, A32);
        } else {
            int pr = (wv == 3) ? 3 : wv;
            int c0 = (wv == 0) ? 0 : ((wv == 1) ? 2 : 7);
            int c1 = c0 + 1;
            int offA = (wv == 0) ? lane : ((wv == 1) ? (64 + lane) : (128 + lane));
            int offB = 64 + lane;     // only used by wave0
            bool W0 = (wv == 0);
            const unsigned int* TP = (const unsigned int*)Tg + (size_t)pr * slab;
            auto flush2 = [&](int cur, int gs, int ge, float a0, float a1) {
                bool lb = (gs == 0) || (srcp[gs - 1] != cur);
                bool rb = (ge >= E) || (srcp[ge] != cur);
                size_t b = (size_t)cur * 64 + lane;
                if (lb && rb) {
                    msg[(size_t)c0 * slab + b] = a0;
                    msg[(size_t)c1 * slab + b] = a1;
                } else {
                    atomicAdd(&msg[(size_t)c0 * slab + b], a0);
                    atomicAdd(&msg[(size_t)c1 * slab + b], a1);
                }
            };
            float A00 = 0.f, A01 = 0.f, A10 = 0.f, A11 = 0.f;
            float A20 = 0.f, A21 = 0.f, A30 = 0.f, A31 = 0.f;
            int cur0 = -1, cur1 = -1, cur2 = -1, cur3 = -1;
            int js0 = 0, js1 = 0, js2 = 0, js3 = 0;
            unsigned int tv0 = 0, tv1 = 0, tv2 = 0, tv3 = 0;
            if (0 < jmax)  tv0 = TP[(size_t)s_dst[0]  * 64 + lane];
            if (16 < jmax) tv1 = TP[(size_t)s_dst[16] * 64 + lane];
            if (32 < jmax) tv2 = TP[(size_t)s_dst[32] * 64 + lane];
            if (48 < jmax) tv3 = TP[(size_t)s_dst[48] * 64 + lane];
#define MS2(BASE, CUR, JS, A0, A1, TV) { \
            int j = (BASE) + t; \
            if (j < jmax) { \
                unsigned int tvc = TV; \
                int jn = j + 1; \
                if (jn < (BASE) + 16 && jn < jmax) \
                    TV = TP[(size_t)s_dst[jn] * 64 + lane]; \
                int s = s_src[j]; \
                if (s != CUR) { if (CUR >= 0) flush2(CUR, p0 + JS, p0 + j, A0, A1); \
                                CUR = s; JS = j; A0 = 0.f; A1 = 0.f; } \
                float2 tvf = __half22float2(*(__half2*)&tvc); \
                float rfA = __half2float(s_act[j * AROW + offA]); \
                float rfB = W0 ? __half2float(s_act[j * AROW + offB]) : rfA; \
                A0 += rfA * tvf.x; A1 += rfB * tvf.y; \
            } }
            for (int t = 0; t < 16; ++t) {
                MS2(0,  cur0, js0, A00, A01, tv0)
                MS2(16, cur1, js1, A10, A11, tv1)
                MS2(32, cur2, js2, A20, A21, tv2)
                MS2(48, cur3, js3, A30, A31, tv3)
            }
#undef MS2
            if (cur0 >= 0) flush2(cur0, p0 + js0, p0 + min(16, jmax), A00, A01);
            if (cur1 >= 0) flush2(cur1, p0 + js1, p0 + min(32, jmax), A10, A11);
            if (cur2 >= 0) flush2(cur2, p0 + js2, p0 + min(48, jmax), A20, A21);
            if (cur3 >= 0) flush2(cur3, p0 + js3, p0 + min(64, jmax), A30, A31);
        }
    }
}

// ---------------------------------------------------------------------------
// K_TAIL: fused node_mix + comp-GEMM#2 + out. 32 nodes per block.
// Phase 1: mix -> U2 fp16 in LDS [(c*32+node)*72 + f].
// Phase 2: 18 (comp,row-tile) MFMA combos -> V fp16 back into same LDS.
// Phase 3: out = Xn + dX + sc*dX@dX.
// ---------------------------------------------------------------------------
__global__ __launch_bounds__(256) void k_tail(
    const float* __restrict__ msg, const float* __restrict__ T,
    const float* __restrict__ X, const float* __restrict__ charges,
    const __half* __restrict__ Wfrag, float* __restrict__ out, int N)
{
    __shared__ __half u2l[9 * 32 * 72];   // 41.5 KB
    __shared__ float s_sc[32];
    int tid = threadIdx.x;
    int n0 = blockIdx.x * 32;
    size_t slab = (size_t)N * 64;

    if (tid < 32) {
        int n = n0 + tid;
        s_sc[tid] = (n < N) ? 1.0f + 0.1f * charges[n] : 0.f;
    }
    __syncthreads();

    // ---- phase 1: node mix
    for (int e = 0; e < 8; ++e) {
        int idx = e * 256 + tid;          // 0..2047
        int node = idx >> 6;
        int f = idx & 63;
        int n = n0 + node;
        float um[9], uy[9];
        if (n < N) {
#pragma unroll
            for (int c = 0; c < 9; ++c) {
                um[c] = msg[(size_t)c * slab + (size_t)n0 * 64 + idx];
                uy[c] = T[(size_t)c * slab + (size_t)n0 * 64 + idx];
            }
        } else {
#pragma unroll
            for (int c = 0; c < 9; ++c) { um[c] = 0.f; uy[c] = 0.f; }
        }
        float M[9], Y[9];
        recon(um, M);
        recon(uy, Y);
        float P[9];
#pragma unroll
        for (int i = 0; i < 3; ++i)
#pragma unroll
            for (int j = 0; j < 3; ++j) {
                float s = 0.f;
#pragma unroll
                for (int k = 0; k < 3; ++k)
                    s += M[i * 3 + k] * Y[k * 3 + j] + Y[i * 3 + k] * M[k * 3 + j];
                P[i * 3 + j] = s;
            }
        float sc = s_sc[node];
        float nrm = 0.f;
#pragma unroll
        for (int i = 0; i < 9; ++i) { P[i] *= sc; nrm += P[i] * P[i]; }
        float inv = 1.0f / (nrm + 1.0f);
        float lam = (P[0] + P[4] + P[8]) * (1.f / 3.f);
        u2l[(0 * 32 + node) * 72 + f] = __float2half(lam * inv);
        u2l[(1 * 32 + node) * 72 + f] = __float2half(0.5f * (P[1] - P[3]) * inv);
        u2l[(2 * 32 + node) * 72 + f] = __float2half(0.5f * (P[2] - P[6]) * inv);
        u2l[(3 * 32 + node) * 72 + f] = __float2half(0.5f * (P[5] - P[7]) * inv);
        u2l[(4 * 32 + node) * 72 + f] = __float2half((P[0] - lam) * inv);
        u2l[(5 * 32 + node) * 72 + f] = __float2half(0.5f * (P[1] + P[3]) * inv);
        u2l[(6 * 32 + node) * 72 + f] = __float2half(0.5f * (P[2] + P[6]) * inv);
        u2l[(7 * 32 + node) * 72 + f] = __float2half((P[4] - lam) * inv);
        u2l[(8 * 32 + node) * 72 + f] = __float2half(0.5f * (P[5] + P[7]) * inv);
    }
    __syncthreads();

    // ---- phase 2: GEMM (18 combos = comp c x row-tile rt)
    int w = tid >> 6, lane = tid & 63;
    int l15 = lane & 15, lg = lane >> 4;
    const f32x4 z = {0.f, 0.f, 0.f, 0.f};
    f32x4 acc[5][4];
#pragma unroll
    for (int q = 0; q < 5; ++q) {
        int cm = w + q * 4;
        if (cm < 18) {
            int c = cm >> 1, rt = cm & 1;
            int gsel = (c == 0) ? 0 : (c < 4 ? 1 : 2);
            const f16x8* WFc = (const f16x8*)(Wfrag + gsel * WLFRAG);
            int abase = (c * 32 + rt * 16 + l15) * 72;
            f16x8 a0 = *(const f16x8*)&u2l[abase + lg * 8];
            f16x8 a1 = *(const f16x8*)&u2l[abase + 32 + lg * 8];
#pragma unroll
            for (int ct = 0; ct < 4; ++ct) {
                acc[q][ct] = __builtin_amdgcn_mfma_f32_16x16x32_f16(a0, WFc[(ct * 2 + 0) * 64 + lane], z, 0, 0, 0);
                acc[q][ct] = __builtin_amdgcn_mfma_f32_16x16x32_f16(a1, WFc[(ct * 2 + 1) * 64 + lane], acc[q][ct], 0, 0, 0);
            }
        }
    }
    __syncthreads();
#pragma unroll
    for (int q = 0; q < 5; ++q) {
        int cm = w + q * 4;
        if (cm < 18) {
            int c = cm >> 1, rt = cm & 1;
#pragma unroll
            for (int ct = 0; ct < 4; ++ct)
#pragma unroll
                for (int r = 0; r < 4; ++r)
                    u2l[(c * 32 + rt * 16 + lg * 4 + r) * 72 + ct * 16 + l15] =
                        __float2half(acc[q][ct][r]);
        }
    }
    __syncthreads();

    // ---- phase 3: out
    for (int e = 0; e < 8; ++e) {
        int idx = e * 256 + tid;
        int node = idx >> 6;
        int n = n0 + node;
        if (n >= N) continue;
        int f = idx & 63;
        float v[9];
#pragma unroll
        for (int c = 0; c < 9; ++c)
            v[c] = __half2float(u2l[(c * 32 + node) * 72 + f]);
        float dX[9];
        recon(v, dX);
        const float* xp = X + (size_t)n * 576 + f * 9;
        float m[9]; float n2 = 0.f;
#pragma unroll
        for (int i = 0; i < 9; ++i) { m[i] = xp[i]; n2 += m[i] * m[i]; }
        float invn = 1.0f / (n2 + 1.0f);
#pragma unroll
        for (int i = 0; i < 9; ++i) m[i] *= invn;
        float sc = s_sc[node];
        float* op = out + (size_t)n * 576 + f * 9;
#pragma unroll
        for (int i = 0; i < 3; ++i)
#pragma unroll
            for (int j = 0; j < 3; ++j) {
                float s = 0.f;
#pragma unroll
                for (int k = 0; k < 3; ++k) s += dX[i * 3 + k] * dX[k * 3 + j];
                op[i * 3 + j] = m[i * 3 + j] + dX[i * 3 + j] + sc * s;
            }
    }
}

// ---------------------------------------------------------------------------
extern "C" void kernel_launch(void* const* d_in, const int* in_sizes, int n_in,
                              void* d_out, int out_size, void* d_ws, size_t ws_size,
                              hipStream_t stream)
{
    const float* X       = (const float*)d_in[0];
    const int*   pair    = (const int*)d_in[1];
    const float* dij     = (const float*)d_in[2];
    const float* radial  = (const float*)d_in[3];
    const float* charges = (const float*)d_in[4];
    const float* W1  = (const float*)d_in[5];
    const float* b1  = (const float*)d_in[6];
    const float* W2  = (const float*)d_in[7];
    const float* b2  = (const float*)d_in[8];
    const float* W3  = (const float*)d_in[9];
    const float* b3  = (const float*)d_in[10];
    const float* Wl0 = (const float*)d_in[11];
    const float* Wl1 = (const float*)d_in[12];
    const float* Wl2 = (const float*)d_in[13];
    const float* Wl3 = (const float*)d_in[14];
    const float* Wl4 = (const float*)d_in[15];
    const float* Wl5 = (const float*)d_in[16];

    int N = in_sizes[4];
    int E = in_sizes[2];
    int R = 9 * N;
    int nb_gemm = (R + 63) / 64;
    int nb_node4 = (N + 3) / 4;
    int nb_edge = (E + 63) / 64;
    int nb_tail = (N + 31) / 32;
    size_t slab = (size_t)N * 64;
    size_t slab9 = slab * 9;

    float* A = (float*)d_ws;               // U -> T (in-place GEMM)
    float* B = A + slab9;                  // msg
    __half2* Tg = (__half2*)(B + slab9);   // 4*slab half2
    __half* Tg6 = (__half*)(Tg + 4 * slab);
    __half* Wf  = Tg6 + slab;
    int* ints   = (int*)(Wf + MLPFRAGS + 6 * WLFRAG);
    int* count  = ints;
    int* off    = count + N;
    int* cursor = off + N + 1;
    int* eOf    = cursor + N;
    int* dstp   = eOf + E;
    int* srcp   = dstp + E;

    hipMemsetAsync(count, 0, (size_t)N * sizeof(int), stream);
    hipMemsetAsync(B, 0, slab9 * sizeof(float), stream);

    int nWf = MLPFRAGS + 6 * WLFRAG;
    k_wcvt<<<(nWf + 255) / 256, 256, 0, stream>>>(W1, W2, W3,
                                                  Wl0, Wl1, Wl2, Wl3, Wl4, Wl5, Wf);
    k_node_prep<<<nb_node4, 256, 0, stream>>>(X, A, N);
    k_comp_gemm_m<<<nb_gemm, 256, 0, stream>>>(A, A, Wf + MLPFRAGS,
                                               Wl0, Wl1, Wl2, R, N);
    k_tcvt<<<(N * 64 + 255) / 256, 256, 0, stream>>>(A, Tg, Tg6, N);

    k_hist<<<(E + 255) / 256, 256, 0, stream>>>(pair, count, E);
    k_scan<<<1, 1024, 0, stream>>>(count, off, cursor, N, E);
    k_scatter_sort<<<(E + 255) / 256, 256, 0, stream>>>(pair, cursor, eOf, dstp, srcp, E);

    k_edge_sorted<<<nb_edge, 256, 0, stream>>>(radial, dij, eOf, dstp, srcp,
                                               Wf, b1, b2, b3, Tg, Tg6, B, E, N);

    k_tail<<<nb_tail, 256, 0, stream>>>(B, A, X, charges,
                                        Wf + MLPFRAGS + 3 * WLFRAG,
                                        (float*)d_out, N);
}

// Round 10
// 414.506 us; speedup vs baseline: 1.6504x; 1.1351x over previous
//
#include <hip/hip_runtime.h>
#include <hip/hip_fp16.h>
#include <math.h>

#ifndef M_PI
#define M_PI 3.14159265358979323846
#endif

// ---------------------------------------------------------------------------
// TensorNet interaction. fp32 math, fp16 LDS/gather tensors, MFMA fp16 GEMMs.
// Compressed irreducible rep per (n,f): u[9] =
//   { lam, a01, a02, a12, s00, s01, s02, s11, s12 }   (s22 = -s00-s11)
//
// ws (~90 MB): B slab (msg fp32), TgP (3 fp16 comp-pair slabs), Tg456
// (packed half4), Wf (fp16 MFMA frags), CSR ints.
//
// Round-10 changes:
//  * k_head fuses node_prep + comp-GEMM#1 + tcvt (one kernel, 32 nodes/blk,
//    3-phase LDS structure mirroring k_tail). fp32 T slab eliminated;
//    only fp16 gather layouts are materialized. 324 -> 94 MB, -2 launches.
//  * k_tail reads Y from TgP/Tg456 (fp16) instead of fp32 T.
//  * edge loop: s_dst pre-multiplied, readfirstlane run-compare (SALU),
//    wave2 single uint2 load for comps {4,5,6}.
// ---------------------------------------------------------------------------

typedef _Float16 f16x8 __attribute__((ext_vector_type(8)));
typedef float f32x4 __attribute__((ext_vector_type(4)));

#define AROW 216        // halfs per activation row (432 B = 27*16)
#define MLPFRAGS 34816  // 68 frags * 512 halfs
#define WLFRAG 4096     // halfs per Wl matrix (8 frags * 512)

__device__ __forceinline__ float silu_f(float x) {
    return x / (1.0f + __expf(-x));
}

__device__ __forceinline__ void recon(const float u[9], float M[9]) {
    M[0] =  u[0] + u[4];
    M[1] =  u[1] + u[5];
    M[2] =  u[2] + u[6];
    M[3] = -u[1] + u[5];
    M[4] =  u[0] + u[7];
    M[5] =  u[3] + u[8];
    M[6] = -u[2] + u[6];
    M[7] = -u[3] + u[8];
    M[8] =  u[0] - u[4] - u[7];
}

// ---------------------------------------------------------------------------
// Weight -> fp16 MFMA-fragment conversion (once per launch).
// Fragment element (lane l, j) = W[ct*16+(l&15)][ks*32+(l>>4)*8+j].
// ---------------------------------------------------------------------------
__global__ __launch_bounds__(256) void k_wcvt(
    const float* __restrict__ W1, const float* __restrict__ W2,
    const float* __restrict__ W3,
    const float* __restrict__ Wl0, const float* __restrict__ Wl1,
    const float* __restrict__ Wl2, const float* __restrict__ Wl3,
    const float* __restrict__ Wl4, const float* __restrict__ Wl5,
    __half* __restrict__ Wf)
{
    int idx = blockIdx.x * 256 + threadIdx.x;
    if (idx >= MLPFRAGS + 6 * WLFRAG) return;
    float v;
    if (idx < MLPFRAGS) {
        int frag = idx >> 9;
        int r = idx & 511;
        int l = r >> 3, j = r & 7;
        int l15 = l & 15, lg = l >> 4;
        if (frag < 4) {
            int ct = frag;
            v = W1[(ct * 16 + l15) * 32 + (lg * 8 + j)];
        } else if (frag < 20) {
            int f2 = frag - 4;
            int ct = f2 >> 1, ks = f2 & 1;
            v = W2[(ct * 16 + l15) * 64 + (ks * 32 + lg * 8 + j)];
        } else {
            int f3 = frag - 20;
            int ct = f3 >> 2, ks = f3 & 3;
            v = W3[(ct * 16 + l15) * 128 + (ks * 32 + lg * 8 + j)];
        }
    } else {
        int r2 = idx - MLPFRAGS;
        int wIdx = r2 >> 12;           // /4096
        int rr = r2 & 4095;
        int f = rr >> 9;               // ct*2+ks
        int ct = f >> 1, ks = f & 1;
        int elem = rr & 511;
        int l = elem >> 3, j = elem & 7;
        int l15 = l & 15, lg = l >> 4;
        const float* W = (wIdx == 0) ? Wl0 : (wIdx == 1) ? Wl1 : (wIdx == 2) ? Wl2
                       : (wIdx == 3) ? Wl3 : (wIdx == 4) ? Wl4 : Wl5;
        v = W[(ct * 16 + l15) * 64 + (ks * 32 + lg * 8 + j)];
    }
    Wf[idx] = __float2half(v);
}

// ---------------------------------------------------------------------------
// K_HEAD: fused node_prep + comp-GEMM#1 + T-convert. 32 nodes per block.
// Phase 1: Xn = X/(|X|^2+1), decompose -> U fp16 in LDS [(c*32+node)*72+f]
//          (8 chunks of 4 nodes staged via s_x for coalesced X reads).
// Phase 2: 18 (comp,row-tile) MFMA combos (Wl0..Wl2) -> T fp16 in-place.
// Phase 3: write gather layouts TgP pairs {0,1},{2,3},{7,8} + Tg456.
// ---------------------------------------------------------------------------
__global__ __launch_bounds__(256) void k_head(
    const float* __restrict__ X, const __half* __restrict__ Wfrag,
    __half2* __restrict__ TgP, uint2* __restrict__ Tg456, int N)
{
    __shared__ __half u2l[9 * 32 * 72];   // 41.5 KB
    __shared__ float s_x[2304];           // 9.2 KB (4 nodes)
    int tid = threadIdx.x;
    int n0 = blockIdx.x * 32;
    size_t total = (size_t)N * 576;

    // ---- phase 1: prep 8 chunks of 4 nodes
    for (int ch = 0; ch < 8; ++ch) {
        size_t base = (size_t)(n0 + ch * 4) * 576;
        for (int idx = tid; idx < 2304; idx += 256) {
            size_t gi = base + idx;
            s_x[idx] = (gi < total) ? X[gi] : 0.f;
        }
        __syncthreads();
        int w = tid >> 6, f = tid & 63;
        int node = ch * 4 + w;
        float m[9]; float n2 = 0.f;
#pragma unroll
        for (int i = 0; i < 9; ++i) { m[i] = s_x[w * 576 + f * 9 + i]; n2 += m[i] * m[i]; }
        float inv = 1.0f / (n2 + 1.0f);
#pragma unroll
        for (int i = 0; i < 9; ++i) m[i] *= inv;
        float lam = (m[0] + m[4] + m[8]) * (1.f / 3.f);
        u2l[(0 * 32 + node) * 72 + f] = __float2half(lam);
        u2l[(1 * 32 + node) * 72 + f] = __float2half(0.5f * (m[1] - m[3]));
        u2l[(2 * 32 + node) * 72 + f] = __float2half(0.5f * (m[2] - m[6]));
        u2l[(3 * 32 + node) * 72 + f] = __float2half(0.5f * (m[5] - m[7]));
        u2l[(4 * 32 + node) * 72 + f] = __float2half(m[0] - lam);
        u2l[(5 * 32 + node) * 72 + f] = __float2half(0.5f * (m[1] + m[3]));
        u2l[(6 * 32 + node) * 72 + f] = __float2half(0.5f * (m[2] + m[6]));
        u2l[(7 * 32 + node) * 72 + f] = __float2half(m[4] - lam);
        u2l[(8 * 32 + node) * 72 + f] = __float2half(0.5f * (m[5] + m[7]));
        __syncthreads();
    }

    // ---- phase 2: GEMM (18 combos = comp c x row-tile rt), in-place
    int w = tid >> 6, lane = tid & 63;
    int l15 = lane & 15, lg = lane >> 4;
    const f32x4 z = {0.f, 0.f, 0.f, 0.f};
    f32x4 acc[5][4];
#pragma unroll
    for (int q = 0; q < 5; ++q) {
        int cm = w + q * 4;
        if (cm < 18) {
            int c = cm >> 1, rt = cm & 1;
            int gsel = (c == 0) ? 0 : (c < 4 ? 1 : 2);
            const f16x8* WFc = (const f16x8*)(Wfrag + gsel * WLFRAG);
            int abase = (c * 32 + rt * 16 + l15) * 72;
            f16x8 a0 = *(const f16x8*)&u2l[abase + lg * 8];
            f16x8 a1 = *(const f16x8*)&u2l[abase + 32 + lg * 8];
#pragma unroll
            for (int ct = 0; ct < 4; ++ct) {
                acc[q][ct] = __builtin_amdgcn_mfma_f32_16x16x32_f16(a0, WFc[(ct * 2 + 0) * 64 + lane], z, 0, 0, 0);
                acc[q][ct] = __builtin_amdgcn_mfma_f32_16x16x32_f16(a1, WFc[(ct * 2 + 1) * 64 + lane], acc[q][ct], 0, 0, 0);
            }
        }
    }
    __syncthreads();
#pragma unroll
    for (int q = 0; q < 5; ++q) {
        int cm = w + q * 4;
        if (cm < 18) {
            int c = cm >> 1, rt = cm & 1;
#pragma unroll
            for (int ct = 0; ct < 4; ++ct)
#pragma unroll
                for (int r = 0; r < 4; ++r)
                    u2l[(c * 32 + rt * 16 + lg * 4 + r) * 72 + ct * 16 + l15] =
                        __float2half(acc[q][ct][r]);
        }
    }
    __syncthreads();

    // ---- phase 3: write gather layouts
    size_t slab = (size_t)N * 64;
    for (int e = 0; e < 8; ++e) {
        int idx = e * 256 + tid;
        int node = idx >> 6;
        int n = n0 + node;
        if (n >= N) continue;
        int f = idx & 63;
        size_t t = (size_t)n * 64 + f;
        const int pa[3] = {0, 2, 7};
#pragma unroll
        for (int pr = 0; pr < 3; ++pr) {
            __half a = u2l[(pa[pr] * 32 + node) * 72 + f];
            __half b = u2l[((pa[pr] + 1) * 32 + node) * 72 + f];
            TgP[(size_t)pr * slab + t] = __halves2half2(a, b);
        }
        __half2 lo = __halves2half2(u2l[(4 * 32 + node) * 72 + f],
                                    u2l[(5 * 32 + node) * 72 + f]);
        __half2 hi = __halves2half2(u2l[(6 * 32 + node) * 72 + f], __float2half(0.f));
        uint2 pk;
        pk.x = *(unsigned int*)&lo;
        pk.y = *(unsigned int*)&hi;
        Tg456[t] = pk;
    }
}

// ---------------------------------------------------------------------------
// CSR sort of edges by src: histogram -> scan -> ranked placement.
// ---------------------------------------------------------------------------
__global__ __launch_bounds__(256) void k_hist(
    const int* __restrict__ pair, int* __restrict__ count, int E)
{
    int e = blockIdx.x * 256 + threadIdx.x;
    if (e < E) atomicAdd(&count[pair[e]], 1);
}

__global__ __launch_bounds__(1024) void k_scan(
    const int* __restrict__ count, int* __restrict__ off,
    int* __restrict__ cursor, int N, int E)
{
    __shared__ int s[1024];
    __shared__ int s_carry;
    int tid = threadIdx.x;
    if (tid == 0) s_carry = 0;
    __syncthreads();
    const int CH = 32;
    for (int base = 0; base < N; base += 1024 * CH) {
        int b0 = base + tid * CH;
        int local[CH]; int sum = 0;
#pragma unroll
        for (int i = 0; i < CH; ++i) {
            int idx = b0 + i;
            int v = (idx < N) ? count[idx] : 0;
            local[i] = sum; sum += v;
        }
        s[tid] = sum;
        __syncthreads();
        for (int d = 1; d < 1024; d <<= 1) {
            int t2 = (tid >= d) ? s[tid - d] : 0;
            __syncthreads();
            s[tid] += t2;
            __syncthreads();
        }
        int excl0 = s_carry + s[tid] - sum;
#pragma unroll
        for (int i = 0; i < CH; ++i) {
            int idx = b0 + i;
            if (idx < N) { int e = excl0 + local[i]; off[idx] = e; cursor[idx] = e; }
        }
        __syncthreads();
        if (tid == 1023) s_carry += s[1023];
        __syncthreads();
    }
    if (tid == 0) off[N] = E;
}

__global__ __launch_bounds__(256) void k_scatter_sort(
    const int* __restrict__ pair, int* __restrict__ cursor,
    int* __restrict__ eOf, int* __restrict__ dstp, int* __restrict__ srcp, int E)
{
    int e = blockIdx.x * 256 + threadIdx.x;
    if (e < E) {
        int s = pair[e];
        int d = pair[(size_t)E + e];
        int pos = atomicAdd(&cursor[s], 1);
        eOf[pos] = e;
        dstp[pos] = d;
        srcp[pos] = s;
    }
}

// ---------------------------------------------------------------------------
// K2: fused edge MLP on MFMA + 4-stream run-accumulated message pass.
// ---------------------------------------------------------------------------
__global__ __launch_bounds__(256) void k_edge_sorted(
    const float* __restrict__ radial, const float* __restrict__ d_ij,
    const int* __restrict__ eOf, const int* __restrict__ dstp,
    const int* __restrict__ srcp,
    const __half* __restrict__ Wf,
    const float* __restrict__ b1, const float* __restrict__ b2,
    const float* __restrict__ b3,
    const __half2* __restrict__ TgP, const uint2* __restrict__ Tg456,
    float* __restrict__ msg, int E, int N)
{
    __shared__ __half s_act[64 * AROW];
    __shared__ float s_C[64];
    __shared__ int s_e[64];
    __shared__ int s_src[64];
    __shared__ int s_dst[64];    // PRE-MULTIPLIED by 64 (element offset)
    int tid = threadIdx.x;
    int p0 = blockIdx.x * 64;

    if (tid < 64) {
        int p = p0 + tid;
        int e = -1, s = 0, d = 0; float C = 0.f;
        if (p < E) {
            e = eOf[p];
            s = srcp[p];
            d = dstp[p];
            float dd = d_ij[e];
            C = (dd < 5.0f) ? 0.5f * (cosf((float)M_PI * dd * 0.2f) + 1.0f) : 0.0f;
        }
        s_e[tid] = e; s_src[tid] = s; s_dst[tid] = d * 64; s_C[tid] = C;
    }
    __syncthreads();

    {   // stage rbf: s_act[j][k], fp16
        int j = tid >> 2;
        int kk = (tid & 3) * 8;
        int e = s_e[j];
        float4 v0 = make_float4(0.f, 0.f, 0.f, 0.f), v1 = v0;
        if (e >= 0) {
            v0 = *(const float4*)(radial + (size_t)e * 32 + kk);
            v1 = *(const float4*)(radial + (size_t)e * 32 + kk + 4);
        }
        __half2* dst = (__half2*)&s_act[j * AROW + kk];
        dst[0] = __floats2half2_rn(v0.x, v0.y);
        dst[1] = __floats2half2_rn(v0.z, v0.w);
        dst[2] = __floats2half2_rn(v1.x, v1.y);
        dst[3] = __floats2half2_rn(v1.z, v1.w);
    }
    __syncthreads();

    int w = tid >> 6;
    int lane = tid & 63;
    int l15 = lane & 15, lg = lane >> 4;
    const int row0 = w * 16;
    const int arow = (row0 + l15) * AROW;
    const int orow = (row0 + lg * 4) * AROW;
    const f16x8* WF = (const f16x8*)Wf;
    const f32x4 zacc = {0.f, 0.f, 0.f, 0.f};

    // ---- layer 1: 32 -> 64
    {
        f16x8 a = *(const f16x8*)&s_act[arow + lg * 8];
        f32x4 acc[4];
#pragma unroll
        for (int ct = 0; ct < 4; ++ct)
            acc[ct] = __builtin_amdgcn_mfma_f32_16x16x32_f16(a, WF[ct * 64 + lane], zacc, 0, 0, 0);
        __syncthreads();
#pragma unroll
        for (int ct = 0; ct < 4; ++ct) {
            int o = ct * 16 + l15;
            float bias = b1[o];
#pragma unroll
            for (int r = 0; r < 4; ++r)
                s_act[orow + r * AROW + o] = __float2half(silu_f(acc[ct][r] + bias));
        }
        __syncthreads();
    }

    // ---- layer 2: 64 -> 128
    {
        f16x8 a0 = *(const f16x8*)&s_act[arow + 0 * 32 + lg * 8];
        f16x8 a1 = *(const f16x8*)&s_act[arow + 1 * 32 + lg * 8];
        f32x4 acc[8];
#pragma unroll
        for (int ct = 0; ct < 8; ++ct) {
            acc[ct] = __builtin_amdgcn_mfma_f32_16x16x32_f16(a0, WF[(4 + ct * 2 + 0) * 64 + lane], zacc, 0, 0, 0);
            acc[ct] = __builtin_amdgcn_mfma_f32_16x16x32_f16(a1, WF[(4 + ct * 2 + 1) * 64 + lane], acc[ct], 0, 0, 0);
        }
        __syncthreads();
#pragma unroll
        for (int ct = 0; ct < 8; ++ct) {
            int o = ct * 16 + l15;
            float bias = b2[o];
#pragma unroll
            for (int r = 0; r < 4; ++r)
                s_act[orow + r * AROW + o] = __float2half(silu_f(acc[ct][r] + bias));
        }
        __syncthreads();
    }

    // ---- layer 3: 128 -> 192 (raw col o -> stored col (o%3)*64 + o/3)
    {
        f16x8 a[4];
#pragma unroll
        for (int ks = 0; ks < 4; ++ks)
            a[ks] = *(const f16x8*)&s_act[arow + ks * 32 + lg * 8];
        float Cr[4];
#pragma unroll
        for (int r = 0; r < 4; ++r) Cr[r] = s_C[row0 + lg * 4 + r];
        __syncthreads();
#pragma unroll
        for (int ct = 0; ct < 12; ++ct) {
            f32x4 acc = zacc;
#pragma unroll
            for (int ks = 0; ks < 4; ++ks)
                acc = __builtin_amdgcn_mfma_f32_16x16x32_f16(a[ks], WF[(20 + ct * 4 + ks) * 64 + lane], acc, 0, 0, 0);
            int o = ct * 16 + l15;
            float bias = b3[o];
            int f = o / 3;
            int cmp = o - f * 3;
            int col = cmp * 64 + f;
#pragma unroll
            for (int r = 0; r < 4; ++r)
                s_act[orow + r * AROW + col] = __float2half(silu_f(acc[r] + bias) * Cr[r]);
        }
        __syncthreads();
    }

    // ---- message pass: 4 independent streams per wave (quarters of 16).
    {
        int wv = __builtin_amdgcn_readfirstlane(w);
        size_t slab = (size_t)N * 64;
        int jmax = min(64, E - p0);

        if (wv == 2) {
            // comps {4,5,6} via ONE uint2 (half4) load; rf2 at col 128+lane
            const uint2* T4 = Tg456;
            auto flush3 = [&](int cur, int gs, int ge, float a0, float a1, float a2) {
                bool lb = (gs == 0) || (srcp[gs - 1] != cur);
                bool rb = (ge >= E) || (srcp[ge] != cur);
                size_t b = (size_t)cur * 64 + lane;
                if (lb && rb) {
                    msg[4 * slab + b] = a0;
                    msg[5 * slab + b] = a1;
                    msg[6 * slab + b] = a2;
                } else {
                    atomicAdd(&msg[4 * slab + b], a0);
                    atomicAdd(&msg[5 * slab + b], a1);
                    atomicAdd(&msg[6 * slab + b], a2);
                }
            };
            float A00 = 0.f, A01 = 0.f, A02 = 0.f, A10 = 0.f, A11 = 0.f, A12 = 0.f;
            float A20 = 0.f, A21 = 0.f, A22 = 0.f, A30 = 0.f, A31 = 0.f, A32 = 0.f;
            int cur0 = -1, cur1 = -1, cur2 = -1, cur3 = -1;
            int js0 = 0, js1 = 0, js2 = 0, js3 = 0;
            uint2 tv0 = make_uint2(0, 0), tv1 = tv0, tv2 = tv0, tv3 = tv0;
            if (0 < jmax)  tv0 = T4[(size_t)s_dst[0]  + lane];
            if (16 < jmax) tv1 = T4[(size_t)s_dst[16] + lane];
            if (32 < jmax) tv2 = T4[(size_t)s_dst[32] + lane];
            if (48 < jmax) tv3 = T4[(size_t)s_dst[48] + lane];
#define MS3(BASE, CUR, JS, A0, A1, A2, TV) { \
            int j = (BASE) + t; \
            if (j < jmax) { \
                uint2 tvc = TV; \
                int jn = j + 1; \
                if (jn < (BASE) + 16 && jn < jmax) \
                    TV = T4[(size_t)s_dst[jn] + lane]; \
                int s = __builtin_amdgcn_readfirstlane(s_src[j]); \
                if (s != CUR) { if (CUR >= 0) flush3(CUR, p0 + JS, p0 + j, A0, A1, A2); \
                                CUR = s; JS = j; A0 = 0.f; A1 = 0.f; A2 = 0.f; } \
                float rf = __half2float(s_act[j * AROW + 128 + lane]); \
                float2 lof = __half22float2(*(__half2*)&tvc.x); \
                __half2 hic = *(__half2*)&tvc.y; \
                A0 += rf * lof.x; A1 += rf * lof.y; \
                A2 += rf * __half2float(hic.x); \
            } }
            for (int t = 0; t < 16; ++t) {
                MS3(0,  cur0, js0, A00, A01, A02, tv0)
                MS3(16, cur1, js1, A10, A11, A12, tv1)
                MS3(32, cur2, js2, A20, A21, A22, tv2)
                MS3(48, cur3, js3, A30, A31, A32, tv3)
            }
#undef MS3
            if (cur0 >= 0) flush3(cur0, p0 + js0, p0 + min(16, jmax), A00, A01, A02);
            if (cur1 >= 0) flush3(cur1, p0 + js1, p0 + min(32, jmax), A10, A11, A12);
            if (cur2 >= 0) flush3(cur2, p0 + js2, p0 + min(48, jmax), A20, A21, A22);
            if (cur3 >= 0) flush3(cur3, p0 + js3, p0 + min(64, jmax), A30, A31, A32);
        } else {
            int pr = (wv == 3) ? 2 : wv;     // TgP slabs: {0,1},{2,3},{7,8}
            int c0 = (wv == 0) ? 0 : ((wv == 1) ? 2 : 7);
            int c1 = c0 + 1;
            int offA = (wv == 0) ? lane : ((wv == 1) ? (64 + lane) : (128 + lane));
            int offB = 64 + lane;     // only used by wave0
            bool W0 = (wv == 0);
            const unsigned int* TP = (const unsigned int*)TgP + (size_t)pr * slab;
            auto flush2 = [&](int cur, int gs, int ge, float a0, float a1) {
                bool lb = (gs == 0) || (srcp[gs - 1] != cur);
                bool rb = (ge >= E) || (srcp[ge] != cur);
                size_t b = (size_t)cur * 64 + lane;
                if (lb && rb) {
                    msg[(size_t)c0 * slab + b] = a0;
                    msg[(size_t)c1 * slab + b] = a1;
                } else {
                    atomicAdd(&msg[(size_t)c0 * slab + b], a0);
                    atomicAdd(&msg[(size_t)c1 * slab + b], a1);
                }
            };
            float A00 = 0.f, A01 = 0.f, A10 = 0.f, A11 = 0.f;
            float A20 = 0.f, A21 = 0.f, A30 = 0.f, A31 = 0.f;
            int cur0 = -1, cur1 = -1, cur2 = -1, cur3 = -1;
            int js0 = 0, js1 = 0, js2 = 0, js3 = 0;
            unsigned int tv0 = 0, tv1 = 0, tv2 = 0, tv3 = 0;
            if (0 < jmax)  tv0 = TP[(size_t)s_dst[0]  + lane];
            if (16 < jmax) tv1 = TP[(size_t)s_dst[16] + lane];
            if (32 < jmax) tv2 = TP[(size_t)s_dst[32] + lane];
            if (48 < jmax) tv3 = TP[(size_t)s_dst[48] + lane];
#define MS2(BASE, CUR, JS, A0, A1, TV) { \
            int j = (BASE) + t; \
            if (j < jmax) { \
                unsigned int tvc = TV; \
                int jn = j + 1; \
                if (jn < (BASE) + 16 && jn < jmax) \
                    TV = TP[(size_t)s_dst[jn] + lane]; \
                int s = __builtin_amdgcn_readfirstlane(s_src[j]); \
                if (s != CUR) { if (CUR >= 0) flush2(CUR, p0 + JS, p0 + j, A0, A1); \
                                CUR = s; JS = j; A0 = 0.f; A1 = 0.f; } \
                float2 tvf = __half22float2(*(__half2*)&tvc); \
                float rfA = __half2float(s_act[j * AROW + offA]); \
                float rfB = W0 ? __half2float(s_act[j * AROW + offB]) : rfA; \
                A0 += rfA * tvf.x; A1 += rfB * tvf.y; \
            } }
            for (int t = 0; t < 16; ++t) {
                MS2(0,  cur0, js0, A00, A01, tv0)
                MS2(16, cur1, js1, A10, A11, tv1)
                MS2(32, cur2, js2, A20, A21, tv2)
                MS2(48, cur3, js3, A30, A31, tv3)
            }
#undef MS2
            if (cur0 >= 0) flush2(cur0, p0 + js0, p0 + min(16, jmax), A00, A01);
            if (cur1 >= 0) flush2(cur1, p0 + js1, p0 + min(32, jmax), A10, A11);
            if (cur2 >= 0) flush2(cur2, p0 + js2, p0 + min(48, jmax), A20, A21);
            if (cur3 >= 0) flush2(cur3, p0 + js3, p0 + min(64, jmax), A30, A31);
        }
    }
}

// ---------------------------------------------------------------------------
// K_TAIL: fused node_mix + comp-GEMM#2 + out. 32 nodes per block.
// Y read from fp16 gather layouts (TgP/Tg456).
// ---------------------------------------------------------------------------
__global__ __launch_bounds__(256) void k_tail(
    const float* __restrict__ msg,
    const __half2* __restrict__ TgP, const uint2* __restrict__ Tg456,
    const float* __restrict__ X, const float* __restrict__ charges,
    const __half* __restrict__ Wfrag, float* __restrict__ out, int N)
{
    __shared__ __half u2l[9 * 32 * 72];   // 41.5 KB
    __shared__ float s_sc[32];
    int tid = threadIdx.x;
    int n0 = blockIdx.x * 32;
    size_t slab = (size_t)N * 64;

    if (tid < 32) {
        int n = n0 + tid;
        s_sc[tid] = (n < N) ? 1.0f + 0.1f * charges[n] : 0.f;
    }
    __syncthreads();

    // ---- phase 1: node mix
    for (int e = 0; e < 8; ++e) {
        int idx = e * 256 + tid;          // 0..2047
        int node = idx >> 6;
        int n = n0 + node;
        float um[9], uy[9];
        if (n < N) {
            size_t t = (size_t)n0 * 64 + idx;
#pragma unroll
            for (int c = 0; c < 9; ++c)
                um[c] = msg[(size_t)c * slab + t];
            float2 p0 = __half22float2(TgP[0 * slab + t]);
            float2 p1 = __half22float2(TgP[1 * slab + t]);
            float2 p2 = __half22float2(TgP[2 * slab + t]);
            uint2 q = Tg456[t];
            float2 q0 = __half22float2(*(__half2*)&q.x);
            __half2 q1 = *(__half2*)&q.y;
            uy[0] = p0.x; uy[1] = p0.y;
            uy[2] = p1.x; uy[3] = p1.y;
            uy[4] = q0.x; uy[5] = q0.y;
            uy[6] = __half2float(q1.x);
            uy[7] = p2.x; uy[8] = p2.y;
        } else {
#pragma unroll
            for (int c = 0; c < 9; ++c) { um[c] = 0.f; uy[c] = 0.f; }
        }
        float M[9], Y[9];
        recon(um, M);
        recon(uy, Y);
        float P[9];
#pragma unroll
        for (int i = 0; i < 3; ++i)
#pragma unroll
            for (int j = 0; j < 3; ++j) {
                float s = 0.f;
#pragma unroll
                for (int k = 0; k < 3; ++k)
                    s += M[i * 3 + k] * Y[k * 3 + j] + Y[i * 3 + k] * M[k * 3 + j];
                P[i * 3 + j] = s;
            }
        float sc = s_sc[node];
        float nrm = 0.f;
#pragma unroll
        for (int i = 0; i < 9; ++i) { P[i] *= sc; nrm += P[i] * P[i]; }
        float inv = 1.0f / (nrm + 1.0f);
        float lam = (P[0] + P[4] + P[8]) * (1.f / 3.f);
        int f = idx & 63;
        u2l[(0 * 32 + node) * 72 + f] = __float2half(lam * inv);
        u2l[(1 * 32 + node) * 72 + f] = __float2half(0.5f * (P[1] - P[3]) * inv);
        u2l[(2 * 32 + node) * 72 + f] = __float2half(0.5f * (P[2] - P[6]) * inv);
        u2l[(3 * 32 + node) * 72 + f] = __float2half(0.5f * (P[5] - P[7]) * inv);
        u2l[(4 * 32 + node) * 72 + f] = __float2half((P[0] - lam) * inv);
        u2l[(5 * 32 + node) * 72 + f] = __float2half(0.5f * (P[1] + P[3]) * inv);
        u2l[(6 * 32 + node) * 72 + f] = __float2half(0.5f * (P[2] + P[6]) * inv);
        u2l[(7 * 32 + node) * 72 + f] = __float2half((P[4] - lam) * inv);
        u2l[(8 * 32 + node) * 72 + f] = __float2half(0.5f * (P[5] + P[7]) * inv);
    }
    __syncthreads();

    // ---- phase 2: GEMM (18 combos)
    int w = tid >> 6, lane = tid & 63;
    int l15 = lane & 15, lg = lane >> 4;
    const f32x4 z = {0.f, 0.f, 0.f, 0.f};
    f32x4 acc[5][4];
#pragma unroll
    for (int q = 0; q < 5; ++q) {
        int cm = w + q * 4;
        if (cm < 18) {
            int c = cm >> 1, rt = cm & 1;
            int gsel = (c == 0) ? 0 : (c < 4 ? 1 : 2);
            const f16x8* WFc = (const f16x8*)(Wfrag + gsel * WLFRAG);
            int abase = (c * 32 + rt * 16 + l15) * 72;
            f16x8 a0 = *(const f16x8*)&u2l[abase + lg * 8];
            f16x8 a1 = *(const f16x8*)&u2l[abase + 32 + lg * 8];
#pragma unroll
            for (int ct = 0; ct < 4; ++ct) {
                acc[q][ct] = __builtin_amdgcn_mfma_f32_16x16x32_f16(a0, WFc[(ct * 2 + 0) * 64 + lane], z, 0, 0, 0);
                acc[q][ct] = __builtin_amdgcn_mfma_f32_16x16x32_f16(a1, WFc[(ct * 2 + 1) * 64 + lane], acc[q][ct], 0, 0, 0);
            }
        }
    }
    __syncthreads();
#pragma unroll
    for (int q = 0; q < 5; ++q) {
        int cm = w + q * 4;
        if (cm < 18) {
            int c = cm >> 1, rt = cm & 1;
#pragma unroll
            for (int ct = 0; ct < 4; ++ct)
#pragma unroll
                for (int r = 0; r < 4; ++r)
                    u2l[(c * 32 + rt * 16 + lg * 4 + r) * 72 + ct * 16 + l15] =
                        __float2half(acc[q][ct][r]);
        }
    }
    __syncthreads();

    // ---- phase 3: out = Xn + dX + sc*dX@dX
    for (int e = 0; e < 8; ++e) {
        int idx = e * 256 + tid;
        int node = idx >> 6;
        int n = n0 + node;
        if (n >= N) continue;
        int f = idx & 63;
        float v[9];
#pragma unroll
        for (int c = 0; c < 9; ++c)
            v[c] = __half2float(u2l[(c * 32 + node) * 72 + f]);
        float dX[9];
        recon(v, dX);
        const float* xp = X + (size_t)n * 576 + f * 9;
        float m[9]; float n2 = 0.f;
#pragma unroll
        for (int i = 0; i < 9; ++i) { m[i] = xp[i]; n2 += m[i] * m[i]; }
        float invn = 1.0f / (n2 + 1.0f);
#pragma unroll
        for (int i = 0; i < 9; ++i) m[i] *= invn;
        float sc = s_sc[node];
        float* op = out + (size_t)n * 576 + f * 9;
#pragma unroll
        for (int i = 0; i < 3; ++i)
#pragma unroll
            for (int j = 0; j < 3; ++j) {
                float s = 0.f;
#pragma unroll
                for (int k = 0; k < 3; ++k) s += dX[i * 3 + k] * dX[k * 3 + j];
                op[i * 3 + j] = m[i * 3 + j] + dX[i * 3 + j] + sc * s;
            }
    }
}

// ---------------------------------------------------------------------------
extern "C" void kernel_launch(void* const* d_in, const int* in_sizes, int n_in,
                              void* d_out, int out_size, void* d_ws, size_t ws_size,
                              hipStream_t stream)
{
    const float* X       = (const float*)d_in[0];
    const int*   pair    = (const int*)d_in[1];
    const float* dij     = (const float*)d_in[2];
    const float* radial  = (const float*)d_in[3];
    const float* charges = (const float*)d_in[4];
    const float* W1  = (const float*)d_in[5];
    const float* b1  = (const float*)d_in[6];
    const float* W2  = (const float*)d_in[7];
    const float* b2  = (const float*)d_in[8];
    const float* W3  = (const float*)d_in[9];
    const float* b3  = (const float*)d_in[10];
    const float* Wl0 = (const float*)d_in[11];
    const float* Wl1 = (const float*)d_in[12];
    const float* Wl2 = (const float*)d_in[13];
    const float* Wl3 = (const float*)d_in[14];
    const float* Wl4 = (const float*)d_in[15];
    const float* Wl5 = (const float*)d_in[16];

    int N = in_sizes[4];
    int E = in_sizes[2];
    int nb_edge = (E + 63) / 64;
    int nb_node32 = (N + 31) / 32;
    size_t slab = (size_t)N * 64;
    size_t slab9 = slab * 9;

    float* B = (float*)d_ws;                   // msg (fp32)
    __half2* TgP = (__half2*)(B + slab9);      // 3 slabs of half2
    uint2* Tg456 = (uint2*)((__half*)TgP + 6 * slab);
    __half* Wf  = (__half*)(Tg456 + slab);
    int* ints   = (int*)(Wf + MLPFRAGS + 6 * WLFRAG);
    int* count  = ints;
    int* off    = count + N;
    int* cursor = off + N + 1;
    int* eOf    = cursor + N;
    int* dstp   = eOf + E;
    int* srcp   = dstp + E;

    hipMemsetAsync(count, 0, (size_t)N * sizeof(int), stream);
    hipMemsetAsync(B, 0, slab9 * sizeof(float), stream);

    int nWf = MLPFRAGS + 6 * WLFRAG;
    k_wcvt<<<(nWf + 255) / 256, 256, 0, stream>>>(W1, W2, W3,
                                                  Wl0, Wl1, Wl2, Wl3, Wl4, Wl5, Wf);
    k_head<<<nb_node32, 256, 0, stream>>>(X, Wf + MLPFRAGS, TgP, Tg456, N);

    k_hist<<<(E + 255) / 256, 256, 0, stream>>>(pair, count, E);
    k_scan<<<1, 1024, 0, stream>>>(count, off, cursor, N, E);
    k_scatter_sort<<<(E + 255) / 256, 256, 0, stream>>>(pair, cursor, eOf, dstp, srcp, E);

    k_edge_sorted<<<nb_edge, 256, 0, stream>>>(radial, dij, eOf, dstp, srcp,
                                               Wf, b1, b2, b3, TgP, Tg456, B, E, N);

    k_tail<<<nb_node32, 256, 0, stream>>>(B, TgP, Tg456, X, charges,
                                          Wf + MLPFRAGS + 3 * WLFRAG,
                                          (float*)d_out, N);
}

// Round 12
// 395.439 us; speedup vs baseline: 1.7300x; 1.0482x over previous
//
#include <hip/hip_runtime.h>
#include <hip/hip_fp16.h>
#include <math.h>

#ifndef M_PI
#define M_PI 3.14159265358979323846
#endif

// ---------------------------------------------------------------------------
// TensorNet interaction. fp32 math, fp16 LDS/gather/msg tensors, MFMA GEMMs.
// Compressed irreducible rep per (n,f): u[9] =
//   { lam, a01, a02, a12, s00, s01, s02, s11, s12 }   (s22 = -s00-s11)
//
// ws (~71 MB): msgP (5 fp16-pair slabs), TgP (3 fp16 comp-pair slabs),
// Tg456 (packed half4), Wf (fp16 MFMA frags), esd (packed edge recs), ints.
//
// Round-12 = round-11 with the fp16 pair atomic emitted via inline asm
// (global_atomic_pk_add_f16) since ROCm has no atomicAdd(__half2*) overload.
// ---------------------------------------------------------------------------

typedef _Float16 f16x8 __attribute__((ext_vector_type(8)));
typedef float f32x4 __attribute__((ext_vector_type(4)));

#define AROW 216        // halfs per activation row (432 B = 27*16)
#define MLPFRAGS 34816  // 68 frags * 512 halfs
#define WLFRAG 4096     // halfs per Wl matrix (8 frags * 512)

__device__ __forceinline__ float silu_f(float x) {
    return x / (1.0f + __expf(-x));
}

// HW packed-fp16 atomic add (no atomicAdd(__half2*) overload in ROCm 7.2)
__device__ __forceinline__ void pk_add_f16(__half2* addr, __half2 val) {
    asm volatile("global_atomic_pk_add_f16 %0, %1, off"
                 :: "v"(addr), "v"(val) : "memory");
}

__device__ __forceinline__ void recon(const float u[9], float M[9]) {
    M[0] =  u[0] + u[4];
    M[1] =  u[1] + u[5];
    M[2] =  u[2] + u[6];
    M[3] = -u[1] + u[5];
    M[4] =  u[0] + u[7];
    M[5] =  u[3] + u[8];
    M[6] = -u[2] + u[6];
    M[7] = -u[3] + u[8];
    M[8] =  u[0] - u[4] - u[7];
}

// ---------------------------------------------------------------------------
// Weight -> fp16 MFMA-fragment conversion (once per launch).
// Fragment element (lane l, j) = W[ct*16+(l&15)][ks*32+(l>>4)*8+j].
// ---------------------------------------------------------------------------
__global__ __launch_bounds__(256) void k_wcvt(
    const float* __restrict__ W1, const float* __restrict__ W2,
    const float* __restrict__ W3,
    const float* __restrict__ Wl0, const float* __restrict__ Wl1,
    const float* __restrict__ Wl2, const float* __restrict__ Wl3,
    const float* __restrict__ Wl4, const float* __restrict__ Wl5,
    __half* __restrict__ Wf)
{
    int idx = blockIdx.x * 256 + threadIdx.x;
    if (idx >= MLPFRAGS + 6 * WLFRAG) return;
    float v;
    if (idx < MLPFRAGS) {
        int frag = idx >> 9;
        int r = idx & 511;
        int l = r >> 3, j = r & 7;
        int l15 = l & 15, lg = l >> 4;
        if (frag < 4) {
            int ct = frag;
            v = W1[(ct * 16 + l15) * 32 + (lg * 8 + j)];
        } else if (frag < 20) {
            int f2 = frag - 4;
            int ct = f2 >> 1, ks = f2 & 1;
            v = W2[(ct * 16 + l15) * 64 + (ks * 32 + lg * 8 + j)];
        } else {
            int f3 = frag - 20;
            int ct = f3 >> 2, ks = f3 & 3;
            v = W3[(ct * 16 + l15) * 128 + (ks * 32 + lg * 8 + j)];
        }
    } else {
        int r2 = idx - MLPFRAGS;
        int wIdx = r2 >> 12;           // /4096
        int rr = r2 & 4095;
        int f = rr >> 9;               // ct*2+ks
        int ct = f >> 1, ks = f & 1;
        int elem = rr & 511;
        int l = elem >> 3, j = elem & 7;
        int l15 = l & 15, lg = l >> 4;
        const float* W = (wIdx == 0) ? Wl0 : (wIdx == 1) ? Wl1 : (wIdx == 2) ? Wl2
                       : (wIdx == 3) ? Wl3 : (wIdx == 4) ? Wl4 : Wl5;
        v = W[(ct * 16 + l15) * 64 + (ks * 32 + lg * 8 + j)];
    }
    Wf[idx] = __float2half(v);
}

// ---------------------------------------------------------------------------
// K_HEAD: fused node_prep + comp-GEMM#1 + T-convert. 32 nodes per block.
// ---------------------------------------------------------------------------
__global__ __launch_bounds__(256) void k_head(
    const float* __restrict__ X, const __half* __restrict__ Wfrag,
    __half2* __restrict__ TgP, uint2* __restrict__ Tg456, int N)
{
    __shared__ __half u2l[9 * 32 * 72];   // 41.5 KB
    __shared__ float s_x[2304];           // 9.2 KB (4 nodes)
    int tid = threadIdx.x;
    int n0 = blockIdx.x * 32;
    size_t total = (size_t)N * 576;

    // ---- phase 1: prep 8 chunks of 4 nodes
    for (int ch = 0; ch < 8; ++ch) {
        size_t base = (size_t)(n0 + ch * 4) * 576;
        for (int idx = tid; idx < 2304; idx += 256) {
            size_t gi = base + idx;
            s_x[idx] = (gi < total) ? X[gi] : 0.f;
        }
        __syncthreads();
        int w = tid >> 6, f = tid & 63;
        int node = ch * 4 + w;
        float m[9]; float n2 = 0.f;
#pragma unroll
        for (int i = 0; i < 9; ++i) { m[i] = s_x[w * 576 + f * 9 + i]; n2 += m[i] * m[i]; }
        float inv = 1.0f / (n2 + 1.0f);
#pragma unroll
        for (int i = 0; i < 9; ++i) m[i] *= inv;
        float lam = (m[0] + m[4] + m[8]) * (1.f / 3.f);
        u2l[(0 * 32 + node) * 72 + f] = __float2half(lam);
        u2l[(1 * 32 + node) * 72 + f] = __float2half(0.5f * (m[1] - m[3]));
        u2l[(2 * 32 + node) * 72 + f] = __float2half(0.5f * (m[2] - m[6]));
        u2l[(3 * 32 + node) * 72 + f] = __float2half(0.5f * (m[5] - m[7]));
        u2l[(4 * 32 + node) * 72 + f] = __float2half(m[0] - lam);
        u2l[(5 * 32 + node) * 72 + f] = __float2half(0.5f * (m[1] + m[3]));
        u2l[(6 * 32 + node) * 72 + f] = __float2half(0.5f * (m[2] + m[6]));
        u2l[(7 * 32 + node) * 72 + f] = __float2half(m[4] - lam);
        u2l[(8 * 32 + node) * 72 + f] = __float2half(0.5f * (m[5] + m[7]));
        __syncthreads();
    }

    // ---- phase 2: GEMM (18 combos = comp c x row-tile rt), in-place
    int w = tid >> 6, lane = tid & 63;
    int l15 = lane & 15, lg = lane >> 4;
    const f32x4 z = {0.f, 0.f, 0.f, 0.f};
    f32x4 acc[5][4];
#pragma unroll
    for (int q = 0; q < 5; ++q) {
        int cm = w + q * 4;
        if (cm < 18) {
            int c = cm >> 1, rt = cm & 1;
            int gsel = (c == 0) ? 0 : (c < 4 ? 1 : 2);
            const f16x8* WFc = (const f16x8*)(Wfrag + gsel * WLFRAG);
            int abase = (c * 32 + rt * 16 + l15) * 72;
            f16x8 a0 = *(const f16x8*)&u2l[abase + lg * 8];
            f16x8 a1 = *(const f16x8*)&u2l[abase + 32 + lg * 8];
#pragma unroll
            for (int ct = 0; ct < 4; ++ct) {
                acc[q][ct] = __builtin_amdgcn_mfma_f32_16x16x32_f16(a0, WFc[(ct * 2 + 0) * 64 + lane], z, 0, 0, 0);
                acc[q][ct] = __builtin_amdgcn_mfma_f32_16x16x32_f16(a1, WFc[(ct * 2 + 1) * 64 + lane], acc[q][ct], 0, 0, 0);
            }
        }
    }
    __syncthreads();
#pragma unroll
    for (int q = 0; q < 5; ++q) {
        int cm = w + q * 4;
        if (cm < 18) {
            int c = cm >> 1, rt = cm & 1;
#pragma unroll
            for (int ct = 0; ct < 4; ++ct)
#pragma unroll
                for (int r = 0; r < 4; ++r)
                    u2l[(c * 32 + rt * 16 + lg * 4 + r) * 72 + ct * 16 + l15] =
                        __float2half(acc[q][ct][r]);
        }
    }
    __syncthreads();

    // ---- phase 3: write gather layouts
    size_t slab = (size_t)N * 64;
    for (int e = 0; e < 8; ++e) {
        int idx = e * 256 + tid;
        int node = idx >> 6;
        int n = n0 + node;
        if (n >= N) continue;
        int f = idx & 63;
        size_t t = (size_t)n * 64 + f;
        const int pa[3] = {0, 2, 7};
#pragma unroll
        for (int pr = 0; pr < 3; ++pr) {
            __half a = u2l[(pa[pr] * 32 + node) * 72 + f];
            __half b = u2l[((pa[pr] + 1) * 32 + node) * 72 + f];
            TgP[(size_t)pr * slab + t] = __halves2half2(a, b);
        }
        __half2 lo = __halves2half2(u2l[(4 * 32 + node) * 72 + f],
                                    u2l[(5 * 32 + node) * 72 + f]);
        __half2 hi = __halves2half2(u2l[(6 * 32 + node) * 72 + f], __float2half(0.f));
        uint2 pk;
        pk.x = *(unsigned int*)&lo;
        pk.y = *(unsigned int*)&hi;
        Tg456[t] = pk;
    }
}

// ---------------------------------------------------------------------------
// CSR sort of edges by src: histogram -> scan -> ranked placement.
// ---------------------------------------------------------------------------
__global__ __launch_bounds__(256) void k_hist(
    const int* __restrict__ pair, int* __restrict__ count, int E)
{
    int e = blockIdx.x * 256 + threadIdx.x;
    if (e < E) atomicAdd(&count[pair[e]], 1);
}

__global__ __launch_bounds__(1024) void k_scan(
    const int* __restrict__ count, int* __restrict__ off,
    int* __restrict__ cursor, int N, int E)
{
    __shared__ int s[1024];
    __shared__ int s_carry;
    int tid = threadIdx.x;
    if (tid == 0) s_carry = 0;
    __syncthreads();
    const int CH = 32;
    for (int base = 0; base < N; base += 1024 * CH) {
        int b0 = base + tid * CH;
        int local[CH]; int sum = 0;
#pragma unroll
        for (int i = 0; i < CH; ++i) {
            int idx = b0 + i;
            int v = (idx < N) ? count[idx] : 0;
            local[i] = sum; sum += v;
        }
        s[tid] = sum;
        __syncthreads();
        for (int d = 1; d < 1024; d <<= 1) {
            int t2 = (tid >= d) ? s[tid - d] : 0;
            __syncthreads();
            s[tid] += t2;
            __syncthreads();
        }
        int excl0 = s_carry + s[tid] - sum;
#pragma unroll
        for (int i = 0; i < CH; ++i) {
            int idx = b0 + i;
            if (idx < N) { int e = excl0 + local[i]; off[idx] = e; cursor[idx] = e; }
        }
        __syncthreads();
        if (tid == 1023) s_carry += s[1023];
        __syncthreads();
    }
    if (tid == 0) off[N] = E;
}

// Packed edge record per sorted position: {src, dst*64, eOrig, C bits}
__global__ __launch_bounds__(256) void k_scatter_sort(
    const int* __restrict__ pair, const float* __restrict__ d_ij,
    int* __restrict__ cursor, uint4* __restrict__ esd, int E)
{
    int e = blockIdx.x * 256 + threadIdx.x;
    if (e < E) {
        int s = pair[e];
        int d = pair[(size_t)E + e];
        float dd = d_ij[e];
        float C = (dd < 5.0f) ? 0.5f * (cosf((float)M_PI * dd * 0.2f) + 1.0f) : 0.0f;
        int pos = atomicAdd(&cursor[s], 1);
        uint4 v;
        v.x = (unsigned int)s;
        v.y = (unsigned int)(d * 64);
        v.z = (unsigned int)e;
        v.w = __float_as_uint(C);
        esd[pos] = v;
    }
}

// ---------------------------------------------------------------------------
// K2: fused edge MLP on MFMA + 4-stream, depth-2-prefetch message pass.
// msg stored as fp16 pairs: slabs {0:(0,1), 1:(2,3), 2:(7,8), 3:(4,5),
// 4:(6,pad)}; flush = one half2 store / pk_add_f16 atomic.
// ---------------------------------------------------------------------------
__global__ __launch_bounds__(256) void k_edge_sorted(
    const float* __restrict__ radial, const uint4* __restrict__ esd,
    const __half* __restrict__ Wf,
    const float* __restrict__ b1, const float* __restrict__ b2,
    const float* __restrict__ b3,
    const __half2* __restrict__ TgP, const uint2* __restrict__ Tg456,
    __half2* __restrict__ msgP, int E, int N)
{
    __shared__ __half s_act[64 * AROW];
    __shared__ float s_C[64];
    __shared__ int s_e[64];
    __shared__ int s_src[64];
    __shared__ int s_dst[64];    // PRE-MULTIPLIED by 64 (element offset)
    int tid = threadIdx.x;
    int p0 = blockIdx.x * 64;

    if (tid < 64) {
        int p = p0 + tid;
        int e = -1, s = 0, d64 = 0; float C = 0.f;
        if (p < E) {
            uint4 v = esd[p];
            s = (int)v.x; d64 = (int)v.y; e = (int)v.z; C = __uint_as_float(v.w);
        }
        s_e[tid] = e; s_src[tid] = s; s_dst[tid] = d64; s_C[tid] = C;
    }
    __syncthreads();

    {   // stage rbf: s_act[j][k], fp16
        int j = tid >> 2;
        int kk = (tid & 3) * 8;
        int e = s_e[j];
        float4 v0 = make_float4(0.f, 0.f, 0.f, 0.f), v1 = v0;
        if (e >= 0) {
            v0 = *(const float4*)(radial + (size_t)e * 32 + kk);
            v1 = *(const float4*)(radial + (size_t)e * 32 + kk + 4);
        }
        __half2* dst = (__half2*)&s_act[j * AROW + kk];
        dst[0] = __floats2half2_rn(v0.x, v0.y);
        dst[1] = __floats2half2_rn(v0.z, v0.w);
        dst[2] = __floats2half2_rn(v1.x, v1.y);
        dst[3] = __floats2half2_rn(v1.z, v1.w);
    }
    __syncthreads();

    int w = tid >> 6;
    int lane = tid & 63;
    int l15 = lane & 15, lg = lane >> 4;
    const int row0 = w * 16;
    const int arow = (row0 + l15) * AROW;
    const int orow = (row0 + lg * 4) * AROW;
    const f16x8* WF = (const f16x8*)Wf;
    const f32x4 zacc = {0.f, 0.f, 0.f, 0.f};

    // ---- layer 1: 32 -> 64
    {
        f16x8 a = *(const f16x8*)&s_act[arow + lg * 8];
        f32x4 acc[4];
#pragma unroll
        for (int ct = 0; ct < 4; ++ct)
            acc[ct] = __builtin_amdgcn_mfma_f32_16x16x32_f16(a, WF[ct * 64 + lane], zacc, 0, 0, 0);
        __syncthreads();
#pragma unroll
        for (int ct = 0; ct < 4; ++ct) {
            int o = ct * 16 + l15;
            float bias = b1[o];
#pragma unroll
            for (int r = 0; r < 4; ++r)
                s_act[orow + r * AROW + o] = __float2half(silu_f(acc[ct][r] + bias));
        }
        __syncthreads();
    }

    // ---- layer 2: 64 -> 128
    {
        f16x8 a0 = *(const f16x8*)&s_act[arow + 0 * 32 + lg * 8];
        f16x8 a1 = *(const f16x8*)&s_act[arow + 1 * 32 + lg * 8];
        f32x4 acc[8];
#pragma unroll
        for (int ct = 0; ct < 8; ++ct) {
            acc[ct] = __builtin_amdgcn_mfma_f32_16x16x32_f16(a0, WF[(4 + ct * 2 + 0) * 64 + lane], zacc, 0, 0, 0);
            acc[ct] = __builtin_amdgcn_mfma_f32_16x16x32_f16(a1, WF[(4 + ct * 2 + 1) * 64 + lane], acc[ct], 0, 0, 0);
        }
        __syncthreads();
#pragma unroll
        for (int ct = 0; ct < 8; ++ct) {
            int o = ct * 16 + l15;
            float bias = b2[o];
#pragma unroll
            for (int r = 0; r < 4; ++r)
                s_act[orow + r * AROW + o] = __float2half(silu_f(acc[ct][r] + bias));
        }
        __syncthreads();
    }

    // ---- layer 3: 128 -> 192 (raw col o -> stored col (o%3)*64 + o/3)
    {
        f16x8 a[4];
#pragma unroll
        for (int ks = 0; ks < 4; ++ks)
            a[ks] = *(const f16x8*)&s_act[arow + ks * 32 + lg * 8];
        float Cr[4];
#pragma unroll
        for (int r = 0; r < 4; ++r) Cr[r] = s_C[row0 + lg * 4 + r];
        __syncthreads();
#pragma unroll
        for (int ct = 0; ct < 12; ++ct) {
            f32x4 acc = zacc;
#pragma unroll
            for (int ks = 0; ks < 4; ++ks)
                acc = __builtin_amdgcn_mfma_f32_16x16x32_f16(a[ks], WF[(20 + ct * 4 + ks) * 64 + lane], acc, 0, 0, 0);
            int o = ct * 16 + l15;
            float bias = b3[o];
            int f = o / 3;
            int cmp = o - f * 3;
            int col = cmp * 64 + f;
#pragma unroll
            for (int r = 0; r < 4; ++r)
                s_act[orow + r * AROW + col] = __float2half(silu_f(acc[r] + bias) * Cr[r]);
        }
        __syncthreads();
    }

    // ---- message pass: 4 streams/wave, prefetch depth 2 (8 loads in flight)
    {
        int wv = __builtin_amdgcn_readfirstlane(w);
        size_t slab = (size_t)N * 64;
        int jmax = min(64, E - p0);

        if (wv == 2) {
            // comps {4,5,6} via ONE uint2 (half4) load; rf2 at col 128+lane
            const uint2* T4 = Tg456;
            auto flush3 = [&](int cur, int gs, int ge, float a0, float a1, float a2) {
                bool lb = (gs == 0) || ((int)esd[gs - 1].x != cur);
                bool rb = (ge >= E) || ((int)esd[ge].x != cur);
                size_t b = (size_t)cur * 64 + lane;
                __half2 h45 = __floats2half2_rn(a0, a1);
                __half2 h6  = __floats2half2_rn(a2, 0.f);
                if (lb && rb) {
                    msgP[3 * slab + b] = h45;
                    msgP[4 * slab + b] = h6;
                } else {
                    pk_add_f16(&msgP[3 * slab + b], h45);
                    pk_add_f16(&msgP[4 * slab + b], h6);
                }
            };
            float A00 = 0.f, A01 = 0.f, A02 = 0.f, A10 = 0.f, A11 = 0.f, A12 = 0.f;
            float A20 = 0.f, A21 = 0.f, A22 = 0.f, A30 = 0.f, A31 = 0.f, A32 = 0.f;
            int cur0 = -1, cur1 = -1, cur2 = -1, cur3 = -1;
            int js0 = 0, js1 = 0, js2 = 0, js3 = 0;
            uint2 ta0 = make_uint2(0, 0), ta1 = ta0, ta2 = ta0, ta3 = ta0;
            uint2 tb0 = ta0, tb1 = ta0, tb2 = ta0, tb3 = ta0;
            if (0 < jmax)  ta0 = T4[(size_t)s_dst[0]  + lane];
            if (16 < jmax) ta1 = T4[(size_t)s_dst[16] + lane];
            if (32 < jmax) ta2 = T4[(size_t)s_dst[32] + lane];
            if (48 < jmax) ta3 = T4[(size_t)s_dst[48] + lane];
            if (1 < jmax)  tb0 = T4[(size_t)s_dst[1]  + lane];
            if (17 < jmax) tb1 = T4[(size_t)s_dst[17] + lane];
            if (33 < jmax) tb2 = T4[(size_t)s_dst[33] + lane];
            if (49 < jmax) tb3 = T4[(size_t)s_dst[49] + lane];
#define MS3(BASE, CUR, JS, A0, A1, A2, TVA, TVB) { \
            int j = (BASE) + t; \
            if (j < jmax) { \
                uint2 tvc = TVA; TVA = TVB; \
                int jn = j + 2; \
                if (jn < (BASE) + 16 && jn < jmax) \
                    TVB = T4[(size_t)s_dst[jn] + lane]; \
                int s = __builtin_amdgcn_readfirstlane(s_src[j]); \
                if (s != CUR) { if (CUR >= 0) flush3(CUR, p0 + JS, p0 + j, A0, A1, A2); \
                                CUR = s; JS = j; A0 = 0.f; A1 = 0.f; A2 = 0.f; } \
                float rf = __half2float(s_act[j * AROW + 128 + lane]); \
                float2 lof = __half22float2(*(__half2*)&tvc.x); \
                __half2 hic = *(__half2*)&tvc.y; \
                A0 += rf * lof.x; A1 += rf * lof.y; \
                A2 += rf * __half2float(hic.x); \
            } }
            for (int t = 0; t < 16; ++t) {
                MS3(0,  cur0, js0, A00, A01, A02, ta0, tb0)
                MS3(16, cur1, js1, A10, A11, A12, ta1, tb1)
                MS3(32, cur2, js2, A20, A21, A22, ta2, tb2)
                MS3(48, cur3, js3, A30, A31, A32, ta3, tb3)
            }
#undef MS3
            if (cur0 >= 0) flush3(cur0, p0 + js0, p0 + min(16, jmax), A00, A01, A02);
            if (cur1 >= 0) flush3(cur1, p0 + js1, p0 + min(32, jmax), A10, A11, A12);
            if (cur2 >= 0) flush3(cur2, p0 + js2, p0 + min(48, jmax), A20, A21, A22);
            if (cur3 >= 0) flush3(cur3, p0 + js3, p0 + min(64, jmax), A30, A31, A32);
        } else {
            // TgP slab & msg slab: wave0 -> 0 {0,1}, wave1 -> 1 {2,3},
            // wave3 -> 2 {7,8}
            int sl = (wv == 0) ? 0 : ((wv == 1) ? 1 : 2);
            int offA = (wv == 0) ? lane : ((wv == 1) ? (64 + lane) : (128 + lane));
            int offB = 64 + lane;     // only used by wave0
            bool W0 = (wv == 0);
            const unsigned int* TP = (const unsigned int*)TgP + (size_t)sl * slab;
            auto flush2 = [&](int cur, int gs, int ge, float a0, float a1) {
                bool lb = (gs == 0) || ((int)esd[gs - 1].x != cur);
                bool rb = (ge >= E) || ((int)esd[ge].x != cur);
                size_t b = (size_t)cur * 64 + lane;
                __half2 hv = __floats2half2_rn(a0, a1);
                if (lb && rb) {
                    msgP[(size_t)sl * slab + b] = hv;
                } else {
                    pk_add_f16(&msgP[(size_t)sl * slab + b], hv);
                }
            };
            float A00 = 0.f, A01 = 0.f, A10 = 0.f, A11 = 0.f;
            float A20 = 0.f, A21 = 0.f, A30 = 0.f, A31 = 0.f;
            int cur0 = -1, cur1 = -1, cur2 = -1, cur3 = -1;
            int js0 = 0, js1 = 0, js2 = 0, js3 = 0;
            unsigned int ta0 = 0, ta1 = 0, ta2 = 0, ta3 = 0;
            unsigned int tb0 = 0, tb1 = 0, tb2 = 0, tb3 = 0;
            if (0 < jmax)  ta0 = TP[(size_t)s_dst[0]  + lane];
            if (16 < jmax) ta1 = TP[(size_t)s_dst[16] + lane];
            if (32 < jmax) ta2 = TP[(size_t)s_dst[32] + lane];
            if (48 < jmax) ta3 = TP[(size_t)s_dst[48] + lane];
            if (1 < jmax)  tb0 = TP[(size_t)s_dst[1]  + lane];
            if (17 < jmax) tb1 = TP[(size_t)s_dst[17] + lane];
            if (33 < jmax) tb2 = TP[(size_t)s_dst[33] + lane];
            if (49 < jmax) tb3 = TP[(size_t)s_dst[49] + lane];
#define MS2(BASE, CUR, JS, A0, A1, TVA, TVB) { \
            int j = (BASE) + t; \
            if (j < jmax) { \
                unsigned int tvc = TVA; TVA = TVB; \
                int jn = j + 2; \
                if (jn < (BASE) + 16 && jn < jmax) \
                    TVB = TP[(size_t)s_dst[jn] + lane]; \
                int s = __builtin_amdgcn_readfirstlane(s_src[j]); \
                if (s != CUR) { if (CUR >= 0) flush2(CUR, p0 + JS, p0 + j, A0, A1); \
                                CUR = s; JS = j; A0 = 0.f; A1 = 0.f; } \
                float2 tvf = __half22float2(*(__half2*)&tvc); \
                float rfA = __half2float(s_act[j * AROW + offA]); \
                float rfB = W0 ? __half2float(s_act[j * AROW + offB]) : rfA; \
                A0 += rfA * tvf.x; A1 += rfB * tvf.y; \
            } }
            for (int t = 0; t < 16; ++t) {
                MS2(0,  cur0, js0, A00, A01, ta0, tb0)
                MS2(16, cur1, js1, A10, A11, ta1, tb1)
                MS2(32, cur2, js2, A20, A21, ta2, tb2)
                MS2(48, cur3, js3, A30, A31, ta3, tb3)
            }
#undef MS2
            if (cur0 >= 0) flush2(cur0, p0 + js0, p0 + min(16, jmax), A00, A01);
            if (cur1 >= 0) flush2(cur1, p0 + js1, p0 + min(32, jmax), A10, A11);
            if (cur2 >= 0) flush2(cur2, p0 + js2, p0 + min(48, jmax), A20, A21);
            if (cur3 >= 0) flush2(cur3, p0 + js3, p0 + min(64, jmax), A30, A31);
        }
    }
}

// ---------------------------------------------------------------------------
// K_TAIL: fused node_mix + comp-GEMM#2 + out. 32 nodes per block.
// msg read from fp16 pair slabs; Y from TgP/Tg456.
// ---------------------------------------------------------------------------
__global__ __launch_bounds__(256) void k_tail(
    const __half2* __restrict__ msgP,
    const __half2* __restrict__ TgP, const uint2* __restrict__ Tg456,
    const float* __restrict__ X, const float* __restrict__ charges,
    const __half* __restrict__ Wfrag, float* __restrict__ out, int N)
{
    __shared__ __half u2l[9 * 32 * 72];   // 41.5 KB
    __shared__ float s_sc[32];
    int tid = threadIdx.x;
    int n0 = blockIdx.x * 32;
    size_t slab = (size_t)N * 64;

    if (tid < 32) {
        int n = n0 + tid;
        s_sc[tid] = (n < N) ? 1.0f + 0.1f * charges[n] : 0.f;
    }
    __syncthreads();

    // ---- phase 1: node mix
    for (int e = 0; e < 8; ++e) {
        int idx = e * 256 + tid;          // 0..2047
        int node = idx >> 6;
        int n = n0 + node;
        float um[9], uy[9];
        if (n < N) {
            size_t t = (size_t)n0 * 64 + idx;
            float2 m01 = __half22float2(msgP[0 * slab + t]);
            float2 m23 = __half22float2(msgP[1 * slab + t]);
            float2 m78 = __half22float2(msgP[2 * slab + t]);
            float2 m45 = __half22float2(msgP[3 * slab + t]);
            float2 m6_ = __half22float2(msgP[4 * slab + t]);
            um[0] = m01.x; um[1] = m01.y;
            um[2] = m23.x; um[3] = m23.y;
            um[4] = m45.x; um[5] = m45.y;
            um[6] = m6_.x;
            um[7] = m78.x; um[8] = m78.y;
            float2 p0 = __half22float2(TgP[0 * slab + t]);
            float2 p1 = __half22float2(TgP[1 * slab + t]);
            float2 p2 = __half22float2(TgP[2 * slab + t]);
            uint2 q = Tg456[t];
            float2 q0 = __half22float2(*(__half2*)&q.x);
            __half2 q1 = *(__half2*)&q.y;
            uy[0] = p0.x; uy[1] = p0.y;
            uy[2] = p1.x; uy[3] = p1.y;
            uy[4] = q0.x; uy[5] = q0.y;
            uy[6] = __half2float(q1.x);
            uy[7] = p2.x; uy[8] = p2.y;
        } else {
#pragma unroll
            for (int c = 0; c < 9; ++c) { um[c] = 0.f; uy[c] = 0.f; }
        }
        float M[9], Y[9];
        recon(um, M);
        recon(uy, Y);
        float P[9];
#pragma unroll
        for (int i = 0; i < 3; ++i)
#pragma unroll
            for (int j = 0; j < 3; ++j) {
                float s = 0.f;
#pragma unroll
                for (int k = 0; k < 3; ++k)
                    s += M[i * 3 + k] * Y[k * 3 + j] + Y[i * 3 + k] * M[k * 3 + j];
                P[i * 3 + j] = s;
            }
        float sc = s_sc[node];
        float nrm = 0.f;
#pragma unroll
        for (int i = 0; i < 9; ++i) { P[i] *= sc; nrm += P[i] * P[i]; }
        float inv = 1.0f / (nrm + 1.0f);
        float lam = (P[0] + P[4] + P[8]) * (1.f / 3.f);
        int f = idx & 63;
        u2l[(0 * 32 + node) * 72 + f] = __float2half(lam * inv);
        u2l[(1 * 32 + node) * 72 + f] = __float2half(0.5f * (P[1] - P[3]) * inv);
        u2l[(2 * 32 + node) * 72 + f] = __float2half(0.5f * (P[2] - P[6]) * inv);
        u2l[(3 * 32 + node) * 72 + f] = __float2half(0.5f * (P[5] - P[7]) * inv);
        u2l[(4 * 32 + node) * 72 + f] = __float2half((P[0] - lam) * inv);
        u2l[(5 * 32 + node) * 72 + f] = __float2half(0.5f * (P[1] + P[3]) * inv);
        u2l[(6 * 32 + node) * 72 + f] = __float2half(0.5f * (P[2] + P[6]) * inv);
        u2l[(7 * 32 + node) * 72 + f] = __float2half((P[4] - lam) * inv);
        u2l[(8 * 32 + node) * 72 + f] = __float2half(0.5f * (P[5] + P[7]) * inv);
    }
    __syncthreads();

    // ---- phase 2: GEMM (18 combos)
    int w = tid >> 6, lane = tid & 63;
    int l15 = lane & 15, lg = lane >> 4;
    const f32x4 z = {0.f, 0.f, 0.f, 0.f};
    f32x4 acc[5][4];
#pragma unroll
    for (int q = 0; q < 5; ++q) {
        int cm = w + q * 4;
        if (cm < 18) {
            int c = cm >> 1, rt = cm & 1;
            int gsel = (c == 0) ? 0 : (c < 4 ? 1 : 2);
            const f16x8* WFc = (const f16x8*)(Wfrag + gsel * WLFRAG);
            int abase = (c * 32 + rt * 16 + l15) * 72;
            f16x8 a0 = *(const f16x8*)&u2l[abase + lg * 8];
            f16x8 a1 = *(const f16x8*)&u2l[abase + 32 + lg * 8];
#pragma unroll
            for (int ct = 0; ct < 4; ++ct) {
                acc[q][ct] = __builtin_amdgcn_mfma_f32_16x16x32_f16(a0, WFc[(ct * 2 + 0) * 64 + lane], z, 0, 0, 0);
                acc[q][ct] = __builtin_amdgcn_mfma_f32_16x16x32_f16(a1, WFc[(ct * 2 + 1) * 64 + lane], acc[q][ct], 0, 0, 0);
            }
        }
    }
    __syncthreads();
#pragma unroll
    for (int q = 0; q < 5; ++q) {
        int cm = w + q * 4;
        if (cm < 18) {
            int c = cm >> 1, rt = cm & 1;
#pragma unroll
            for (int ct = 0; ct < 4; ++ct)
#pragma unroll
                for (int r = 0; r < 4; ++r)
                    u2l[(c * 32 + rt * 16 + lg * 4 + r) * 72 + ct * 16 + l15] =
                        __float2half(acc[q][ct][r]);
        }
    }
    __syncthreads();

    // ---- phase 3: out = Xn + dX + sc*dX@dX
    for (int e = 0; e < 8; ++e) {
        int idx = e * 256 + tid;
        int node = idx >> 6;
        int n = n0 + node;
        if (n >= N) continue;
        int f = idx & 63;
        float v[9];
#pragma unroll
        for (int c = 0; c < 9; ++c)
            v[c] = __half2float(u2l[(c * 32 + node) * 72 + f]);
        float dX[9];
        recon(v, dX);
        const float* xp = X + (size_t)n * 576 + f * 9;
        float m[9]; float n2 = 0.f;
#pragma unroll
        for (int i = 0; i < 9; ++i) { m[i] = xp[i]; n2 += m[i] * m[i]; }
        float invn = 1.0f / (n2 + 1.0f);
#pragma unroll
        for (int i = 0; i < 9; ++i) m[i] *= invn;
        float sc = s_sc[node];
        float* op = out + (size_t)n * 576 + f * 9;
#pragma unroll
        for (int i = 0; i < 3; ++i)
#pragma unroll
            for (int j = 0; j < 3; ++j) {
                float s = 0.f;
#pragma unroll
                for (int k = 0; k < 3; ++k) s += dX[i * 3 + k] * dX[k * 3 + j];
                op[i * 3 + j] = m[i * 3 + j] + dX[i * 3 + j] + sc * s;
            }
    }
}

// ---------------------------------------------------------------------------
extern "C" void kernel_launch(void* const* d_in, const int* in_sizes, int n_in,
                              void* d_out, int out_size, void* d_ws, size_t ws_size,
                              hipStream_t stream)
{
    const float* X       = (const float*)d_in[0];
    const int*   pair    = (const int*)d_in[1];
    const float* dij     = (const float*)d_in[2];
    const float* radial  = (const float*)d_in[3];
    const float* charges = (const float*)d_in[4];
    const float* W1  = (const float*)d_in[5];
    const float* b1  = (const float*)d_in[6];
    const float* W2  = (const float*)d_in[7];
    const float* b2  = (const float*)d_in[8];
    const float* W3  = (const float*)d_in[9];
    const float* b3  = (const float*)d_in[10];
    const float* Wl0 = (const float*)d_in[11];
    const float* Wl1 = (const float*)d_in[12];
    const float* Wl2 = (const float*)d_in[13];
    const float* Wl3 = (const float*)d_in[14];
    const float* Wl4 = (const float*)d_in[15];
    const float* Wl5 = (const float*)d_in[16];

    int N = in_sizes[4];
    int E = in_sizes[2];
    int nb_edge = (E + 63) / 64;
    int nb_node32 = (N + 31) / 32;
    size_t slab = (size_t)N * 64;

    __half2* msgP = (__half2*)d_ws;            // 5 slabs half2 (fp16 pairs)
    __half2* TgP  = msgP + 5 * slab;           // 3 slabs half2
    uint2* Tg456  = (uint2*)(TgP + 3 * slab);  // 1 slab uint2
    __half* Wf    = (__half*)(Tg456 + slab);   // 59392 halfs
    uint4* esd    = (uint4*)(Wf + MLPFRAGS + 6 * WLFRAG);
    int* ints   = (int*)(esd + E);
    int* count  = ints;
    int* off    = count + N;
    int* cursor = off + N + 1;

    hipMemsetAsync(count, 0, (size_t)N * sizeof(int), stream);
    hipMemsetAsync(msgP, 0, 5 * slab * sizeof(__half2), stream);

    int nWf = MLPFRAGS + 6 * WLFRAG;
    k_wcvt<<<(nWf + 255) / 256, 256, 0, stream>>>(W1, W2, W3,
                                                  Wl0, Wl1, Wl2, Wl3, Wl4, Wl5, Wf);
    k_head<<<nb_node32, 256, 0, stream>>>(X, Wf + MLPFRAGS, TgP, Tg456, N);

    k_hist<<<(E + 255) / 256, 256, 0, stream>>>(pair, count, E);
    k_scan<<<1, 1024, 0, stream>>>(count, off, cursor, N, E);
    k_scatter_sort<<<(E + 255) / 256, 256, 0, stream>>>(pair, dij, cursor, esd, E);

    k_edge_sorted<<<nb_edge, 256, 0, stream>>>(radial, esd,
                                               Wf, b1, b2, b3, TgP, Tg456,
                                               msgP, E, N);

    k_tail<<<nb_node32, 256, 0, stream>>>(msgP, TgP, Tg456, X, charges,
                                          Wf + MLPFRAGS + 3 * WLFRAG,
                                          (float*)d_out, N);
}

// Round 13
// 384.221 us; speedup vs baseline: 1.7805x; 1.0292x over previous
//
#include <hip/hip_runtime.h>
#include <hip/hip_fp16.h>
#include <math.h>

#ifndef M_PI
#define M_PI 3.14159265358979323846
#endif

// ---------------------------------------------------------------------------
// TensorNet interaction. fp32 math, fp16 LDS/gather/msg tensors, MFMA GEMMs.
// Compressed irreducible rep per (n,f): u[9] =
//   { lam, a01, a02, a12, s00, s01, s02, s11, s12 }   (s22 = -s00-s11)
//
// ws (~71 MB): msgP (5 fp16-pair slabs), TgP (3 fp16 comp-pair slabs),
// Tg456 (packed half4), Wf (fp16 MFMA frags), esd (packed edge recs), ints.
//
// Round-13 changes (message loop VALU cut ~2x):
//  * accumulate message partials in __half2 via __hfma2 (v_pk_fma_f16):
//    1 pk-fma replaces 2-3 cvt + 2-3 fma per comp pair.
//  * flush run-boundary checks now LDS-only (s_prev/s_next staged once;
//    src padding = -3) -> no global esd reads on the flush path.
//  * #pragma unroll 4 on the 16-iter message t-loop.
// ---------------------------------------------------------------------------

typedef _Float16 f16x8 __attribute__((ext_vector_type(8)));
typedef float f32x4 __attribute__((ext_vector_type(4)));

#define AROW 216        // halfs per activation row (432 B = 27*16)
#define MLPFRAGS 34816  // 68 frags * 512 halfs
#define WLFRAG 4096     // halfs per Wl matrix (8 frags * 512)

__device__ __forceinline__ float silu_f(float x) {
    return x / (1.0f + __expf(-x));
}

// HW packed-fp16 atomic add (no atomicAdd(__half2*) overload in ROCm 7.2)
__device__ __forceinline__ void pk_add_f16(__half2* addr, __half2 val) {
    asm volatile("global_atomic_pk_add_f16 %0, %1, off"
                 :: "v"(addr), "v"(val) : "memory");
}

__device__ __forceinline__ void recon(const float u[9], float M[9]) {
    M[0] =  u[0] + u[4];
    M[1] =  u[1] + u[5];
    M[2] =  u[2] + u[6];
    M[3] = -u[1] + u[5];
    M[4] =  u[0] + u[7];
    M[5] =  u[3] + u[8];
    M[6] = -u[2] + u[6];
    M[7] = -u[3] + u[8];
    M[8] =  u[0] - u[4] - u[7];
}

// ---------------------------------------------------------------------------
// Weight -> fp16 MFMA-fragment conversion (once per launch).
// Fragment element (lane l, j) = W[ct*16+(l&15)][ks*32+(l>>4)*8+j].
// ---------------------------------------------------------------------------
__global__ __launch_bounds__(256) void k_wcvt(
    const float* __restrict__ W1, const float* __restrict__ W2,
    const float* __restrict__ W3,
    const float* __restrict__ Wl0, const float* __restrict__ Wl1,
    const float* __restrict__ Wl2, const float* __restrict__ Wl3,
    const float* __restrict__ Wl4, const float* __restrict__ Wl5,
    __half* __restrict__ Wf)
{
    int idx = blockIdx.x * 256 + threadIdx.x;
    if (idx >= MLPFRAGS + 6 * WLFRAG) return;
    float v;
    if (idx < MLPFRAGS) {
        int frag = idx >> 9;
        int r = idx & 511;
        int l = r >> 3, j = r & 7;
        int l15 = l & 15, lg = l >> 4;
        if (frag < 4) {
            int ct = frag;
            v = W1[(ct * 16 + l15) * 32 + (lg * 8 + j)];
        } else if (frag < 20) {
            int f2 = frag - 4;
            int ct = f2 >> 1, ks = f2 & 1;
            v = W2[(ct * 16 + l15) * 64 + (ks * 32 + lg * 8 + j)];
        } else {
            int f3 = frag - 20;
            int ct = f3 >> 2, ks = f3 & 3;
            v = W3[(ct * 16 + l15) * 128 + (ks * 32 + lg * 8 + j)];
        }
    } else {
        int r2 = idx - MLPFRAGS;
        int wIdx = r2 >> 12;           // /4096
        int rr = r2 & 4095;
        int f = rr >> 9;               // ct*2+ks
        int ct = f >> 1, ks = f & 1;
        int elem = rr & 511;
        int l = elem >> 3, j = elem & 7;
        int l15 = l & 15, lg = l >> 4;
        const float* W = (wIdx == 0) ? Wl0 : (wIdx == 1) ? Wl1 : (wIdx == 2) ? Wl2
                       : (wIdx == 3) ? Wl3 : (wIdx == 4) ? Wl4 : Wl5;
        v = W[(ct * 16 + l15) * 64 + (ks * 32 + lg * 8 + j)];
    }
    Wf[idx] = __float2half(v);
}

// ---------------------------------------------------------------------------
// K_HEAD: fused node_prep + comp-GEMM#1 + T-convert. 32 nodes per block.
// ---------------------------------------------------------------------------
__global__ __launch_bounds__(256) void k_head(
    const float* __restrict__ X, const __half* __restrict__ Wfrag,
    __half2* __restrict__ TgP, uint2* __restrict__ Tg456, int N)
{
    __shared__ __half u2l[9 * 32 * 72];   // 41.5 KB
    __shared__ float s_x[2304];           // 9.2 KB (4 nodes)
    int tid = threadIdx.x;
    int n0 = blockIdx.x * 32;
    size_t total = (size_t)N * 576;

    // ---- phase 1: prep 8 chunks of 4 nodes
    for (int ch = 0; ch < 8; ++ch) {
        size_t base = (size_t)(n0 + ch * 4) * 576;
        for (int idx = tid; idx < 2304; idx += 256) {
            size_t gi = base + idx;
            s_x[idx] = (gi < total) ? X[gi] : 0.f;
        }
        __syncthreads();
        int w = tid >> 6, f = tid & 63;
        int node = ch * 4 + w;
        float m[9]; float n2 = 0.f;
#pragma unroll
        for (int i = 0; i < 9; ++i) { m[i] = s_x[w * 576 + f * 9 + i]; n2 += m[i] * m[i]; }
        float inv = 1.0f / (n2 + 1.0f);
#pragma unroll
        for (int i = 0; i < 9; ++i) m[i] *= inv;
        float lam = (m[0] + m[4] + m[8]) * (1.f / 3.f);
        u2l[(0 * 32 + node) * 72 + f] = __float2half(lam);
        u2l[(1 * 32 + node) * 72 + f] = __float2half(0.5f * (m[1] - m[3]));
        u2l[(2 * 32 + node) * 72 + f] = __float2half(0.5f * (m[2] - m[6]));
        u2l[(3 * 32 + node) * 72 + f] = __float2half(0.5f * (m[5] - m[7]));
        u2l[(4 * 32 + node) * 72 + f] = __float2half(m[0] - lam);
        u2l[(5 * 32 + node) * 72 + f] = __float2half(0.5f * (m[1] + m[3]));
        u2l[(6 * 32 + node) * 72 + f] = __float2half(0.5f * (m[2] + m[6]));
        u2l[(7 * 32 + node) * 72 + f] = __float2half(m[4] - lam);
        u2l[(8 * 32 + node) * 72 + f] = __float2half(0.5f * (m[5] + m[7]));
        __syncthreads();
    }

    // ---- phase 2: GEMM (18 combos = comp c x row-tile rt), in-place
    int w = tid >> 6, lane = tid & 63;
    int l15 = lane & 15, lg = lane >> 4;
    const f32x4 z = {0.f, 0.f, 0.f, 0.f};
    f32x4 acc[5][4];
#pragma unroll
    for (int q = 0; q < 5; ++q) {
        int cm = w + q * 4;
        if (cm < 18) {
            int c = cm >> 1, rt = cm & 1;
            int gsel = (c == 0) ? 0 : (c < 4 ? 1 : 2);
            const f16x8* WFc = (const f16x8*)(Wfrag + gsel * WLFRAG);
            int abase = (c * 32 + rt * 16 + l15) * 72;
            f16x8 a0 = *(const f16x8*)&u2l[abase + lg * 8];
            f16x8 a1 = *(const f16x8*)&u2l[abase + 32 + lg * 8];
#pragma unroll
            for (int ct = 0; ct < 4; ++ct) {
                acc[q][ct] = __builtin_amdgcn_mfma_f32_16x16x32_f16(a0, WFc[(ct * 2 + 0) * 64 + lane], z, 0, 0, 0);
                acc[q][ct] = __builtin_amdgcn_mfma_f32_16x16x32_f16(a1, WFc[(ct * 2 + 1) * 64 + lane], acc[q][ct], 0, 0, 0);
            }
        }
    }
    __syncthreads();
#pragma unroll
    for (int q = 0; q < 5; ++q) {
        int cm = w + q * 4;
        if (cm < 18) {
            int c = cm >> 1, rt = cm & 1;
#pragma unroll
            for (int ct = 0; ct < 4; ++ct)
#pragma unroll
                for (int r = 0; r < 4; ++r)
                    u2l[(c * 32 + rt * 16 + lg * 4 + r) * 72 + ct * 16 + l15] =
                        __float2half(acc[q][ct][r]);
        }
    }
    __syncthreads();

    // ---- phase 3: write gather layouts
    size_t slab = (size_t)N * 64;
    for (int e = 0; e < 8; ++e) {
        int idx = e * 256 + tid;
        int node = idx >> 6;
        int n = n0 + node;
        if (n >= N) continue;
        int f = idx & 63;
        size_t t = (size_t)n * 64 + f;
        const int pa[3] = {0, 2, 7};
#pragma unroll
        for (int pr = 0; pr < 3; ++pr) {
            __half a = u2l[(pa[pr] * 32 + node) * 72 + f];
            __half b = u2l[((pa[pr] + 1) * 32 + node) * 72 + f];
            TgP[(size_t)pr * slab + t] = __halves2half2(a, b);
        }
        __half2 lo = __halves2half2(u2l[(4 * 32 + node) * 72 + f],
                                    u2l[(5 * 32 + node) * 72 + f]);
        __half2 hi = __halves2half2(u2l[(6 * 32 + node) * 72 + f], __float2half(0.f));
        uint2 pk;
        pk.x = *(unsigned int*)&lo;
        pk.y = *(unsigned int*)&hi;
        Tg456[t] = pk;
    }
}

// ---------------------------------------------------------------------------
// CSR sort of edges by src: histogram -> scan -> ranked placement.
// ---------------------------------------------------------------------------
__global__ __launch_bounds__(256) void k_hist(
    const int* __restrict__ pair, int* __restrict__ count, int E)
{
    int e = blockIdx.x * 256 + threadIdx.x;
    if (e < E) atomicAdd(&count[pair[e]], 1);
}

__global__ __launch_bounds__(1024) void k_scan(
    const int* __restrict__ count, int* __restrict__ off,
    int* __restrict__ cursor, int N, int E)
{
    __shared__ int s[1024];
    __shared__ int s_carry;
    int tid = threadIdx.x;
    if (tid == 0) s_carry = 0;
    __syncthreads();
    const int CH = 32;
    for (int base = 0; base < N; base += 1024 * CH) {
        int b0 = base + tid * CH;
        int local[CH]; int sum = 0;
#pragma unroll
        for (int i = 0; i < CH; ++i) {
            int idx = b0 + i;
            int v = (idx < N) ? count[idx] : 0;
            local[i] = sum; sum += v;
        }
        s[tid] = sum;
        __syncthreads();
        for (int d = 1; d < 1024; d <<= 1) {
            int t2 = (tid >= d) ? s[tid - d] : 0;
            __syncthreads();
            s[tid] += t2;
            __syncthreads();
        }
        int excl0 = s_carry + s[tid] - sum;
#pragma unroll
        for (int i = 0; i < CH; ++i) {
            int idx = b0 + i;
            if (idx < N) { int e = excl0 + local[i]; off[idx] = e; cursor[idx] = e; }
        }
        __syncthreads();
        if (tid == 1023) s_carry += s[1023];
        __syncthreads();
    }
    if (tid == 0) off[N] = E;
}

// Packed edge record per sorted position: {src, dst*64, eOrig, C bits}
__global__ __launch_bounds__(256) void k_scatter_sort(
    const int* __restrict__ pair, const float* __restrict__ d_ij,
    int* __restrict__ cursor, uint4* __restrict__ esd, int E)
{
    int e = blockIdx.x * 256 + threadIdx.x;
    if (e < E) {
        int s = pair[e];
        int d = pair[(size_t)E + e];
        float dd = d_ij[e];
        float C = (dd < 5.0f) ? 0.5f * (cosf((float)M_PI * dd * 0.2f) + 1.0f) : 0.0f;
        int pos = atomicAdd(&cursor[s], 1);
        uint4 v;
        v.x = (unsigned int)s;
        v.y = (unsigned int)(d * 64);
        v.z = (unsigned int)e;
        v.w = __float_as_uint(C);
        esd[pos] = v;
    }
}

// ---------------------------------------------------------------------------
// K2: fused edge MLP on MFMA + 4-stream, depth-2-prefetch message pass with
// packed-fp16 accumulation. msg slabs {0:(0,1), 1:(2,3), 2:(7,8), 3:(4,5),
// 4:(6,pad)}; flush = one half2 store / pk_add_f16 atomic; run-boundary
// checks are LDS-only (s_prev/s_next + padded src = -3).
// ---------------------------------------------------------------------------
__global__ __launch_bounds__(256) void k_edge_sorted(
    const float* __restrict__ radial, const uint4* __restrict__ esd,
    const __half* __restrict__ Wf,
    const float* __restrict__ b1, const float* __restrict__ b2,
    const float* __restrict__ b3,
    const __half2* __restrict__ TgP, const uint2* __restrict__ Tg456,
    __half2* __restrict__ msgP, int E, int N)
{
    __shared__ __half s_act[64 * AROW];
    __shared__ float s_C[64];
    __shared__ int s_e[64];
    __shared__ int s_src[64];    // padded entries = -3
    __shared__ int s_dst[64];    // PRE-MULTIPLIED by 64 (element offset)
    __shared__ int s_prevs, s_nexts;
    int tid = threadIdx.x;
    int p0 = blockIdx.x * 64;

    if (tid < 64) {
        int p = p0 + tid;
        int e = -1, s = -3, d64 = 0; float C = 0.f;
        if (p < E) {
            uint4 v = esd[p];
            s = (int)v.x; d64 = (int)v.y; e = (int)v.z; C = __uint_as_float(v.w);
        }
        s_e[tid] = e; s_src[tid] = s; s_dst[tid] = d64; s_C[tid] = C;
        if (tid == 0) {
            s_prevs = (p0 > 0) ? (int)esd[p0 - 1].x : -2;
            s_nexts = (p0 + 64 < E) ? (int)esd[p0 + 64].x : -2;
        }
    }
    __syncthreads();

    {   // stage rbf: s_act[j][k], fp16
        int j = tid >> 2;
        int kk = (tid & 3) * 8;
        int e = s_e[j];
        float4 v0 = make_float4(0.f, 0.f, 0.f, 0.f), v1 = v0;
        if (e >= 0) {
            v0 = *(const float4*)(radial + (size_t)e * 32 + kk);
            v1 = *(const float4*)(radial + (size_t)e * 32 + kk + 4);
        }
        __half2* dst = (__half2*)&s_act[j * AROW + kk];
        dst[0] = __floats2half2_rn(v0.x, v0.y);
        dst[1] = __floats2half2_rn(v0.z, v0.w);
        dst[2] = __floats2half2_rn(v1.x, v1.y);
        dst[3] = __floats2half2_rn(v1.z, v1.w);
    }
    __syncthreads();

    int w = tid >> 6;
    int lane = tid & 63;
    int l15 = lane & 15, lg = lane >> 4;
    const int row0 = w * 16;
    const int arow = (row0 + l15) * AROW;
    const int orow = (row0 + lg * 4) * AROW;
    const f16x8* WF = (const f16x8*)Wf;
    const f32x4 zacc = {0.f, 0.f, 0.f, 0.f};

    // ---- layer 1: 32 -> 64
    {
        f16x8 a = *(const f16x8*)&s_act[arow + lg * 8];
        f32x4 acc[4];
#pragma unroll
        for (int ct = 0; ct < 4; ++ct)
            acc[ct] = __builtin_amdgcn_mfma_f32_16x16x32_f16(a, WF[ct * 64 + lane], zacc, 0, 0, 0);
        __syncthreads();
#pragma unroll
        for (int ct = 0; ct < 4; ++ct) {
            int o = ct * 16 + l15;
            float bias = b1[o];
#pragma unroll
            for (int r = 0; r < 4; ++r)
                s_act[orow + r * AROW + o] = __float2half(silu_f(acc[ct][r] + bias));
        }
        __syncthreads();
    }

    // ---- layer 2: 64 -> 128
    {
        f16x8 a0 = *(const f16x8*)&s_act[arow + 0 * 32 + lg * 8];
        f16x8 a1 = *(const f16x8*)&s_act[arow + 1 * 32 + lg * 8];
        f32x4 acc[8];
#pragma unroll
        for (int ct = 0; ct < 8; ++ct) {
            acc[ct] = __builtin_amdgcn_mfma_f32_16x16x32_f16(a0, WF[(4 + ct * 2 + 0) * 64 + lane], zacc, 0, 0, 0);
            acc[ct] = __builtin_amdgcn_mfma_f32_16x16x32_f16(a1, WF[(4 + ct * 2 + 1) * 64 + lane], acc[ct], 0, 0, 0);
        }
        __syncthreads();
#pragma unroll
        for (int ct = 0; ct < 8; ++ct) {
            int o = ct * 16 + l15;
            float bias = b2[o];
#pragma unroll
            for (int r = 0; r < 4; ++r)
                s_act[orow + r * AROW + o] = __float2half(silu_f(acc[ct][r] + bias));
        }
        __syncthreads();
    }

    // ---- layer 3: 128 -> 192 (raw col o -> stored col (o%3)*64 + o/3)
    {
        f16x8 a[4];
#pragma unroll
        for (int ks = 0; ks < 4; ++ks)
            a[ks] = *(const f16x8*)&s_act[arow + ks * 32 + lg * 8];
        float Cr[4];
#pragma unroll
        for (int r = 0; r < 4; ++r) Cr[r] = s_C[row0 + lg * 4 + r];
        __syncthreads();
#pragma unroll
        for (int ct = 0; ct < 12; ++ct) {
            f32x4 acc = zacc;
#pragma unroll
            for (int ks = 0; ks < 4; ++ks)
                acc = __builtin_amdgcn_mfma_f32_16x16x32_f16(a[ks], WF[(20 + ct * 4 + ks) * 64 + lane], acc, 0, 0, 0);
            int o = ct * 16 + l15;
            float bias = b3[o];
            int f = o / 3;
            int cmp = o - f * 3;
            int col = cmp * 64 + f;
#pragma unroll
            for (int r = 0; r < 4; ++r)
                s_act[orow + r * AROW + col] = __float2half(silu_f(acc[r] + bias) * Cr[r]);
        }
        __syncthreads();
    }

    // ---- message pass: 4 streams/wave, depth-2 prefetch, fp16 pk-fma accum
    {
        int wv = __builtin_amdgcn_readfirstlane(w);
        size_t slab = (size_t)N * 64;
        int jmax = min(64, E - p0);
        const __half2 Zh = __floats2half2_rn(0.f, 0.f);

        if (wv == 2) {
            // comps {4,5,6} via ONE uint2 (half4) load; rf2 at col 128+lane
            const uint2* T4 = Tg456;
            auto flush3 = [&](int cur, int js, int je, __half2 a45, __half2 a6) {
                bool lb = (js == 0) ? (s_prevs != cur) : (s_src[js - 1] != cur);
                bool rb = (je == 64) ? (s_nexts != cur) : (s_src[je] != cur);
                size_t b = (size_t)cur * 64 + lane;
                if (lb && rb) {
                    msgP[3 * slab + b] = a45;
                    msgP[4 * slab + b] = a6;
                } else {
                    pk_add_f16(&msgP[3 * slab + b], a45);
                    pk_add_f16(&msgP[4 * slab + b], a6);
                }
            };
            __half2 A00 = Zh, A01 = Zh, A10 = Zh, A11 = Zh;
            __half2 A20 = Zh, A21 = Zh, A30 = Zh, A31 = Zh;
            int cur0 = -1, cur1 = -1, cur2 = -1, cur3 = -1;
            int js0 = 0, js1 = 0, js2 = 0, js3 = 0;
            uint2 ta0 = make_uint2(0, 0), ta1 = ta0, ta2 = ta0, ta3 = ta0;
            uint2 tb0 = ta0, tb1 = ta0, tb2 = ta0, tb3 = ta0;
            if (0 < jmax)  ta0 = T4[(size_t)s_dst[0]  + lane];
            if (16 < jmax) ta1 = T4[(size_t)s_dst[16] + lane];
            if (32 < jmax) ta2 = T4[(size_t)s_dst[32] + lane];
            if (48 < jmax) ta3 = T4[(size_t)s_dst[48] + lane];
            if (1 < jmax)  tb0 = T4[(size_t)s_dst[1]  + lane];
            if (17 < jmax) tb1 = T4[(size_t)s_dst[17] + lane];
            if (33 < jmax) tb2 = T4[(size_t)s_dst[33] + lane];
            if (49 < jmax) tb3 = T4[(size_t)s_dst[49] + lane];
#define MS3(BASE, CUR, JS, A45, A6, TVA, TVB) { \
            int j = (BASE) + t; \
            if (j < jmax) { \
                uint2 tvc = TVA; TVA = TVB; \
                int jn = j + 2; \
                if (jn < (BASE) + 16 && jn < jmax) \
                    TVB = T4[(size_t)s_dst[jn] + lane]; \
                int s = __builtin_amdgcn_readfirstlane(s_src[j]); \
                if (s != CUR) { if (CUR >= 0) flush3(CUR, JS, j, A45, A6); \
                                CUR = s; JS = j; A45 = Zh; A6 = Zh; } \
                __half rfh = s_act[j * AROW + 128 + lane]; \
                __half2 rf2 = __halves2half2(rfh, rfh); \
                A45 = __hfma2(rf2, *(__half2*)&tvc.x, A45); \
                A6  = __hfma2(rf2, *(__half2*)&tvc.y, A6); \
            } }
#pragma unroll 4
            for (int t = 0; t < 16; ++t) {
                MS3(0,  cur0, js0, A00, A01, ta0, tb0)
                MS3(16, cur1, js1, A10, A11, ta1, tb1)
                MS3(32, cur2, js2, A20, A21, ta2, tb2)
                MS3(48, cur3, js3, A30, A31, ta3, tb3)
            }
#undef MS3
            if (cur0 >= 0) flush3(cur0, js0, min(16, jmax), A00, A01);
            if (cur1 >= 0) flush3(cur1, js1, min(32, jmax), A10, A11);
            if (cur2 >= 0) flush3(cur2, js2, min(48, jmax), A20, A21);
            if (cur3 >= 0) flush3(cur3, js3, min(64, jmax), A30, A31);
        } else {
            // TgP slab & msg slab: wave0 -> 0 {0,1}, wave1 -> 1 {2,3},
            // wave3 -> 2 {7,8}
            int sl = (wv == 0) ? 0 : ((wv == 1) ? 1 : 2);
            int offA = (wv == 0) ? lane : ((wv == 1) ? (64 + lane) : (128 + lane));
            int offB = 64 + lane;     // only used by wave0
            bool W0 = (wv == 0);
            const unsigned int* TP = (const unsigned int*)TgP + (size_t)sl * slab;
            auto flush2 = [&](int cur, int js, int je, __half2 a) {
                bool lb = (js == 0) ? (s_prevs != cur) : (s_src[js - 1] != cur);
                bool rb = (je == 64) ? (s_nexts != cur) : (s_src[je] != cur);
                size_t b = (size_t)cur * 64 + lane;
                if (lb && rb) {
                    msgP[(size_t)sl * slab + b] = a;
                } else {
                    pk_add_f16(&msgP[(size_t)sl * slab + b], a);
                }
            };
            __half2 A0 = Zh, A1 = Zh, A2 = Zh, A3 = Zh;
            int cur0 = -1, cur1 = -1, cur2 = -1, cur3 = -1;
            int js0 = 0, js1 = 0, js2 = 0, js3 = 0;
            unsigned int ta0 = 0, ta1 = 0, ta2 = 0, ta3 = 0;
            unsigned int tb0 = 0, tb1 = 0, tb2 = 0, tb3 = 0;
            if (0 < jmax)  ta0 = TP[(size_t)s_dst[0]  + lane];
            if (16 < jmax) ta1 = TP[(size_t)s_dst[16] + lane];
            if (32 < jmax) ta2 = TP[(size_t)s_dst[32] + lane];
            if (48 < jmax) ta3 = TP[(size_t)s_dst[48] + lane];
            if (1 < jmax)  tb0 = TP[(size_t)s_dst[1]  + lane];
            if (17 < jmax) tb1 = TP[(size_t)s_dst[17] + lane];
            if (33 < jmax) tb2 = TP[(size_t)s_dst[33] + lane];
            if (49 < jmax) tb3 = TP[(size_t)s_dst[49] + lane];
#define MS2(BASE, CUR, JS, A, TVA, TVB) { \
            int j = (BASE) + t; \
            if (j < jmax) { \
                unsigned int tvc = TVA; TVA = TVB; \
                int jn = j + 2; \
                if (jn < (BASE) + 16 && jn < jmax) \
                    TVB = TP[(size_t)s_dst[jn] + lane]; \
                int s = __builtin_amdgcn_readfirstlane(s_src[j]); \
                if (s != CUR) { if (CUR >= 0) flush2(CUR, JS, j, A); \
                                CUR = s; JS = j; A = Zh; } \
                __half rfa = s_act[j * AROW + offA]; \
                __half rfb = W0 ? s_act[j * AROW + offB] : rfa; \
                A = __hfma2(__halves2half2(rfa, rfb), *(__half2*)&tvc, A); \
            } }
#pragma unroll 4
            for (int t = 0; t < 16; ++t) {
                MS2(0,  cur0, js0, A0, ta0, tb0)
                MS2(16, cur1, js1, A1, ta1, tb1)
                MS2(32, cur2, js2, A2, ta2, tb2)
                MS2(48, cur3, js3, A3, ta3, tb3)
            }
#undef MS2
            if (cur0 >= 0) flush2(cur0, js0, min(16, jmax), A0);
            if (cur1 >= 0) flush2(cur1, js1, min(32, jmax), A1);
            if (cur2 >= 0) flush2(cur2, js2, min(48, jmax), A2);
            if (cur3 >= 0) flush2(cur3, js3, min(64, jmax), A3);
        }
    }
}

// ---------------------------------------------------------------------------
// K_TAIL: fused node_mix + comp-GEMM#2 + out. 32 nodes per block.
// msg read from fp16 pair slabs; Y from TgP/Tg456.
// ---------------------------------------------------------------------------
__global__ __launch_bounds__(256) void k_tail(
    const __half2* __restrict__ msgP,
    const __half2* __restrict__ TgP, const uint2* __restrict__ Tg456,
    const float* __restrict__ X, const float* __restrict__ charges,
    const __half* __restrict__ Wfrag, float* __restrict__ out, int N)
{
    __shared__ __half u2l[9 * 32 * 72];   // 41.5 KB
    __shared__ float s_sc[32];
    int tid = threadIdx.x;
    int n0 = blockIdx.x * 32;
    size_t slab = (size_t)N * 64;

    if (tid < 32) {
        int n = n0 + tid;
        s_sc[tid] = (n < N) ? 1.0f + 0.1f * charges[n] : 0.f;
    }
    __syncthreads();

    // ---- phase 1: node mix
    for (int e = 0; e < 8; ++e) {
        int idx = e * 256 + tid;          // 0..2047
        int node = idx >> 6;
        int n = n0 + node;
        float um[9], uy[9];
        if (n < N) {
            size_t t = (size_t)n0 * 64 + idx;
            float2 m01 = __half22float2(msgP[0 * slab + t]);
            float2 m23 = __half22float2(msgP[1 * slab + t]);
            float2 m78 = __half22float2(msgP[2 * slab + t]);
            float2 m45 = __half22float2(msgP[3 * slab + t]);
            float2 m6_ = __half22float2(msgP[4 * slab + t]);
            um[0] = m01.x; um[1] = m01.y;
            um[2] = m23.x; um[3] = m23.y;
            um[4] = m45.x; um[5] = m45.y;
            um[6] = m6_.x;
            um[7] = m78.x; um[8] = m78.y;
            float2 p0 = __half22float2(TgP[0 * slab + t]);
            float2 p1 = __half22float2(TgP[1 * slab + t]);
            float2 p2 = __half22float2(TgP[2 * slab + t]);
            uint2 q = Tg456[t];
            float2 q0 = __half22float2(*(__half2*)&q.x);
            __half2 q1 = *(__half2*)&q.y;
            uy[0] = p0.x; uy[1] = p0.y;
            uy[2] = p1.x; uy[3] = p1.y;
            uy[4] = q0.x; uy[5] = q0.y;
            uy[6] = __half2float(q1.x);
            uy[7] = p2.x; uy[8] = p2.y;
        } else {
#pragma unroll
            for (int c = 0; c < 9; ++c) { um[c] = 0.f; uy[c] = 0.f; }
        }
        float M[9], Y[9];
        recon(um, M);
        recon(uy, Y);
        float P[9];
#pragma unroll
        for (int i = 0; i < 3; ++i)
#pragma unroll
            for (int j = 0; j < 3; ++j) {
                float s = 0.f;
#pragma unroll
                for (int k = 0; k < 3; ++k)
                    s += M[i * 3 + k] * Y[k * 3 + j] + Y[i * 3 + k] * M[k * 3 + j];
                P[i * 3 + j] = s;
            }
        float sc = s_sc[node];
        float nrm = 0.f;
#pragma unroll
        for (int i = 0; i < 9; ++i) { P[i] *= sc; nrm += P[i] * P[i]; }
        float inv = 1.0f / (nrm + 1.0f);
        float lam = (P[0] + P[4] + P[8]) * (1.f / 3.f);
        int f = idx & 63;
        u2l[(0 * 32 + node) * 72 + f] = __float2half(lam * inv);
        u2l[(1 * 32 + node) * 72 + f] = __float2half(0.5f * (P[1] - P[3]) * inv);
        u2l[(2 * 32 + node) * 72 + f] = __float2half(0.5f * (P[2] - P[6]) * inv);
        u2l[(3 * 32 + node) * 72 + f] = __float2half(0.5f * (P[5] - P[7]) * inv);
        u2l[(4 * 32 + node) * 72 + f] = __float2half((P[0] - lam) * inv);
        u2l[(5 * 32 + node) * 72 + f] = __float2half(0.5f * (P[1] + P[3]) * inv);
        u2l[(6 * 32 + node) * 72 + f] = __float2half(0.5f * (P[2] + P[6]) * inv);
        u2l[(7 * 32 + node) * 72 + f] = __float2half((P[4] - lam) * inv);
        u2l[(8 * 32 + node) * 72 + f] = __float2half(0.5f * (P[5] + P[7]) * inv);
    }
    __syncthreads();

    // ---- phase 2: GEMM (18 combos)
    int w = tid >> 6, lane = tid & 63;
    int l15 = lane & 15, lg = lane >> 4;
    const f32x4 z = {0.f, 0.f, 0.f, 0.f};
    f32x4 acc[5][4];
#pragma unroll
    for (int q = 0; q < 5; ++q) {
        int cm = w + q * 4;
        if (cm < 18) {
            int c = cm >> 1, rt = cm & 1;
            int gsel = (c == 0) ? 0 : (c < 4 ? 1 : 2);
            const f16x8* WFc = (const f16x8*)(Wfrag + gsel * WLFRAG);
            int abase = (c * 32 + rt * 16 + l15) * 72;
            f16x8 a0 = *(const f16x8*)&u2l[abase + lg * 8];
            f16x8 a1 = *(const f16x8*)&u2l[abase + 32 + lg * 8];
#pragma unroll
            for (int ct = 0; ct < 4; ++ct) {
                acc[q][ct] = __builtin_amdgcn_mfma_f32_16x16x32_f16(a0, WFc[(ct * 2 + 0) * 64 + lane], z, 0, 0, 0);
                acc[q][ct] = __builtin_amdgcn_mfma_f32_16x16x32_f16(a1, WFc[(ct * 2 + 1) * 64 + lane], acc[q][ct], 0, 0, 0);
            }
        }
    }
    __syncthreads();
#pragma unroll
    for (int q = 0; q < 5; ++q) {
        int cm = w + q * 4;
        if (cm < 18) {
            int c = cm >> 1, rt = cm & 1;
#pragma unroll
            for (int ct = 0; ct < 4; ++ct)
#pragma unroll
                for (int r = 0; r < 4; ++r)
                    u2l[(c * 32 + rt * 16 + lg * 4 + r) * 72 + ct * 16 + l15] =
                        __float2half(acc[q][ct][r]);
        }
    }
    __syncthreads();

    // ---- phase 3: out = Xn + dX + sc*dX@dX
    for (int e = 0; e < 8; ++e) {
        int idx = e * 256 + tid;
        int node = idx >> 6;
        int n = n0 + node;
        if (n >= N) continue;
        int f = idx & 63;
        float v[9];
#pragma unroll
        for (int c = 0; c < 9; ++c)
            v[c] = __half2float(u2l[(c * 32 + node) * 72 + f]);
        float dX[9];
        recon(v, dX);
        const float* xp = X + (size_t)n * 576 + f * 9;
        float m[9]; float n2 = 0.f;
#pragma unroll
        for (int i = 0; i < 9; ++i) { m[i] = xp[i]; n2 += m[i] * m[i]; }
        float invn = 1.0f / (n2 + 1.0f);
#pragma unroll
        for (int i = 0; i < 9; ++i) m[i] *= invn;
        float sc = s_sc[node];
        float* op = out + (size_t)n * 576 + f * 9;
#pragma unroll
        for (int i = 0; i < 3; ++i)
#pragma unroll
            for (int j = 0; j < 3; ++j) {
                float s = 0.f;
#pragma unroll
                for (int k = 0; k < 3; ++k) s += dX[i * 3 + k] * dX[k * 3 + j];
                op[i * 3 + j] = m[i * 3 + j] + dX[i * 3 + j] + sc * s;
            }
    }
}

// ---------------------------------------------------------------------------
extern "C" void kernel_launch(void* const* d_in, const int* in_sizes, int n_in,
                              void* d_out, int out_size, void* d_ws, size_t ws_size,
                              hipStream_t stream)
{
    const float* X       = (const float*)d_in[0];
    const int*   pair    = (const int*)d_in[1];
    const float* dij     = (const float*)d_in[2];
    const float* radial  = (const float*)d_in[3];
    const float* charges = (const float*)d_in[4];
    const float* W1  = (const float*)d_in[5];
    const float* b1  = (const float*)d_in[6];
    const float* W2  = (const float*)d_in[7];
    const float* b2  = (const float*)d_in[8];
    const float* W3  = (const float*)d_in[9];
    const float* b3  = (const float*)d_in[10];
    const float* Wl0 = (const float*)d_in[11];
    const float* Wl1 = (const float*)d_in[12];
    const float* Wl2 = (const float*)d_in[13];
    const float* Wl3 = (const float*)d_in[14];
    const float* Wl4 = (const float*)d_in[15];
    const float* Wl5 = (const float*)d_in[16];

    int N = in_sizes[4];
    int E = in_sizes[2];
    int nb_edge = (E + 63) / 64;
    int nb_node32 = (N + 31) / 32;
    size_t slab = (size_t)N * 64;

    __half2* msgP = (__half2*)d_ws;            // 5 slabs half2 (fp16 pairs)
    __half2* TgP  = msgP + 5 * slab;           // 3 slabs half2
    uint2* Tg456  = (uint2*)(TgP + 3 * slab);  // 1 slab uint2
    __half* Wf    = (__half*)(Tg456 + slab);   // 59392 halfs
    uint4* esd    = (uint4*)(Wf + MLPFRAGS + 6 * WLFRAG);
    int* ints   = (int*)(esd + E);
    int* count  = ints;
    int* off    = count + N;
    int* cursor = off + N + 1;

    hipMemsetAsync(count, 0, (size_t)N * sizeof(int), stream);
    hipMemsetAsync(msgP, 0, 5 * slab * sizeof(__half2), stream);

    int nWf = MLPFRAGS + 6 * WLFRAG;
    k_wcvt<<<(nWf + 255) / 256, 256, 0, stream>>>(W1, W2, W3,
                                                  Wl0, Wl1, Wl2, Wl3, Wl4, Wl5, Wf);
    k_head<<<nb_node32, 256, 0, stream>>>(X, Wf + MLPFRAGS, TgP, Tg456, N);

    k_hist<<<(E + 255) / 256, 256, 0, stream>>>(pair, count, E);
    k_scan<<<1, 1024, 0, stream>>>(count, off, cursor, N, E);
    k_scatter_sort<<<(E + 255) / 256, 256, 0, stream>>>(pair, dij, cursor, esd, E);

    k_edge_sorted<<<nb_edge, 256, 0, stream>>>(radial, esd,
                                               Wf, b1, b2, b3, TgP, Tg456,
                                               msgP, E, N);

    k_tail<<<nb_node32, 256, 0, stream>>>(msgP, TgP, Tg456, X, charges,
                                          Wf + MLPFRAGS + 3 * WLFRAG,
                                          (float*)d_out, N);
}

// Round 14
// 384.050 us; speedup vs baseline: 1.7813x; 1.0004x over previous
//
#include <hip/hip_runtime.h>
#include <hip/hip_fp16.h>
#include <math.h>

#ifndef M_PI
#define M_PI 3.14159265358979323846
#endif

// ---------------------------------------------------------------------------
// TensorNet interaction. fp32 math, fp16 LDS/gather/msg tensors, MFMA GEMMs.
// Compressed irreducible rep per (n,f): u[9] =
//   { lam, a01, a02, a12, s00, s01, s02, s11, s12 }   (s22 = -s00-s11)
//
// ws (~71 MB): msgP (5 fp16-pair slabs), TgP (3 fp16 comp-pair slabs),
// Tg456 (packed half4), Wf (fp16 MFMA frags), esd (packed edge recs), ints.
//
// Round-14 change: AROW 216 -> 200 (only 192 activation cols are used;
// 400 B row stride keeps 16 B alignment for f16x8 frags). LDS/block
// 29.2 -> 26.6 KB => 5 -> 6 blocks/CU residency for the edge kernel.
// ---------------------------------------------------------------------------

typedef _Float16 f16x8 __attribute__((ext_vector_type(8)));
typedef float f32x4 __attribute__((ext_vector_type(4)));

#define AROW 200        // halfs per activation row (400 B = 25*16)
#define MLPFRAGS 34816  // 68 frags * 512 halfs
#define WLFRAG 4096     // halfs per Wl matrix (8 frags * 512)

__device__ __forceinline__ float silu_f(float x) {
    return x / (1.0f + __expf(-x));
}

// HW packed-fp16 atomic add (no atomicAdd(__half2*) overload in ROCm 7.2)
__device__ __forceinline__ void pk_add_f16(__half2* addr, __half2 val) {
    asm volatile("global_atomic_pk_add_f16 %0, %1, off"
                 :: "v"(addr), "v"(val) : "memory");
}

__device__ __forceinline__ void recon(const float u[9], float M[9]) {
    M[0] =  u[0] + u[4];
    M[1] =  u[1] + u[5];
    M[2] =  u[2] + u[6];
    M[3] = -u[1] + u[5];
    M[4] =  u[0] + u[7];
    M[5] =  u[3] + u[8];
    M[6] = -u[2] + u[6];
    M[7] = -u[3] + u[8];
    M[8] =  u[0] - u[4] - u[7];
}

// ---------------------------------------------------------------------------
// Weight -> fp16 MFMA-fragment conversion (once per launch).
// Fragment element (lane l, j) = W[ct*16+(l&15)][ks*32+(l>>4)*8+j].
// ---------------------------------------------------------------------------
__global__ __launch_bounds__(256) void k_wcvt(
    const float* __restrict__ W1, const float* __restrict__ W2,
    const float* __restrict__ W3,
    const float* __restrict__ Wl0, const float* __restrict__ Wl1,
    const float* __restrict__ Wl2, const float* __restrict__ Wl3,
    const float* __restrict__ Wl4, const float* __restrict__ Wl5,
    __half* __restrict__ Wf)
{
    int idx = blockIdx.x * 256 + threadIdx.x;
    if (idx >= MLPFRAGS + 6 * WLFRAG) return;
    float v;
    if (idx < MLPFRAGS) {
        int frag = idx >> 9;
        int r = idx & 511;
        int l = r >> 3, j = r & 7;
        int l15 = l & 15, lg = l >> 4;
        if (frag < 4) {
            int ct = frag;
            v = W1[(ct * 16 + l15) * 32 + (lg * 8 + j)];
        } else if (frag < 20) {
            int f2 = frag - 4;
            int ct = f2 >> 1, ks = f2 & 1;
            v = W2[(ct * 16 + l15) * 64 + (ks * 32 + lg * 8 + j)];
        } else {
            int f3 = frag - 20;
            int ct = f3 >> 2, ks = f3 & 3;
            v = W3[(ct * 16 + l15) * 128 + (ks * 32 + lg * 8 + j)];
        }
    } else {
        int r2 = idx - MLPFRAGS;
        int wIdx = r2 >> 12;           // /4096
        int rr = r2 & 4095;
        int f = rr >> 9;               // ct*2+ks
        int ct = f >> 1, ks = f & 1;
        int elem = rr & 511;
        int l = elem >> 3, j = elem & 7;
        int l15 = l & 15, lg = l >> 4;
        const float* W = (wIdx == 0) ? Wl0 : (wIdx == 1) ? Wl1 : (wIdx == 2) ? Wl2
                       : (wIdx == 3) ? Wl3 : (wIdx == 4) ? Wl4 : Wl5;
        v = W[(ct * 16 + l15) * 64 + (ks * 32 + lg * 8 + j)];
    }
    Wf[idx] = __float2half(v);
}

// ---------------------------------------------------------------------------
// K_HEAD: fused node_prep + comp-GEMM#1 + T-convert. 32 nodes per block.
// ---------------------------------------------------------------------------
__global__ __launch_bounds__(256) void k_head(
    const float* __restrict__ X, const __half* __restrict__ Wfrag,
    __half2* __restrict__ TgP, uint2* __restrict__ Tg456, int N)
{
    __shared__ __half u2l[9 * 32 * 72];   // 41.5 KB
    __shared__ float s_x[2304];           // 9.2 KB (4 nodes)
    int tid = threadIdx.x;
    int n0 = blockIdx.x * 32;
    size_t total = (size_t)N * 576;

    // ---- phase 1: prep 8 chunks of 4 nodes
    for (int ch = 0; ch < 8; ++ch) {
        size_t base = (size_t)(n0 + ch * 4) * 576;
        for (int idx = tid; idx < 2304; idx += 256) {
            size_t gi = base + idx;
            s_x[idx] = (gi < total) ? X[gi] : 0.f;
        }
        __syncthreads();
        int w = tid >> 6, f = tid & 63;
        int node = ch * 4 + w;
        float m[9]; float n2 = 0.f;
#pragma unroll
        for (int i = 0; i < 9; ++i) { m[i] = s_x[w * 576 + f * 9 + i]; n2 += m[i] * m[i]; }
        float inv = 1.0f / (n2 + 1.0f);
#pragma unroll
        for (int i = 0; i < 9; ++i) m[i] *= inv;
        float lam = (m[0] + m[4] + m[8]) * (1.f / 3.f);
        u2l[(0 * 32 + node) * 72 + f] = __float2half(lam);
        u2l[(1 * 32 + node) * 72 + f] = __float2half(0.5f * (m[1] - m[3]));
        u2l[(2 * 32 + node) * 72 + f] = __float2half(0.5f * (m[2] - m[6]));
        u2l[(3 * 32 + node) * 72 + f] = __float2half(0.5f * (m[5] - m[7]));
        u2l[(4 * 32 + node) * 72 + f] = __float2half(m[0] - lam);
        u2l[(5 * 32 + node) * 72 + f] = __float2half(0.5f * (m[1] + m[3]));
        u2l[(6 * 32 + node) * 72 + f] = __float2half(0.5f * (m[2] + m[6]));
        u2l[(7 * 32 + node) * 72 + f] = __float2half(m[4] - lam);
        u2l[(8 * 32 + node) * 72 + f] = __float2half(0.5f * (m[5] + m[7]));
        __syncthreads();
    }

    // ---- phase 2: GEMM (18 combos = comp c x row-tile rt), in-place
    int w = tid >> 6, lane = tid & 63;
    int l15 = lane & 15, lg = lane >> 4;
    const f32x4 z = {0.f, 0.f, 0.f, 0.f};
    f32x4 acc[5][4];
#pragma unroll
    for (int q = 0; q < 5; ++q) {
        int cm = w + q * 4;
        if (cm < 18) {
            int c = cm >> 1, rt = cm & 1;
            int gsel = (c == 0) ? 0 : (c < 4 ? 1 : 2);
            const f16x8* WFc = (const f16x8*)(Wfrag + gsel * WLFRAG);
            int abase = (c * 32 + rt * 16 + l15) * 72;
            f16x8 a0 = *(const f16x8*)&u2l[abase + lg * 8];
            f16x8 a1 = *(const f16x8*)&u2l[abase + 32 + lg * 8];
#pragma unroll
            for (int ct = 0; ct < 4; ++ct) {
                acc[q][ct] = __builtin_amdgcn_mfma_f32_16x16x32_f16(a0, WFc[(ct * 2 + 0) * 64 + lane], z, 0, 0, 0);
                acc[q][ct] = __builtin_amdgcn_mfma_f32_16x16x32_f16(a1, WFc[(ct * 2 + 1) * 64 + lane], acc[q][ct], 0, 0, 0);
            }
        }
    }
    __syncthreads();
#pragma unroll
    for (int q = 0; q < 5; ++q) {
        int cm = w + q * 4;
        if (cm < 18) {
            int c = cm >> 1, rt = cm & 1;
#pragma unroll
            for (int ct = 0; ct < 4; ++ct)
#pragma unroll
                for (int r = 0; r < 4; ++r)
                    u2l[(c * 32 + rt * 16 + lg * 4 + r) * 72 + ct * 16 + l15] =
                        __float2half(acc[q][ct][r]);
        }
    }
    __syncthreads();

    // ---- phase 3: write gather layouts
    size_t slab = (size_t)N * 64;
    for (int e = 0; e < 8; ++e) {
        int idx = e * 256 + tid;
        int node = idx >> 6;
        int n = n0 + node;
        if (n >= N) continue;
        int f = idx & 63;
        size_t t = (size_t)n * 64 + f;
        const int pa[3] = {0, 2, 7};
#pragma unroll
        for (int pr = 0; pr < 3; ++pr) {
            __half a = u2l[(pa[pr] * 32 + node) * 72 + f];
            __half b = u2l[((pa[pr] + 1) * 32 + node) * 72 + f];
            TgP[(size_t)pr * slab + t] = __halves2half2(a, b);
        }
        __half2 lo = __halves2half2(u2l[(4 * 32 + node) * 72 + f],
                                    u2l[(5 * 32 + node) * 72 + f]);
        __half2 hi = __halves2half2(u2l[(6 * 32 + node) * 72 + f], __float2half(0.f));
        uint2 pk;
        pk.x = *(unsigned int*)&lo;
        pk.y = *(unsigned int*)&hi;
        Tg456[t] = pk;
    }
}

// ---------------------------------------------------------------------------
// CSR sort of edges by src: histogram -> scan -> ranked placement.
// ---------------------------------------------------------------------------
__global__ __launch_bounds__(256) void k_hist(
    const int* __restrict__ pair, int* __restrict__ count, int E)
{
    int e = blockIdx.x * 256 + threadIdx.x;
    if (e < E) atomicAdd(&count[pair[e]], 1);
}

__global__ __launch_bounds__(1024) void k_scan(
    const int* __restrict__ count, int* __restrict__ off,
    int* __restrict__ cursor, int N, int E)
{
    __shared__ int s[1024];
    __shared__ int s_carry;
    int tid = threadIdx.x;
    if (tid == 0) s_carry = 0;
    __syncthreads();
    const int CH = 32;
    for (int base = 0; base < N; base += 1024 * CH) {
        int b0 = base + tid * CH;
        int local[CH]; int sum = 0;
#pragma unroll
        for (int i = 0; i < CH; ++i) {
            int idx = b0 + i;
            int v = (idx < N) ? count[idx] : 0;
            local[i] = sum; sum += v;
        }
        s[tid] = sum;
        __syncthreads();
        for (int d = 1; d < 1024; d <<= 1) {
            int t2 = (tid >= d) ? s[tid - d] : 0;
            __syncthreads();
            s[tid] += t2;
            __syncthreads();
        }
        int excl0 = s_carry + s[tid] - sum;
#pragma unroll
        for (int i = 0; i < CH; ++i) {
            int idx = b0 + i;
            if (idx < N) { int e = excl0 + local[i]; off[idx] = e; cursor[idx] = e; }
        }
        __syncthreads();
        if (tid == 1023) s_carry += s[1023];
        __syncthreads();
    }
    if (tid == 0) off[N] = E;
}

// Packed edge record per sorted position: {src, dst*64, eOrig, C bits}
__global__ __launch_bounds__(256) void k_scatter_sort(
    const int* __restrict__ pair, const float* __restrict__ d_ij,
    int* __restrict__ cursor, uint4* __restrict__ esd, int E)
{
    int e = blockIdx.x * 256 + threadIdx.x;
    if (e < E) {
        int s = pair[e];
        int d = pair[(size_t)E + e];
        float dd = d_ij[e];
        float C = (dd < 5.0f) ? 0.5f * (cosf((float)M_PI * dd * 0.2f) + 1.0f) : 0.0f;
        int pos = atomicAdd(&cursor[s], 1);
        uint4 v;
        v.x = (unsigned int)s;
        v.y = (unsigned int)(d * 64);
        v.z = (unsigned int)e;
        v.w = __float_as_uint(C);
        esd[pos] = v;
    }
}

// ---------------------------------------------------------------------------
// K2: fused edge MLP on MFMA + 4-stream, depth-2-prefetch message pass with
// packed-fp16 accumulation. msg slabs {0:(0,1), 1:(2,3), 2:(7,8), 3:(4,5),
// 4:(6,pad)}; flush = one half2 store / pk_add_f16 atomic; run-boundary
// checks are LDS-only (s_prev/s_next + padded src = -3).
// ---------------------------------------------------------------------------
__global__ __launch_bounds__(256) void k_edge_sorted(
    const float* __restrict__ radial, const uint4* __restrict__ esd,
    const __half* __restrict__ Wf,
    const float* __restrict__ b1, const float* __restrict__ b2,
    const float* __restrict__ b3,
    const __half2* __restrict__ TgP, const uint2* __restrict__ Tg456,
    __half2* __restrict__ msgP, int E, int N)
{
    __shared__ __half s_act[64 * AROW];
    __shared__ float s_C[64];
    __shared__ int s_e[64];
    __shared__ int s_src[64];    // padded entries = -3
    __shared__ int s_dst[64];    // PRE-MULTIPLIED by 64 (element offset)
    __shared__ int s_prevs, s_nexts;
    int tid = threadIdx.x;
    int p0 = blockIdx.x * 64;

    if (tid < 64) {
        int p = p0 + tid;
        int e = -1, s = -3, d64 = 0; float C = 0.f;
        if (p < E) {
            uint4 v = esd[p];
            s = (int)v.x; d64 = (int)v.y; e = (int)v.z; C = __uint_as_float(v.w);
        }
        s_e[tid] = e; s_src[tid] = s; s_dst[tid] = d64; s_C[tid] = C;
        if (tid == 0) {
            s_prevs = (p0 > 0) ? (int)esd[p0 - 1].x : -2;
            s_nexts = (p0 + 64 < E) ? (int)esd[p0 + 64].x : -2;
        }
    }
    __syncthreads();

    {   // stage rbf: s_act[j][k], fp16
        int j = tid >> 2;
        int kk = (tid & 3) * 8;
        int e = s_e[j];
        float4 v0 = make_float4(0.f, 0.f, 0.f, 0.f), v1 = v0;
        if (e >= 0) {
            v0 = *(const float4*)(radial + (size_t)e * 32 + kk);
            v1 = *(const float4*)(radial + (size_t)e * 32 + kk + 4);
        }
        __half2* dst = (__half2*)&s_act[j * AROW + kk];
        dst[0] = __floats2half2_rn(v0.x, v0.y);
        dst[1] = __floats2half2_rn(v0.z, v0.w);
        dst[2] = __floats2half2_rn(v1.x, v1.y);
        dst[3] = __floats2half2_rn(v1.z, v1.w);
    }
    __syncthreads();

    int w = tid >> 6;
    int lane = tid & 63;
    int l15 = lane & 15, lg = lane >> 4;
    const int row0 = w * 16;
    const int arow = (row0 + l15) * AROW;
    const int orow = (row0 + lg * 4) * AROW;
    const f16x8* WF = (const f16x8*)Wf;
    const f32x4 zacc = {0.f, 0.f, 0.f, 0.f};

    // ---- layer 1: 32 -> 64
    {
        f16x8 a = *(const f16x8*)&s_act[arow + lg * 8];
        f32x4 acc[4];
#pragma unroll
        for (int ct = 0; ct < 4; ++ct)
            acc[ct] = __builtin_amdgcn_mfma_f32_16x16x32_f16(a, WF[ct * 64 + lane], zacc, 0, 0, 0);
        __syncthreads();
#pragma unroll
        for (int ct = 0; ct < 4; ++ct) {
            int o = ct * 16 + l15;
            float bias = b1[o];
#pragma unroll
            for (int r = 0; r < 4; ++r)
                s_act[orow + r * AROW + o] = __float2half(silu_f(acc[ct][r] + bias));
        }
        __syncthreads();
    }

    // ---- layer 2: 64 -> 128
    {
        f16x8 a0 = *(const f16x8*)&s_act[arow + 0 * 32 + lg * 8];
        f16x8 a1 = *(const f16x8*)&s_act[arow + 1 * 32 + lg * 8];
        f32x4 acc[8];
#pragma unroll
        for (int ct = 0; ct < 8; ++ct) {
            acc[ct] = __builtin_amdgcn_mfma_f32_16x16x32_f16(a0, WF[(4 + ct * 2 + 0) * 64 + lane], zacc, 0, 0, 0);
            acc[ct] = __builtin_amdgcn_mfma_f32_16x16x32_f16(a1, WF[(4 + ct * 2 + 1) * 64 + lane], acc[ct], 0, 0, 0);
        }
        __syncthreads();
#pragma unroll
        for (int ct = 0; ct < 8; ++ct) {
            int o = ct * 16 + l15;
            float bias = b2[o];
#pragma unroll
            for (int r = 0; r < 4; ++r)
                s_act[orow + r * AROW + o] = __float2half(silu_f(acc[ct][r] + bias));
        }
        __syncthreads();
    }

    // ---- layer 3: 128 -> 192 (raw col o -> stored col (o%3)*64 + o/3)
    {
        f16x8 a[4];
#pragma unroll
        for (int ks = 0; ks < 4; ++ks)
            a[ks] = *(const f16x8*)&s_act[arow + ks * 32 + lg * 8];
        float Cr[4];
#pragma unroll
        for (int r = 0; r < 4; ++r) Cr[r] = s_C[row0 + lg * 4 + r];
        __syncthreads();
#pragma unroll
        for (int ct = 0; ct < 12; ++ct) {
            f32x4 acc = zacc;
#pragma unroll
            for (int ks = 0; ks < 4; ++ks)
                acc = __builtin_amdgcn_mfma_f32_16x16x32_f16(a[ks], WF[(20 + ct * 4 + ks) * 64 + lane], acc, 0, 0, 0);
            int o = ct * 16 + l15;
            float bias = b3[o];
            int f = o / 3;
            int cmp = o - f * 3;
            int col = cmp * 64 + f;
#pragma unroll
            for (int r = 0; r < 4; ++r)
                s_act[orow + r * AROW + col] = __float2half(silu_f(acc[r] + bias) * Cr[r]);
        }
        __syncthreads();
    }

    // ---- message pass: 4 streams/wave, depth-2 prefetch, fp16 pk-fma accum
    {
        int wv = __builtin_amdgcn_readfirstlane(w);
        size_t slab = (size_t)N * 64;
        int jmax = min(64, E - p0);
        const __half2 Zh = __floats2half2_rn(0.f, 0.f);

        if (wv == 2) {
            // comps {4,5,6} via ONE uint2 (half4) load; rf2 at col 128+lane
            const uint2* T4 = Tg456;
            auto flush3 = [&](int cur, int js, int je, __half2 a45, __half2 a6) {
                bool lb = (js == 0) ? (s_prevs != cur) : (s_src[js - 1] != cur);
                bool rb = (je == 64) ? (s_nexts != cur) : (s_src[je] != cur);
                size_t b = (size_t)cur * 64 + lane;
                if (lb && rb) {
                    msgP[3 * slab + b] = a45;
                    msgP[4 * slab + b] = a6;
                } else {
                    pk_add_f16(&msgP[3 * slab + b], a45);
                    pk_add_f16(&msgP[4 * slab + b], a6);
                }
            };
            __half2 A00 = Zh, A01 = Zh, A10 = Zh, A11 = Zh;
            __half2 A20 = Zh, A21 = Zh, A30 = Zh, A31 = Zh;
            int cur0 = -1, cur1 = -1, cur2 = -1, cur3 = -1;
            int js0 = 0, js1 = 0, js2 = 0, js3 = 0;
            uint2 ta0 = make_uint2(0, 0), ta1 = ta0, ta2 = ta0, ta3 = ta0;
            uint2 tb0 = ta0, tb1 = ta0, tb2 = ta0, tb3 = ta0;
            if (0 < jmax)  ta0 = T4[(size_t)s_dst[0]  + lane];
            if (16 < jmax) ta1 = T4[(size_t)s_dst[16] + lane];
            if (32 < jmax) ta2 = T4[(size_t)s_dst[32] + lane];
            if (48 < jmax) ta3 = T4[(size_t)s_dst[48] + lane];
            if (1 < jmax)  tb0 = T4[(size_t)s_dst[1]  + lane];
            if (17 < jmax) tb1 = T4[(size_t)s_dst[17] + lane];
            if (33 < jmax) tb2 = T4[(size_t)s_dst[33] + lane];
            if (49 < jmax) tb3 = T4[(size_t)s_dst[49] + lane];
#define MS3(BASE, CUR, JS, A45, A6, TVA, TVB) { \
            int j = (BASE) + t; \
            if (j < jmax) { \
                uint2 tvc = TVA; TVA = TVB; \
                int jn = j + 2; \
                if (jn < (BASE) + 16 && jn < jmax) \
                    TVB = T4[(size_t)s_dst[jn] + lane]; \
                int s = __builtin_amdgcn_readfirstlane(s_src[j]); \
                if (s != CUR) { if (CUR >= 0) flush3(CUR, JS, j, A45, A6); \
                                CUR = s; JS = j; A45 = Zh; A6 = Zh; } \
                __half rfh = s_act[j * AROW + 128 + lane]; \
                __half2 rf2 = __halves2half2(rfh, rfh); \
                A45 = __hfma2(rf2, *(__half2*)&tvc.x, A45); \
                A6  = __hfma2(rf2, *(__half2*)&tvc.y, A6); \
            } }
#pragma unroll 4
            for (int t = 0; t < 16; ++t) {
                MS3(0,  cur0, js0, A00, A01, ta0, tb0)
                MS3(16, cur1, js1, A10, A11, ta1, tb1)
                MS3(32, cur2, js2, A20, A21, ta2, tb2)
                MS3(48, cur3, js3, A30, A31, ta3, tb3)
            }
#undef MS3
            if (cur0 >= 0) flush3(cur0, js0, min(16, jmax), A00, A01);
            if (cur1 >= 0) flush3(cur1, js1, min(32, jmax), A10, A11);
            if (cur2 >= 0) flush3(cur2, js2, min(48, jmax), A20, A21);
            if (cur3 >= 0) flush3(cur3, js3, min(64, jmax), A30, A31);
        } else {
            // TgP slab & msg slab: wave0 -> 0 {0,1}, wave1 -> 1 {2,3},
            // wave3 -> 2 {7,8}
            int sl = (wv == 0) ? 0 : ((wv == 1) ? 1 : 2);
            int offA = (wv == 0) ? lane : ((wv == 1) ? (64 + lane) : (128 + lane));
            int offB = 64 + lane;     // only used by wave0
            bool W0 = (wv == 0);
            const unsigned int* TP = (const unsigned int*)TgP + (size_t)sl * slab;
            auto flush2 = [&](int cur, int js, int je, __half2 a) {
                bool lb = (js == 0) ? (s_prevs != cur) : (s_src[js - 1] != cur);
                bool rb = (je == 64) ? (s_nexts != cur) : (s_src[je] != cur);
                size_t b = (size_t)cur * 64 + lane;
                if (lb && rb) {
                    msgP[(size_t)sl * slab + b] = a;
                } else {
                    pk_add_f16(&msgP[(size_t)sl * slab + b], a);
                }
            };
            __half2 A0 = Zh, A1 = Zh, A2 = Zh, A3 = Zh;
            int cur0 = -1, cur1 = -1, cur2 = -1, cur3 = -1;
            int js0 = 0, js1 = 0, js2 = 0, js3 = 0;
            unsigned int ta0 = 0, ta1 = 0, ta2 = 0, ta3 = 0;
            unsigned int tb0 = 0, tb1 = 0, tb2 = 0, tb3 = 0;
            if (0 < jmax)  ta0 = TP[(size_t)s_dst[0]  + lane];
            if (16 < jmax) ta1 = TP[(size_t)s_dst[16] + lane];
            if (32 < jmax) ta2 = TP[(size_t)s_dst[32] + lane];
            if (48 < jmax) ta3 = TP[(size_t)s_dst[48] + lane];
            if (1 < jmax)  tb0 = TP[(size_t)s_dst[1]  + lane];
            if (17 < jmax) tb1 = TP[(size_t)s_dst[17] + lane];
            if (33 < jmax) tb2 = TP[(size_t)s_dst[33] + lane];
            if (49 < jmax) tb3 = TP[(size_t)s_dst[49] + lane];
#define MS2(BASE, CUR, JS, A, TVA, TVB) { \
            int j = (BASE) + t; \
            if (j < jmax) { \
                unsigned int tvc = TVA; TVA = TVB; \
                int jn = j + 2; \
                if (jn < (BASE) + 16 && jn < jmax) \
                    TVB = TP[(size_t)s_dst[jn] + lane]; \
                int s = __builtin_amdgcn_readfirstlane(s_src[j]); \
                if (s != CUR) { if (CUR >= 0) flush2(CUR, JS, j, A); \
                                CUR = s; JS = j; A = Zh; } \
                __half rfa = s_act[j * AROW + offA]; \
                __half rfb = W0 ? s_act[j * AROW + offB] : rfa; \
                A = __hfma2(__halves2half2(rfa, rfb), *(__half2*)&tvc, A); \
            } }
#pragma unroll 4
            for (int t = 0; t < 16; ++t) {
                MS2(0,  cur0, js0, A0, ta0, tb0)
                MS2(16, cur1, js1, A1, ta1, tb1)
                MS2(32, cur2, js2, A2, ta2, tb2)
                MS2(48, cur3, js3, A3, ta3, tb3)
            }
#undef MS2
            if (cur0 >= 0) flush2(cur0, js0, min(16, jmax), A0);
            if (cur1 >= 0) flush2(cur1, js1, min(32, jmax), A1);
            if (cur2 >= 0) flush2(cur2, js2, min(48, jmax), A2);
            if (cur3 >= 0) flush2(cur3, js3, min(64, jmax), A3);
        }
    }
}

// ---------------------------------------------------------------------------
// K_TAIL: fused node_mix + comp-GEMM#2 + out. 32 nodes per block.
// msg read from fp16 pair slabs; Y from TgP/Tg456.
// ---------------------------------------------------------------------------
__global__ __launch_bounds__(256) void k_tail(
    const __half2* __restrict__ msgP,
    const __half2* __restrict__ TgP, const uint2* __restrict__ Tg456,
    const float* __restrict__ X, const float* __restrict__ charges,
    const __half* __restrict__ Wfrag, float* __restrict__ out, int N)
{
    __shared__ __half u2l[9 * 32 * 72];   // 41.5 KB
    __shared__ float s_sc[32];
    int tid = threadIdx.x;
    int n0 = blockIdx.x * 32;
    size_t slab = (size_t)N * 64;

    if (tid < 32) {
        int n = n0 + tid;
        s_sc[tid] = (n < N) ? 1.0f + 0.1f * charges[n] : 0.f;
    }
    __syncthreads();

    // ---- phase 1: node mix
    for (int e = 0; e < 8; ++e) {
        int idx = e * 256 + tid;          // 0..2047
        int node = idx >> 6;
        int n = n0 + node;
        float um[9], uy[9];
        if (n < N) {
            size_t t = (size_t)n0 * 64 + idx;
            float2 m01 = __half22float2(msgP[0 * slab + t]);
            float2 m23 = __half22float2(msgP[1 * slab + t]);
            float2 m78 = __half22float2(msgP[2 * slab + t]);
            float2 m45 = __half22float2(msgP[3 * slab + t]);
            float2 m6_ = __half22float2(msgP[4 * slab + t]);
            um[0] = m01.x; um[1] = m01.y;
            um[2] = m23.x; um[3] = m23.y;
            um[4] = m45.x; um[5] = m45.y;
            um[6] = m6_.x;
            um[7] = m78.x; um[8] = m78.y;
            float2 p0 = __half22float2(TgP[0 * slab + t]);
            float2 p1 = __half22float2(TgP[1 * slab + t]);
            float2 p2 = __half22float2(TgP[2 * slab + t]);
            uint2 q = Tg456[t];
            float2 q0 = __half22float2(*(__half2*)&q.x);
            __half2 q1 = *(__half2*)&q.y;
            uy[0] = p0.x; uy[1] = p0.y;
            uy[2] = p1.x; uy[3] = p1.y;
            uy[4] = q0.x; uy[5] = q0.y;
            uy[6] = __half2float(q1.x);
            uy[7] = p2.x; uy[8] = p2.y;
        } else {
#pragma unroll
            for (int c = 0; c < 9; ++c) { um[c] = 0.f; uy[c] = 0.f; }
        }
        float M[9], Y[9];
        recon(um, M);
        recon(uy, Y);
        float P[9];
#pragma unroll
        for (int i = 0; i < 3; ++i)
#pragma unroll
            for (int j = 0; j < 3; ++j) {
                float s = 0.f;
#pragma unroll
                for (int k = 0; k < 3; ++k)
                    s += M[i * 3 + k] * Y[k * 3 + j] + Y[i * 3 + k] * M[k * 3 + j];
                P[i * 3 + j] = s;
            }
        float sc = s_sc[node];
        float nrm = 0.f;
#pragma unroll
        for (int i = 0; i < 9; ++i) { P[i] *= sc; nrm += P[i] * P[i]; }
        float inv = 1.0f / (nrm + 1.0f);
        float lam = (P[0] + P[4] + P[8]) * (1.f / 3.f);
        int f = idx & 63;
        u2l[(0 * 32 + node) * 72 + f] = __float2half(lam * inv);
        u2l[(1 * 32 + node) * 72 + f] = __float2half(0.5f * (P[1] - P[3]) * inv);
        u2l[(2 * 32 + node) * 72 + f] = __float2half(0.5f * (P[2] - P[6]) * inv);
        u2l[(3 * 32 + node) * 72 + f] = __float2half(0.5f * (P[5] - P[7]) * inv);
        u2l[(4 * 32 + node) * 72 + f] = __float2half((P[0] - lam) * inv);
        u2l[(5 * 32 + node) * 72 + f] = __float2half(0.5f * (P[1] + P[3]) * inv);
        u2l[(6 * 32 + node) * 72 + f] = __float2half(0.5f * (P[2] + P[6]) * inv);
        u2l[(7 * 32 + node) * 72 + f] = __float2half((P[4] - lam) * inv);
        u2l[(8 * 32 + node) * 72 + f] = __float2half(0.5f * (P[5] + P[7]) * inv);
    }
    __syncthreads();

    // ---- phase 2: GEMM (18 combos)
    int w = tid >> 6, lane = tid & 63;
    int l15 = lane & 15, lg = lane >> 4;
    const f32x4 z = {0.f, 0.f, 0.f, 0.f};
    f32x4 acc[5][4];
#pragma unroll
    for (int q = 0; q < 5; ++q) {
        int cm = w + q * 4;
        if (cm < 18) {
            int c = cm >> 1, rt = cm & 1;
            int gsel = (c == 0) ? 0 : (c < 4 ? 1 : 2);
            const f16x8* WFc = (const f16x8*)(Wfrag + gsel * WLFRAG);
            int abase = (c * 32 + rt * 16 + l15) * 72;
            f16x8 a0 = *(const f16x8*)&u2l[abase + lg * 8];
            f16x8 a1 = *(const f16x8*)&u2l[abase + 32 + lg * 8];
#pragma unroll
            for (int ct = 0; ct < 4; ++ct) {
                acc[q][ct] = __builtin_amdgcn_mfma_f32_16x16x32_f16(a0, WFc[(ct * 2 + 0) * 64 + lane], z, 0, 0, 0);
                acc[q][ct] = __builtin_amdgcn_mfma_f32_16x16x32_f16(a1, WFc[(ct * 2 + 1) * 64 + lane], acc[q][ct], 0, 0, 0);
            }
        }
    }
    __syncthreads();
#pragma unroll
    for (int q = 0; q < 5; ++q) {
        int cm = w + q * 4;
        if (cm < 18) {
            int c = cm >> 1, rt = cm & 1;
#pragma unroll
            for (int ct = 0; ct < 4; ++ct)
#pragma unroll
                for (int r = 0; r < 4; ++r)
                    u2l[(c * 32 + rt * 16 + lg * 4 + r) * 72 + ct * 16 + l15] =
                        __float2half(acc[q][ct][r]);
        }
    }
    __syncthreads();

    // ---- phase 3: out = Xn + dX + sc*dX@dX
    for (int e = 0; e < 8; ++e) {
        int idx = e * 256 + tid;
        int node = idx >> 6;
        int n = n0 + node;
        if (n >= N) continue;
        int f = idx & 63;
        float v[9];
#pragma unroll
        for (int c = 0; c < 9; ++c)
            v[c] = __half2float(u2l[(c * 32 + node) * 72 + f]);
        float dX[9];
        recon(v, dX);
        const float* xp = X + (size_t)n * 576 + f * 9;
        float m[9]; float n2 = 0.f;
#pragma unroll
        for (int i = 0; i < 9; ++i) { m[i] = xp[i]; n2 += m[i] * m[i]; }
        float invn = 1.0f / (n2 + 1.0f);
#pragma unroll
        for (int i = 0; i < 9; ++i) m[i] *= invn;
        float sc = s_sc[node];
        float* op = out + (size_t)n * 576 + f * 9;
#pragma unroll
        for (int i = 0; i < 3; ++i)
#pragma unroll
            for (int j = 0; j < 3; ++j) {
                float s = 0.f;
#pragma unroll
                for (int k = 0; k < 3; ++k) s += dX[i * 3 + k] * dX[k * 3 + j];
                op[i * 3 + j] = m[i * 3 + j] + dX[i * 3 + j] + sc * s;
            }
    }
}

// ---------------------------------------------------------------------------
extern "C" void kernel_launch(void* const* d_in, const int* in_sizes, int n_in,
                              void* d_out, int out_size, void* d_ws, size_t ws_size,
                              hipStream_t stream)
{
    const float* X       = (const float*)d_in[0];
    const int*   pair    = (const int*)d_in[1];
    const float* dij     = (const float*)d_in[2];
    const float* radial  = (const float*)d_in[3];
    const float* charges = (const float*)d_in[4];
    const float* W1  = (const float*)d_in[5];
    const float* b1  = (const float*)d_in[6];
    const float* W2  = (const float*)d_in[7];
    const float* b2  = (const float*)d_in[8];
    const float* W3  = (const float*)d_in[9];
    const float* b3  = (const float*)d_in[10];
    const float* Wl0 = (const float*)d_in[11];
    const float* Wl1 = (const float*)d_in[12];
    const float* Wl2 = (const float*)d_in[13];
    const float* Wl3 = (const float*)d_in[14];
    const float* Wl4 = (const float*)d_in[15];
    const float* Wl5 = (const float*)d_in[16];

    int N = in_sizes[4];
    int E = in_sizes[2];
    int nb_edge = (E + 63) / 64;
    int nb_node32 = (N + 31) / 32;
    size_t slab = (size_t)N * 64;

    __half2* msgP = (__half2*)d_ws;            // 5 slabs half2 (fp16 pairs)
    __half2* TgP  = msgP + 5 * slab;           // 3 slabs half2
    uint2* Tg456  = (uint2*)(TgP + 3 * slab);  // 1 slab uint2
    __half* Wf    = (__half*)(Tg456 + slab);   // 59392 halfs
    uint4* esd    = (uint4*)(Wf + MLPFRAGS + 6 * WLFRAG);
    int* ints   = (int*)(esd + E);
    int* count  = ints;
    int* off    = count + N;
    int* cursor = off + N + 1;

    hipMemsetAsync(count, 0, (size_t)N * sizeof(int), stream);
    hipMemsetAsync(msgP, 0, 5 * slab * sizeof(__half2), stream);

    int nWf = MLPFRAGS + 6 * WLFRAG;
    k_wcvt<<<(nWf + 255) / 256, 256, 0, stream>>>(W1, W2, W3,
                                                  Wl0, Wl1, Wl2, Wl3, Wl4, Wl5, Wf);
    k_head<<<nb_node32, 256, 0, stream>>>(X, Wf + MLPFRAGS, TgP, Tg456, N);

    k_hist<<<(E + 255) / 256, 256, 0, stream>>>(pair, count, E);
    k_scan<<<1, 1024, 0, stream>>>(count, off, cursor, N, E);
    k_scatter_sort<<<(E + 255) / 256, 256, 0, stream>>>(pair, dij, cursor, esd, E);

    k_edge_sorted<<<nb_edge, 256, 0, stream>>>(radial, esd,
                                               Wf, b1, b2, b3, TgP, Tg456,
                                               msgP, E, N);

    k_tail<<<nb_node32, 256, 0, stream>>>(msgP, TgP, Tg456, X, charges,
                                          Wf + MLPFRAGS + 3 * WLFRAG,
                                          (float*)d_out, N);
}

// Round 15
// 346.212 us; speedup vs baseline: 1.9760x; 1.1093x over previous
//
#include <hip/hip_runtime.h>
#include <hip/hip_fp16.h>
#include <math.h>

#ifndef M_PI
#define M_PI 3.14159265358979323846
#endif

// ---------------------------------------------------------------------------
// TensorNet interaction. fp32 math, fp16 LDS/gather/msg tensors, MFMA GEMMs.
// Compressed irreducible rep per (n,f): u[9] =
//   { lam, a01, a02, a12, s00, s01, s02, s11, s12 }   (s22 = -s00-s11)
//
// ws (~71 MB): msgP (5 fp16-pair slabs), TgP (3 fp16 comp-pair slabs),
// Tg456 (packed half4), Wf (fp16 MFMA frags), esd (packed edge recs), ints.
//
// Round-15 change: message pass gets a FULL-BLOCK specialization
// (jmax==64, true for every block when E%64==0): fully-unrolled 16-iter
// loop (prefetch guards constant-folded, LDS immediates), 32-bit unsigned
// gather indices (enables global_load saddr+voffset form, kills 64-bit
// address chains), s_dst padded to 66 for unconditional prefetch.
// ---------------------------------------------------------------------------

typedef _Float16 f16x8 __attribute__((ext_vector_type(8)));
typedef float f32x4 __attribute__((ext_vector_type(4)));

#define AROW 200        // halfs per activation row (400 B = 25*16)
#define MLPFRAGS 34816  // 68 frags * 512 halfs
#define WLFRAG 4096     // halfs per Wl matrix (8 frags * 512)

__device__ __forceinline__ float silu_f(float x) {
    return x / (1.0f + __expf(-x));
}

// HW packed-fp16 atomic add (no atomicAdd(__half2*) overload in ROCm 7.2)
__device__ __forceinline__ void pk_add_f16(__half2* addr, __half2 val) {
    asm volatile("global_atomic_pk_add_f16 %0, %1, off"
                 :: "v"(addr), "v"(val) : "memory");
}

__device__ __forceinline__ void recon(const float u[9], float M[9]) {
    M[0] =  u[0] + u[4];
    M[1] =  u[1] + u[5];
    M[2] =  u[2] + u[6];
    M[3] = -u[1] + u[5];
    M[4] =  u[0] + u[7];
    M[5] =  u[3] + u[8];
    M[6] = -u[2] + u[6];
    M[7] = -u[3] + u[8];
    M[8] =  u[0] - u[4] - u[7];
}

// ---------------------------------------------------------------------------
// Weight -> fp16 MFMA-fragment conversion (once per launch).
// Fragment element (lane l, j) = W[ct*16+(l&15)][ks*32+(l>>4)*8+j].
// ---------------------------------------------------------------------------
__global__ __launch_bounds__(256) void k_wcvt(
    const float* __restrict__ W1, const float* __restrict__ W2,
    const float* __restrict__ W3,
    const float* __restrict__ Wl0, const float* __restrict__ Wl1,
    const float* __restrict__ Wl2, const float* __restrict__ Wl3,
    const float* __restrict__ Wl4, const float* __restrict__ Wl5,
    __half* __restrict__ Wf)
{
    int idx = blockIdx.x * 256 + threadIdx.x;
    if (idx >= MLPFRAGS + 6 * WLFRAG) return;
    float v;
    if (idx < MLPFRAGS) {
        int frag = idx >> 9;
        int r = idx & 511;
        int l = r >> 3, j = r & 7;
        int l15 = l & 15, lg = l >> 4;
        if (frag < 4) {
            int ct = frag;
            v = W1[(ct * 16 + l15) * 32 + (lg * 8 + j)];
        } else if (frag < 20) {
            int f2 = frag - 4;
            int ct = f2 >> 1, ks = f2 & 1;
            v = W2[(ct * 16 + l15) * 64 + (ks * 32 + lg * 8 + j)];
        } else {
            int f3 = frag - 20;
            int ct = f3 >> 2, ks = f3 & 3;
            v = W3[(ct * 16 + l15) * 128 + (ks * 32 + lg * 8 + j)];
        }
    } else {
        int r2 = idx - MLPFRAGS;
        int wIdx = r2 >> 12;           // /4096
        int rr = r2 & 4095;
        int f = rr >> 9;               // ct*2+ks
        int ct = f >> 1, ks = f & 1;
        int elem = rr & 511;
        int l = elem >> 3, j = elem & 7;
        int l15 = l & 15, lg = l >> 4;
        const float* W = (wIdx == 0) ? Wl0 : (wIdx == 1) ? Wl1 : (wIdx == 2) ? Wl2
                       : (wIdx == 3) ? Wl3 : (wIdx == 4) ? Wl4 : Wl5;
        v = W[(ct * 16 + l15) * 64 + (ks * 32 + lg * 8 + j)];
    }
    Wf[idx] = __float2half(v);
}

// ---------------------------------------------------------------------------
// K_HEAD: fused node_prep + comp-GEMM#1 + T-convert. 32 nodes per block.
// ---------------------------------------------------------------------------
__global__ __launch_bounds__(256) void k_head(
    const float* __restrict__ X, const __half* __restrict__ Wfrag,
    __half2* __restrict__ TgP, uint2* __restrict__ Tg456, int N)
{
    __shared__ __half u2l[9 * 32 * 72];   // 41.5 KB
    __shared__ float s_x[2304];           // 9.2 KB (4 nodes)
    int tid = threadIdx.x;
    int n0 = blockIdx.x * 32;
    size_t total = (size_t)N * 576;

    // ---- phase 1: prep 8 chunks of 4 nodes
    for (int ch = 0; ch < 8; ++ch) {
        size_t base = (size_t)(n0 + ch * 4) * 576;
        for (int idx = tid; idx < 2304; idx += 256) {
            size_t gi = base + idx;
            s_x[idx] = (gi < total) ? X[gi] : 0.f;
        }
        __syncthreads();
        int w = tid >> 6, f = tid & 63;
        int node = ch * 4 + w;
        float m[9]; float n2 = 0.f;
#pragma unroll
        for (int i = 0; i < 9; ++i) { m[i] = s_x[w * 576 + f * 9 + i]; n2 += m[i] * m[i]; }
        float inv = 1.0f / (n2 + 1.0f);
#pragma unroll
        for (int i = 0; i < 9; ++i) m[i] *= inv;
        float lam = (m[0] + m[4] + m[8]) * (1.f / 3.f);
        u2l[(0 * 32 + node) * 72 + f] = __float2half(lam);
        u2l[(1 * 32 + node) * 72 + f] = __float2half(0.5f * (m[1] - m[3]));
        u2l[(2 * 32 + node) * 72 + f] = __float2half(0.5f * (m[2] - m[6]));
        u2l[(3 * 32 + node) * 72 + f] = __float2half(0.5f * (m[5] - m[7]));
        u2l[(4 * 32 + node) * 72 + f] = __float2half(m[0] - lam);
        u2l[(5 * 32 + node) * 72 + f] = __float2half(0.5f * (m[1] + m[3]));
        u2l[(6 * 32 + node) * 72 + f] = __float2half(0.5f * (m[2] + m[6]));
        u2l[(7 * 32 + node) * 72 + f] = __float2half(m[4] - lam);
        u2l[(8 * 32 + node) * 72 + f] = __float2half(0.5f * (m[5] + m[7]));
        __syncthreads();
    }

    // ---- phase 2: GEMM (18 combos = comp c x row-tile rt), in-place
    int w = tid >> 6, lane = tid & 63;
    int l15 = lane & 15, lg = lane >> 4;
    const f32x4 z = {0.f, 0.f, 0.f, 0.f};
    f32x4 acc[5][4];
#pragma unroll
    for (int q = 0; q < 5; ++q) {
        int cm = w + q * 4;
        if (cm < 18) {
            int c = cm >> 1, rt = cm & 1;
            int gsel = (c == 0) ? 0 : (c < 4 ? 1 : 2);
            const f16x8* WFc = (const f16x8*)(Wfrag + gsel * WLFRAG);
            int abase = (c * 32 + rt * 16 + l15) * 72;
            f16x8 a0 = *(const f16x8*)&u2l[abase + lg * 8];
            f16x8 a1 = *(const f16x8*)&u2l[abase + 32 + lg * 8];
#pragma unroll
            for (int ct = 0; ct < 4; ++ct) {
                acc[q][ct] = __builtin_amdgcn_mfma_f32_16x16x32_f16(a0, WFc[(ct * 2 + 0) * 64 + lane], z, 0, 0, 0);
                acc[q][ct] = __builtin_amdgcn_mfma_f32_16x16x32_f16(a1, WFc[(ct * 2 + 1) * 64 + lane], acc[q][ct], 0, 0, 0);
            }
        }
    }
    __syncthreads();
#pragma unroll
    for (int q = 0; q < 5; ++q) {
        int cm = w + q * 4;
        if (cm < 18) {
            int c = cm >> 1, rt = cm & 1;
#pragma unroll
            for (int ct = 0; ct < 4; ++ct)
#pragma unroll
                for (int r = 0; r < 4; ++r)
                    u2l[(c * 32 + rt * 16 + lg * 4 + r) * 72 + ct * 16 + l15] =
                        __float2half(acc[q][ct][r]);
        }
    }
    __syncthreads();

    // ---- phase 3: write gather layouts
    size_t slab = (size_t)N * 64;
    for (int e = 0; e < 8; ++e) {
        int idx = e * 256 + tid;
        int node = idx >> 6;
        int n = n0 + node;
        if (n >= N) continue;
        int f = idx & 63;
        size_t t = (size_t)n * 64 + f;
        const int pa[3] = {0, 2, 7};
#pragma unroll
        for (int pr = 0; pr < 3; ++pr) {
            __half a = u2l[(pa[pr] * 32 + node) * 72 + f];
            __half b = u2l[((pa[pr] + 1) * 32 + node) * 72 + f];
            TgP[(size_t)pr * slab + t] = __halves2half2(a, b);
        }
        __half2 lo = __halves2half2(u2l[(4 * 32 + node) * 72 + f],
                                    u2l[(5 * 32 + node) * 72 + f]);
        __half2 hi = __halves2half2(u2l[(6 * 32 + node) * 72 + f], __float2half(0.f));
        uint2 pk;
        pk.x = *(unsigned int*)&lo;
        pk.y = *(unsigned int*)&hi;
        Tg456[t] = pk;
    }
}

// ---------------------------------------------------------------------------
// CSR sort of edges by src: histogram -> scan -> ranked placement.
// ---------------------------------------------------------------------------
__global__ __launch_bounds__(256) void k_hist(
    const int* __restrict__ pair, int* __restrict__ count, int E)
{
    int e = blockIdx.x * 256 + threadIdx.x;
    if (e < E) atomicAdd(&count[pair[e]], 1);
}

__global__ __launch_bounds__(1024) void k_scan(
    const int* __restrict__ count, int* __restrict__ off,
    int* __restrict__ cursor, int N, int E)
{
    __shared__ int s[1024];
    __shared__ int s_carry;
    int tid = threadIdx.x;
    if (tid == 0) s_carry = 0;
    __syncthreads();
    const int CH = 32;
    for (int base = 0; base < N; base += 1024 * CH) {
        int b0 = base + tid * CH;
        int local[CH]; int sum = 0;
#pragma unroll
        for (int i = 0; i < CH; ++i) {
            int idx = b0 + i;
            int v = (idx < N) ? count[idx] : 0;
            local[i] = sum; sum += v;
        }
        s[tid] = sum;
        __syncthreads();
        for (int d = 1; d < 1024; d <<= 1) {
            int t2 = (tid >= d) ? s[tid - d] : 0;
            __syncthreads();
            s[tid] += t2;
            __syncthreads();
        }
        int excl0 = s_carry + s[tid] - sum;
#pragma unroll
        for (int i = 0; i < CH; ++i) {
            int idx = b0 + i;
            if (idx < N) { int e = excl0 + local[i]; off[idx] = e; cursor[idx] = e; }
        }
        __syncthreads();
        if (tid == 1023) s_carry += s[1023];
        __syncthreads();
    }
    if (tid == 0) off[N] = E;
}

// Packed edge record per sorted position: {src, dst*64, eOrig, C bits}
__global__ __launch_bounds__(256) void k_scatter_sort(
    const int* __restrict__ pair, const float* __restrict__ d_ij,
    int* __restrict__ cursor, uint4* __restrict__ esd, int E)
{
    int e = blockIdx.x * 256 + threadIdx.x;
    if (e < E) {
        int s = pair[e];
        int d = pair[(size_t)E + e];
        float dd = d_ij[e];
        float C = (dd < 5.0f) ? 0.5f * (cosf((float)M_PI * dd * 0.2f) + 1.0f) : 0.0f;
        int pos = atomicAdd(&cursor[s], 1);
        uint4 v;
        v.x = (unsigned int)s;
        v.y = (unsigned int)(d * 64);
        v.z = (unsigned int)e;
        v.w = __float_as_uint(C);
        esd[pos] = v;
    }
}

// ---------------------------------------------------------------------------
// K2: fused edge MLP on MFMA + 4-stream, depth-2-prefetch message pass with
// packed-fp16 accumulation. msg slabs {0:(0,1), 1:(2,3), 2:(7,8), 3:(4,5),
// 4:(6,pad)}; flush = one half2 store / pk_add_f16 atomic; run-boundary
// checks are LDS-only. Full blocks (jmax==64) take an unguarded,
// fully-unrolled path with 32-bit gather indices.
// ---------------------------------------------------------------------------
__global__ __launch_bounds__(256) void k_edge_sorted(
    const float* __restrict__ radial, const uint4* __restrict__ esd,
    const __half* __restrict__ Wf,
    const float* __restrict__ b1, const float* __restrict__ b2,
    const float* __restrict__ b3,
    const __half2* __restrict__ TgP, const uint2* __restrict__ Tg456,
    __half2* __restrict__ msgP, int E, int N)
{
    __shared__ __half s_act[64 * AROW];
    __shared__ float s_C[64];
    __shared__ int s_e[64];
    __shared__ int s_src[64];    // padded entries = -3
    __shared__ int s_dst[66];    // PRE-MULTIPLIED by 64; [64],[65] = 0 pad
    __shared__ int s_prevs, s_nexts;
    int tid = threadIdx.x;
    int p0 = blockIdx.x * 64;

    if (tid < 64) {
        int p = p0 + tid;
        int e = -1, s = -3, d64 = 0; float C = 0.f;
        if (p < E) {
            uint4 v = esd[p];
            s = (int)v.x; d64 = (int)v.y; e = (int)v.z; C = __uint_as_float(v.w);
        }
        s_e[tid] = e; s_src[tid] = s; s_dst[tid] = d64; s_C[tid] = C;
        if (tid < 2) s_dst[64 + tid] = 0;
        if (tid == 0) {
            s_prevs = (p0 > 0) ? (int)esd[p0 - 1].x : -2;
            s_nexts = (p0 + 64 < E) ? (int)esd[p0 + 64].x : -2;
        }
    }
    __syncthreads();

    {   // stage rbf: s_act[j][k], fp16
        int j = tid >> 2;
        int kk = (tid & 3) * 8;
        int e = s_e[j];
        float4 v0 = make_float4(0.f, 0.f, 0.f, 0.f), v1 = v0;
        if (e >= 0) {
            v0 = *(const float4*)(radial + (size_t)e * 32 + kk);
            v1 = *(const float4*)(radial + (size_t)e * 32 + kk + 4);
        }
        __half2* dst = (__half2*)&s_act[j * AROW + kk];
        dst[0] = __floats2half2_rn(v0.x, v0.y);
        dst[1] = __floats2half2_rn(v0.z, v0.w);
        dst[2] = __floats2half2_rn(v1.x, v1.y);
        dst[3] = __floats2half2_rn(v1.z, v1.w);
    }
    __syncthreads();

    int w = tid >> 6;
    int lane = tid & 63;
    int l15 = lane & 15, lg = lane >> 4;
    const int row0 = w * 16;
    const int arow = (row0 + l15) * AROW;
    const int orow = (row0 + lg * 4) * AROW;
    const f16x8* WF = (const f16x8*)Wf;
    const f32x4 zacc = {0.f, 0.f, 0.f, 0.f};

    // ---- layer 1: 32 -> 64
    {
        f16x8 a = *(const f16x8*)&s_act[arow + lg * 8];
        f32x4 acc[4];
#pragma unroll
        for (int ct = 0; ct < 4; ++ct)
            acc[ct] = __builtin_amdgcn_mfma_f32_16x16x32_f16(a, WF[ct * 64 + lane], zacc, 0, 0, 0);
        __syncthreads();
#pragma unroll
        for (int ct = 0; ct < 4; ++ct) {
            int o = ct * 16 + l15;
            float bias = b1[o];
#pragma unroll
            for (int r = 0; r < 4; ++r)
                s_act[orow + r * AROW + o] = __float2half(silu_f(acc[ct][r] + bias));
        }
        __syncthreads();
    }

    // ---- layer 2: 64 -> 128
    {
        f16x8 a0 = *(const f16x8*)&s_act[arow + 0 * 32 + lg * 8];
        f16x8 a1 = *(const f16x8*)&s_act[arow + 1 * 32 + lg * 8];
        f32x4 acc[8];
#pragma unroll
        for (int ct = 0; ct < 8; ++ct) {
            acc[ct] = __builtin_amdgcn_mfma_f32_16x16x32_f16(a0, WF[(4 + ct * 2 + 0) * 64 + lane], zacc, 0, 0, 0);
            acc[ct] = __builtin_amdgcn_mfma_f32_16x16x32_f16(a1, WF[(4 + ct * 2 + 1) * 64 + lane], acc[ct], 0, 0, 0);
        }
        __syncthreads();
#pragma unroll
        for (int ct = 0; ct < 8; ++ct) {
            int o = ct * 16 + l15;
            float bias = b2[o];
#pragma unroll
            for (int r = 0; r < 4; ++r)
                s_act[orow + r * AROW + o] = __float2half(silu_f(acc[ct][r] + bias));
        }
        __syncthreads();
    }

    // ---- layer 3: 128 -> 192 (raw col o -> stored col (o%3)*64 + o/3)
    {
        f16x8 a[4];
#pragma unroll
        for (int ks = 0; ks < 4; ++ks)
            a[ks] = *(const f16x8*)&s_act[arow + ks * 32 + lg * 8];
        float Cr[4];
#pragma unroll
        for (int r = 0; r < 4; ++r) Cr[r] = s_C[row0 + lg * 4 + r];
        __syncthreads();
#pragma unroll
        for (int ct = 0; ct < 12; ++ct) {
            f32x4 acc = zacc;
#pragma unroll
            for (int ks = 0; ks < 4; ++ks)
                acc = __builtin_amdgcn_mfma_f32_16x16x32_f16(a[ks], WF[(20 + ct * 4 + ks) * 64 + lane], acc, 0, 0, 0);
            int o = ct * 16 + l15;
            float bias = b3[o];
            int f = o / 3;
            int cmp = o - f * 3;
            int col = cmp * 64 + f;
#pragma unroll
            for (int r = 0; r < 4; ++r)
                s_act[orow + r * AROW + col] = __float2half(silu_f(acc[r] + bias) * Cr[r]);
        }
        __syncthreads();
    }

    // ---- message pass: 4 streams/wave, depth-2 prefetch, fp16 pk-fma accum
    {
        int wv = __builtin_amdgcn_readfirstlane(w);
        size_t slab = (size_t)N * 64;
        int jmax = min(64, E - p0);
        const __half2 Zh = __floats2half2_rn(0.f, 0.f);
        unsigned ulane = (unsigned)lane;

        if (wv == 2) {
            const uint2* T4 = Tg456;
            auto flush3 = [&](int cur, int js, int je, __half2 a45, __half2 a6) {
                bool lb = (js == 0) ? (s_prevs != cur) : (s_src[js - 1] != cur);
                bool rb = (je == 64) ? (s_nexts != cur) : (s_src[je] != cur);
                size_t b = (size_t)cur * 64 + lane;
                if (lb && rb) {
                    msgP[3 * slab + b] = a45;
                    msgP[4 * slab + b] = a6;
                } else {
                    pk_add_f16(&msgP[3 * slab + b], a45);
                    pk_add_f16(&msgP[4 * slab + b], a6);
                }
            };
            __half2 A00 = Zh, A01 = Zh, A10 = Zh, A11 = Zh;
            __half2 A20 = Zh, A21 = Zh, A30 = Zh, A31 = Zh;
            int cur0 = -1, cur1 = -1, cur2 = -1, cur3 = -1;
            int js0 = 0, js1 = 0, js2 = 0, js3 = 0;
            uint2 ta0 = make_uint2(0, 0), ta1 = ta0, ta2 = ta0, ta3 = ta0;
            uint2 tb0 = ta0, tb1 = ta0, tb2 = ta0, tb3 = ta0;

            if (jmax == 64) {
                // ---- full-block path: no bounds checks, full unroll
                ta0 = T4[(unsigned)s_dst[0]  + ulane];
                ta1 = T4[(unsigned)s_dst[16] + ulane];
                ta2 = T4[(unsigned)s_dst[32] + ulane];
                ta3 = T4[(unsigned)s_dst[48] + ulane];
                tb0 = T4[(unsigned)s_dst[1]  + ulane];
                tb1 = T4[(unsigned)s_dst[17] + ulane];
                tb2 = T4[(unsigned)s_dst[33] + ulane];
                tb3 = T4[(unsigned)s_dst[49] + ulane];
#define MS3F(BASE, CUR, JS, A45, A6, TVA, TVB) { \
                int j = (BASE) + t; \
                uint2 tvc = TVA; TVA = TVB; \
                if (t < 14) TVB = T4[(unsigned)s_dst[j + 2] + ulane]; \
                int s = __builtin_amdgcn_readfirstlane(s_src[j]); \
                if (s != CUR) { if (CUR >= 0) flush3(CUR, JS, j, A45, A6); \
                                CUR = s; JS = j; A45 = Zh; A6 = Zh; } \
                __half rfh = s_act[j * AROW + 128 + lane]; \
                __half2 rf2 = __halves2half2(rfh, rfh); \
                A45 = __hfma2(rf2, *(__half2*)&tvc.x, A45); \
                A6  = __hfma2(rf2, *(__half2*)&tvc.y, A6); }
#pragma unroll
                for (int t = 0; t < 16; ++t) {
                    MS3F(0,  cur0, js0, A00, A01, ta0, tb0)
                    MS3F(16, cur1, js1, A10, A11, ta1, tb1)
                    MS3F(32, cur2, js2, A20, A21, ta2, tb2)
                    MS3F(48, cur3, js3, A30, A31, ta3, tb3)
                }
#undef MS3F
                if (cur0 >= 0) flush3(cur0, js0, 16, A00, A01);
                if (cur1 >= 0) flush3(cur1, js1, 32, A10, A11);
                if (cur2 >= 0) flush3(cur2, js2, 48, A20, A21);
                if (cur3 >= 0) flush3(cur3, js3, 64, A30, A31);
            } else {
                // ---- partial-block path (guarded)
                if (0 < jmax)  ta0 = T4[(size_t)s_dst[0]  + lane];
                if (16 < jmax) ta1 = T4[(size_t)s_dst[16] + lane];
                if (32 < jmax) ta2 = T4[(size_t)s_dst[32] + lane];
                if (48 < jmax) ta3 = T4[(size_t)s_dst[48] + lane];
                if (1 < jmax)  tb0 = T4[(size_t)s_dst[1]  + lane];
                if (17 < jmax) tb1 = T4[(size_t)s_dst[17] + lane];
                if (33 < jmax) tb2 = T4[(size_t)s_dst[33] + lane];
                if (49 < jmax) tb3 = T4[(size_t)s_dst[49] + lane];
#define MS3(BASE, CUR, JS, A45, A6, TVA, TVB) { \
                int j = (BASE) + t; \
                if (j < jmax) { \
                    uint2 tvc = TVA; TVA = TVB; \
                    int jn = j + 2; \
                    if (jn < (BASE) + 16 && jn < jmax) \
                        TVB = T4[(size_t)s_dst[jn] + lane]; \
                    int s = __builtin_amdgcn_readfirstlane(s_src[j]); \
                    if (s != CUR) { if (CUR >= 0) flush3(CUR, JS, j, A45, A6); \
                                    CUR = s; JS = j; A45 = Zh; A6 = Zh; } \
                    __half rfh = s_act[j * AROW + 128 + lane]; \
                    __half2 rf2 = __halves2half2(rfh, rfh); \
                    A45 = __hfma2(rf2, *(__half2*)&tvc.x, A45); \
                    A6  = __hfma2(rf2, *(__half2*)&tvc.y, A6); \
                } }
#pragma unroll 4
                for (int t = 0; t < 16; ++t) {
                    MS3(0,  cur0, js0, A00, A01, ta0, tb0)
                    MS3(16, cur1, js1, A10, A11, ta1, tb1)
                    MS3(32, cur2, js2, A20, A21, ta2, tb2)
                    MS3(48, cur3, js3, A30, A31, ta3, tb3)
                }
#undef MS3
                if (cur0 >= 0) flush3(cur0, js0, min(16, jmax), A00, A01);
                if (cur1 >= 0) flush3(cur1, js1, min(32, jmax), A10, A11);
                if (cur2 >= 0) flush3(cur2, js2, min(48, jmax), A20, A21);
                if (cur3 >= 0) flush3(cur3, js3, min(64, jmax), A30, A31);
            }
        } else {
            // TgP slab & msg slab: wave0 -> 0 {0,1}, wave1 -> 1 {2,3},
            // wave3 -> 2 {7,8}
            int sl = (wv == 0) ? 0 : ((wv == 1) ? 1 : 2);
            int offA = (wv == 0) ? lane : ((wv == 1) ? (64 + lane) : (128 + lane));
            int offB = 64 + lane;     // only used by wave0
            bool W0 = (wv == 0);
            const unsigned int* TP = (const unsigned int*)TgP + (size_t)sl * slab;
            auto flush2 = [&](int cur, int js, int je, __half2 a) {
                bool lb = (js == 0) ? (s_prevs != cur) : (s_src[js - 1] != cur);
                bool rb = (je == 64) ? (s_nexts != cur) : (s_src[je] != cur);
                size_t b = (size_t)cur * 64 + lane;
                if (lb && rb) {
                    msgP[(size_t)sl * slab + b] = a;
                } else {
                    pk_add_f16(&msgP[(size_t)sl * slab + b], a);
                }
            };
            __half2 A0 = Zh, A1 = Zh, A2 = Zh, A3 = Zh;
            int cur0 = -1, cur1 = -1, cur2 = -1, cur3 = -1;
            int js0 = 0, js1 = 0, js2 = 0, js3 = 0;
            unsigned int ta0 = 0, ta1 = 0, ta2 = 0, ta3 = 0;
            unsigned int tb0 = 0, tb1 = 0, tb2 = 0, tb3 = 0;

            if (jmax == 64) {
                // ---- full-block path: no bounds checks, full unroll
                ta0 = TP[(unsigned)s_dst[0]  + ulane];
                ta1 = TP[(unsigned)s_dst[16] + ulane];
                ta2 = TP[(unsigned)s_dst[32] + ulane];
                ta3 = TP[(unsigned)s_dst[48] + ulane];
                tb0 = TP[(unsigned)s_dst[1]  + ulane];
                tb1 = TP[(unsigned)s_dst[17] + ulane];
                tb2 = TP[(unsigned)s_dst[33] + ulane];
                tb3 = TP[(unsigned)s_dst[49] + ulane];
#define MS2F(BASE, CUR, JS, A, TVA, TVB) { \
                int j = (BASE) + t; \
                unsigned int tvc = TVA; TVA = TVB; \
                if (t < 14) TVB = TP[(unsigned)s_dst[j + 2] + ulane]; \
                int s = __builtin_amdgcn_readfirstlane(s_src[j]); \
                if (s != CUR) { if (CUR >= 0) flush2(CUR, JS, j, A); \
                                CUR = s; JS = j; A = Zh; } \
                __half rfa = s_act[j * AROW + offA]; \
                __half rfb = W0 ? s_act[j * AROW + offB] : rfa; \
                A = __hfma2(__halves2half2(rfa, rfb), *(__half2*)&tvc, A); }
#pragma unroll
                for (int t = 0; t < 16; ++t) {
                    MS2F(0,  cur0, js0, A0, ta0, tb0)
                    MS2F(16, cur1, js1, A1, ta1, tb1)
                    MS2F(32, cur2, js2, A2, ta2, tb2)
                    MS2F(48, cur3, js3, A3, ta3, tb3)
                }
#undef MS2F
                if (cur0 >= 0) flush2(cur0, js0, 16, A0);
                if (cur1 >= 0) flush2(cur1, js1, 32, A1);
                if (cur2 >= 0) flush2(cur2, js2, 48, A2);
                if (cur3 >= 0) flush2(cur3, js3, 64, A3);
            } else {
                // ---- partial-block path (guarded)
                if (0 < jmax)  ta0 = TP[(size_t)s_dst[0]  + lane];
                if (16 < jmax) ta1 = TP[(size_t)s_dst[16] + lane];
                if (32 < jmax) ta2 = TP[(size_t)s_dst[32] + lane];
                if (48 < jmax) ta3 = TP[(size_t)s_dst[48] + lane];
                if (1 < jmax)  tb0 = TP[(size_t)s_dst[1]  + lane];
                if (17 < jmax) tb1 = TP[(size_t)s_dst[17] + lane];
                if (33 < jmax) tb2 = TP[(size_t)s_dst[33] + lane];
                if (49 < jmax) tb3 = TP[(size_t)s_dst[49] + lane];
#define MS2(BASE, CUR, JS, A, TVA, TVB) { \
                int j = (BASE) + t; \
                if (j < jmax) { \
                    unsigned int tvc = TVA; TVA = TVB; \
                    int jn = j + 2; \
                    if (jn < (BASE) + 16 && jn < jmax) \
                        TVB = TP[(size_t)s_dst[jn] + lane]; \
                    int s = __builtin_amdgcn_readfirstlane(s_src[j]); \
                    if (s != CUR) { if (CUR >= 0) flush2(CUR, JS, j, A); \
                                    CUR = s; JS = j; A = Zh; } \
                    __half rfa = s_act[j * AROW + offA]; \
                    __half rfb = W0 ? s_act[j * AROW + offB] : rfa; \
                    A = __hfma2(__halves2half2(rfa, rfb), *(__half2*)&tvc, A); \
                } }
#pragma unroll 4
                for (int t = 0; t < 16; ++t) {
                    MS2(0,  cur0, js0, A0, ta0, tb0)
                    MS2(16, cur1, js1, A1, ta1, tb1)
                    MS2(32, cur2, js2, A2, ta2, tb2)
                    MS2(48, cur3, js3, A3, ta3, tb3)
                }
#undef MS2
                if (cur0 >= 0) flush2(cur0, js0, min(16, jmax), A0);
                if (cur1 >= 0) flush2(cur1, js1, min(32, jmax), A1);
                if (cur2 >= 0) flush2(cur2, js2, min(48, jmax), A2);
                if (cur3 >= 0) flush2(cur3, js3, min(64, jmax), A3);
            }
        }
    }
}

// ---------------------------------------------------------------------------
// K_TAIL: fused node_mix + comp-GEMM#2 + out. 32 nodes per block.
// msg read from fp16 pair slabs; Y from TgP/Tg456.
// ---------------------------------------------------------------------------
__global__ __launch_bounds__(256) void k_tail(
    const __half2* __restrict__ msgP,
    const __half2* __restrict__ TgP, const uint2* __restrict__ Tg456,
    const float* __restrict__ X, const float* __restrict__ charges,
    const __half* __restrict__ Wfrag, float* __restrict__ out, int N)
{
    __shared__ __half u2l[9 * 32 * 72];   // 41.5 KB
    __shared__ float s_sc[32];
    int tid = threadIdx.x;
    int n0 = blockIdx.x * 32;
    size_t slab = (size_t)N * 64;

    if (tid < 32) {
        int n = n0 + tid;
        s_sc[tid] = (n < N) ? 1.0f + 0.1f * charges[n] : 0.f;
    }
    __syncthreads();

    // ---- phase 1: node mix
    for (int e = 0; e < 8; ++e) {
        int idx = e * 256 + tid;          // 0..2047
        int node = idx >> 6;
        int n = n0 + node;
        float um[9], uy[9];
        if (n < N) {
            size_t t = (size_t)n0 * 64 + idx;
            float2 m01 = __half22float2(msgP[0 * slab + t]);
            float2 m23 = __half22float2(msgP[1 * slab + t]);
            float2 m78 = __half22float2(msgP[2 * slab + t]);
            float2 m45 = __half22float2(msgP[3 * slab + t]);
            float2 m6_ = __half22float2(msgP[4 * slab + t]);
            um[0] = m01.x; um[1] = m01.y;
            um[2] = m23.x; um[3] = m23.y;
            um[4] = m45.x; um[5] = m45.y;
            um[6] = m6_.x;
            um[7] = m78.x; um[8] = m78.y;
            float2 p0 = __half22float2(TgP[0 * slab + t]);
            float2 p1 = __half22float2(TgP[1 * slab + t]);
            float2 p2 = __half22float2(TgP[2 * slab + t]);
            uint2 q = Tg456[t];
            float2 q0 = __half22float2(*(__half2*)&q.x);
            __half2 q1 = *(__half2*)&q.y;
            uy[0] = p0.x; uy[1] = p0.y;
            uy[2] = p1.x; uy[3] = p1.y;
            uy[4] = q0.x; uy[5] = q0.y;
            uy[6] = __half2float(q1.x);
            uy[7] = p2.x; uy[8] = p2.y;
        } else {
#pragma unroll
            for (int c = 0; c < 9; ++c) { um[c] = 0.f; uy[c] = 0.f; }
        }
        float M[9], Y[9];
        recon(um, M);
        recon(uy, Y);
        float P[9];
#pragma unroll
        for (int i = 0; i < 3; ++i)
#pragma unroll
            for (int j = 0; j < 3; ++j) {
                float s = 0.f;
#pragma unroll
                for (int k = 0; k < 3; ++k)
                    s += M[i * 3 + k] * Y[k * 3 + j] + Y[i * 3 + k] * M[k * 3 + j];
                P[i * 3 + j] = s;
            }
        float sc = s_sc[node];
        float nrm = 0.f;
#pragma unroll
        for (int i = 0; i < 9; ++i) { P[i] *= sc; nrm += P[i] * P[i]; }
        float inv = 1.0f / (nrm + 1.0f);
        float lam = (P[0] + P[4] + P[8]) * (1.f / 3.f);
        int f = idx & 63;
        u2l[(0 * 32 + node) * 72 + f] = __float2half(lam * inv);
        u2l[(1 * 32 + node) * 72 + f] = __float2half(0.5f * (P[1] - P[3]) * inv);
        u2l[(2 * 32 + node) * 72 + f] = __float2half(0.5f * (P[2] - P[6]) * inv);
        u2l[(3 * 32 + node) * 72 + f] = __float2half(0.5f * (P[5] - P[7]) * inv);
        u2l[(4 * 32 + node) * 72 + f] = __float2half((P[0] - lam) * inv);
        u2l[(5 * 32 + node) * 72 + f] = __float2half(0.5f * (P[1] + P[3]) * inv);
        u2l[(6 * 32 + node) * 72 + f] = __float2half(0.5f * (P[2] + P[6]) * inv);
        u2l[(7 * 32 + node) * 72 + f] = __float2half((P[4] - lam) * inv);
        u2l[(8 * 32 + node) * 72 + f] = __float2half(0.5f * (P[5] + P[7]) * inv);
    }
    __syncthreads();

    // ---- phase 2: GEMM (18 combos)
    int w = tid >> 6, lane = tid & 63;
    int l15 = lane & 15, lg = lane >> 4;
    const f32x4 z = {0.f, 0.f, 0.f, 0.f};
    f32x4 acc[5][4];
#pragma unroll
    for (int q = 0; q < 5; ++q) {
        int cm = w + q * 4;
        if (cm < 18) {
            int c = cm >> 1, rt = cm & 1;
            int gsel = (c == 0) ? 0 : (c < 4 ? 1 : 2);
            const f16x8* WFc = (const f16x8*)(Wfrag + gsel * WLFRAG);
            int abase = (c * 32 + rt * 16 + l15) * 72;
            f16x8 a0 = *(const f16x8*)&u2l[abase + lg * 8];
            f16x8 a1 = *(const f16x8*)&u2l[abase + 32 + lg * 8];
#pragma unroll
            for (int ct = 0; ct < 4; ++ct) {
                acc[q][ct] = __builtin_amdgcn_mfma_f32_16x16x32_f16(a0, WFc[(ct * 2 + 0) * 64 + lane], z, 0, 0, 0);
                acc[q][ct] = __builtin_amdgcn_mfma_f32_16x16x32_f16(a1, WFc[(ct * 2 + 1) * 64 + lane], acc[q][ct], 0, 0, 0);
            }
        }
    }
    __syncthreads();
#pragma unroll
    for (int q = 0; q < 5; ++q) {
        int cm = w + q * 4;
        if (cm < 18) {
            int c = cm >> 1, rt = cm & 1;
#pragma unroll
            for (int ct = 0; ct < 4; ++ct)
#pragma unroll
                for (int r = 0; r < 4; ++r)
                    u2l[(c * 32 + rt * 16 + lg * 4 + r) * 72 + ct * 16 + l15] =
                        __float2half(acc[q][ct][r]);
        }
    }
    __syncthreads();

    // ---- phase 3: out = Xn + dX + sc*dX@dX
    for (int e = 0; e < 8; ++e) {
        int idx = e * 256 + tid;
        int node = idx >> 6;
        int n = n0 + node;
        if (n >= N) continue;
        int f = idx & 63;
        float v[9];
#pragma unroll
        for (int c = 0; c < 9; ++c)
            v[c] = __half2float(u2l[(c * 32 + node) * 72 + f]);
        float dX[9];
        recon(v, dX);
        const float* xp = X + (size_t)n * 576 + f * 9;
        float m[9]; float n2 = 0.f;
#pragma unroll
        for (int i = 0; i < 9; ++i) { m[i] = xp[i]; n2 += m[i] * m[i]; }
        float invn = 1.0f / (n2 + 1.0f);
#pragma unroll
        for (int i = 0; i < 9; ++i) m[i] *= invn;
        float sc = s_sc[node];
        float* op = out + (size_t)n * 576 + f * 9;
#pragma unroll
        for (int i = 0; i < 3; ++i)
#pragma unroll
            for (int j = 0; j < 3; ++j) {
                float s = 0.f;
#pragma unroll
                for (int k = 0; k < 3; ++k) s += dX[i * 3 + k] * dX[k * 3 + j];
                op[i * 3 + j] = m[i * 3 + j] + dX[i * 3 + j] + sc * s;
            }
    }
}

// ---------------------------------------------------------------------------
extern "C" void kernel_launch(void* const* d_in, const int* in_sizes, int n_in,
                              void* d_out, int out_size, void* d_ws, size_t ws_size,
                              hipStream_t stream)
{
    const float* X       = (const float*)d_in[0];
    const int*   pair    = (const int*)d_in[1];
    const float* dij     = (const float*)d_in[2];
    const float* radial  = (const float*)d_in[3];
    const float* charges = (const float*)d_in[4];
    const float* W1  = (const float*)d_in[5];
    const float* b1  = (const float*)d_in[6];
    const float* W2  = (const float*)d_in[7];
    const float* b2  = (const float*)d_in[8];
    const float* W3  = (const float*)d_in[9];
    const float* b3  = (const float*)d_in[10];
    const float* Wl0 = (const float*)d_in[11];
    const float* Wl1 = (const float*)d_in[12];
    const float* Wl2 = (const float*)d_in[13];
    const float* Wl3 = (const float*)d_in[14];
    const float* Wl4 = (const float*)d_in[15];
    const float* Wl5 = (const float*)d_in[16];

    int N = in_sizes[4];
    int E = in_sizes[2];
    int nb_edge = (E + 63) / 64;
    int nb_node32 = (N + 31) / 32;
    size_t slab = (size_t)N * 64;

    __half2* msgP = (__half2*)d_ws;            // 5 slabs half2 (fp16 pairs)
    __half2* TgP  = msgP + 5 * slab;           // 3 slabs half2
    uint2* Tg456  = (uint2*)(TgP + 3 * slab);  // 1 slab uint2
    __half* Wf    = (__half*)(Tg456 + slab);   // 59392 halfs
    uint4* esd    = (uint4*)(Wf + MLPFRAGS + 6 * WLFRAG);
    int* ints   = (int*)(esd + E);
    int* count  = ints;
    int* off    = count + N;
    int* cursor = off + N + 1;

    hipMemsetAsync(count, 0, (size_t)N * sizeof(int), stream);
    hipMemsetAsync(msgP, 0, 5 * slab * sizeof(__half2), stream);

    int nWf = MLPFRAGS + 6 * WLFRAG;
    k_wcvt<<<(nWf + 255) / 256, 256, 0, stream>>>(W1, W2, W3,
                                                  Wl0, Wl1, Wl2, Wl3, Wl4, Wl5, Wf);
    k_head<<<nb_node32, 256, 0, stream>>>(X, Wf + MLPFRAGS, TgP, Tg456, N);

    k_hist<<<(E + 255) / 256, 256, 0, stream>>>(pair, count, E);
    k_scan<<<1, 1024, 0, stream>>>(count, off, cursor, N, E);
    k_scatter_sort<<<(E + 255) / 256, 256, 0, stream>>>(pair, dij, cursor, esd, E);

    k_edge_sorted<<<nb_edge, 256, 0, stream>>>(radial, esd,
                                               Wf, b1, b2, b3, TgP, Tg456,
                                               msgP, E, N);

    k_tail<<<nb_node32, 256, 0, stream>>>(msgP, TgP, Tg456, X, charges,
                                          Wf + MLPFRAGS + 3 * WLFRAG,
                                          (float*)d_out, N);
}

// Round 16
// 345.328 us; speedup vs baseline: 1.9811x; 1.0026x over previous
//
#include <hip/hip_runtime.h>
#include <hip/hip_fp16.h>
#include <math.h>

#ifndef M_PI
#define M_PI 3.14159265358979323846
#endif

// ---------------------------------------------------------------------------
// TensorNet interaction. fp32 math, fp16 LDS/gather/msg tensors, MFMA GEMMs.
// Compressed irreducible rep per (n,f): u[9] =
//   { lam, a01, a02, a12, s00, s01, s02, s11, s12 }   (s22 = -s00-s11)
//
// ws (~71 MB): msgP (5 fp16-pair slabs), TgP (3 fp16 comp-pair slabs),
// Tg456 (packed half4), Wf (fp16 MFMA frags), esd (packed edge recs), ints.
//
// Round-16 change: full-block message path prefetch depth 2 -> 3
// (12 gather loads in flight per wave; VGPR 52 -> ~64, still far under cap).
// Pre-commit: <4% delta => structure converged, declare roofline.
// ---------------------------------------------------------------------------

typedef _Float16 f16x8 __attribute__((ext_vector_type(8)));
typedef float f32x4 __attribute__((ext_vector_type(4)));

#define AROW 200        // halfs per activation row (400 B = 25*16)
#define MLPFRAGS 34816  // 68 frags * 512 halfs
#define WLFRAG 4096     // halfs per Wl matrix (8 frags * 512)

__device__ __forceinline__ float silu_f(float x) {
    return x / (1.0f + __expf(-x));
}

// HW packed-fp16 atomic add (no atomicAdd(__half2*) overload in ROCm 7.2)
__device__ __forceinline__ void pk_add_f16(__half2* addr, __half2 val) {
    asm volatile("global_atomic_pk_add_f16 %0, %1, off"
                 :: "v"(addr), "v"(val) : "memory");
}

__device__ __forceinline__ void recon(const float u[9], float M[9]) {
    M[0] =  u[0] + u[4];
    M[1] =  u[1] + u[5];
    M[2] =  u[2] + u[6];
    M[3] = -u[1] + u[5];
    M[4] =  u[0] + u[7];
    M[5] =  u[3] + u[8];
    M[6] = -u[2] + u[6];
    M[7] = -u[3] + u[8];
    M[8] =  u[0] - u[4] - u[7];
}

// ---------------------------------------------------------------------------
// Weight -> fp16 MFMA-fragment conversion (once per launch).
// Fragment element (lane l, j) = W[ct*16+(l&15)][ks*32+(l>>4)*8+j].
// ---------------------------------------------------------------------------
__global__ __launch_bounds__(256) void k_wcvt(
    const float* __restrict__ W1, const float* __restrict__ W2,
    const float* __restrict__ W3,
    const float* __restrict__ Wl0, const float* __restrict__ Wl1,
    const float* __restrict__ Wl2, const float* __restrict__ Wl3,
    const float* __restrict__ Wl4, const float* __restrict__ Wl5,
    __half* __restrict__ Wf)
{
    int idx = blockIdx.x * 256 + threadIdx.x;
    if (idx >= MLPFRAGS + 6 * WLFRAG) return;
    float v;
    if (idx < MLPFRAGS) {
        int frag = idx >> 9;
        int r = idx & 511;
        int l = r >> 3, j = r & 7;
        int l15 = l & 15, lg = l >> 4;
        if (frag < 4) {
            int ct = frag;
            v = W1[(ct * 16 + l15) * 32 + (lg * 8 + j)];
        } else if (frag < 20) {
            int f2 = frag - 4;
            int ct = f2 >> 1, ks = f2 & 1;
            v = W2[(ct * 16 + l15) * 64 + (ks * 32 + lg * 8 + j)];
        } else {
            int f3 = frag - 20;
            int ct = f3 >> 2, ks = f3 & 3;
            v = W3[(ct * 16 + l15) * 128 + (ks * 32 + lg * 8 + j)];
        }
    } else {
        int r2 = idx - MLPFRAGS;
        int wIdx = r2 >> 12;           // /4096
        int rr = r2 & 4095;
        int f = rr >> 9;               // ct*2+ks
        int ct = f >> 1, ks = f & 1;
        int elem = rr & 511;
        int l = elem >> 3, j = elem & 7;
        int l15 = l & 15, lg = l >> 4;
        const float* W = (wIdx == 0) ? Wl0 : (wIdx == 1) ? Wl1 : (wIdx == 2) ? Wl2
                       : (wIdx == 3) ? Wl3 : (wIdx == 4) ? Wl4 : Wl5;
        v = W[(ct * 16 + l15) * 64 + (ks * 32 + lg * 8 + j)];
    }
    Wf[idx] = __float2half(v);
}

// ---------------------------------------------------------------------------
// K_HEAD: fused node_prep + comp-GEMM#1 + T-convert. 32 nodes per block.
// ---------------------------------------------------------------------------
__global__ __launch_bounds__(256) void k_head(
    const float* __restrict__ X, const __half* __restrict__ Wfrag,
    __half2* __restrict__ TgP, uint2* __restrict__ Tg456, int N)
{
    __shared__ __half u2l[9 * 32 * 72];   // 41.5 KB
    __shared__ float s_x[2304];           // 9.2 KB (4 nodes)
    int tid = threadIdx.x;
    int n0 = blockIdx.x * 32;
    size_t total = (size_t)N * 576;

    // ---- phase 1: prep 8 chunks of 4 nodes
    for (int ch = 0; ch < 8; ++ch) {
        size_t base = (size_t)(n0 + ch * 4) * 576;
        for (int idx = tid; idx < 2304; idx += 256) {
            size_t gi = base + idx;
            s_x[idx] = (gi < total) ? X[gi] : 0.f;
        }
        __syncthreads();
        int w = tid >> 6, f = tid & 63;
        int node = ch * 4 + w;
        float m[9]; float n2 = 0.f;
#pragma unroll
        for (int i = 0; i < 9; ++i) { m[i] = s_x[w * 576 + f * 9 + i]; n2 += m[i] * m[i]; }
        float inv = 1.0f / (n2 + 1.0f);
#pragma unroll
        for (int i = 0; i < 9; ++i) m[i] *= inv;
        float lam = (m[0] + m[4] + m[8]) * (1.f / 3.f);
        u2l[(0 * 32 + node) * 72 + f] = __float2half(lam);
        u2l[(1 * 32 + node) * 72 + f] = __float2half(0.5f * (m[1] - m[3]));
        u2l[(2 * 32 + node) * 72 + f] = __float2half(0.5f * (m[2] - m[6]));
        u2l[(3 * 32 + node) * 72 + f] = __float2half(0.5f * (m[5] - m[7]));
        u2l[(4 * 32 + node) * 72 + f] = __float2half(m[0] - lam);
        u2l[(5 * 32 + node) * 72 + f] = __float2half(0.5f * (m[1] + m[3]));
        u2l[(6 * 32 + node) * 72 + f] = __float2half(0.5f * (m[2] + m[6]));
        u2l[(7 * 32 + node) * 72 + f] = __float2half(m[4] - lam);
        u2l[(8 * 32 + node) * 72 + f] = __float2half(0.5f * (m[5] + m[7]));
        __syncthreads();
    }

    // ---- phase 2: GEMM (18 combos = comp c x row-tile rt), in-place
    int w = tid >> 6, lane = tid & 63;
    int l15 = lane & 15, lg = lane >> 4;
    const f32x4 z = {0.f, 0.f, 0.f, 0.f};
    f32x4 acc[5][4];
#pragma unroll
    for (int q = 0; q < 5; ++q) {
        int cm = w + q * 4;
        if (cm < 18) {
            int c = cm >> 1, rt = cm & 1;
            int gsel = (c == 0) ? 0 : (c < 4 ? 1 : 2);
            const f16x8* WFc = (const f16x8*)(Wfrag + gsel * WLFRAG);
            int abase = (c * 32 + rt * 16 + l15) * 72;
            f16x8 a0 = *(const f16x8*)&u2l[abase + lg * 8];
            f16x8 a1 = *(const f16x8*)&u2l[abase + 32 + lg * 8];
#pragma unroll
            for (int ct = 0; ct < 4; ++ct) {
                acc[q][ct] = __builtin_amdgcn_mfma_f32_16x16x32_f16(a0, WFc[(ct * 2 + 0) * 64 + lane], z, 0, 0, 0);
                acc[q][ct] = __builtin_amdgcn_mfma_f32_16x16x32_f16(a1, WFc[(ct * 2 + 1) * 64 + lane], acc[q][ct], 0, 0, 0);
            }
        }
    }
    __syncthreads();
#pragma unroll
    for (int q = 0; q < 5; ++q) {
        int cm = w + q * 4;
        if (cm < 18) {
            int c = cm >> 1, rt = cm & 1;
#pragma unroll
            for (int ct = 0; ct < 4; ++ct)
#pragma unroll
                for (int r = 0; r < 4; ++r)
                    u2l[(c * 32 + rt * 16 + lg * 4 + r) * 72 + ct * 16 + l15] =
                        __float2half(acc[q][ct][r]);
        }
    }
    __syncthreads();

    // ---- phase 3: write gather layouts
    size_t slab = (size_t)N * 64;
    for (int e = 0; e < 8; ++e) {
        int idx = e * 256 + tid;
        int node = idx >> 6;
        int n = n0 + node;
        if (n >= N) continue;
        int f = idx & 63;
        size_t t = (size_t)n * 64 + f;
        const int pa[3] = {0, 2, 7};
#pragma unroll
        for (int pr = 0; pr < 3; ++pr) {
            __half a = u2l[(pa[pr] * 32 + node) * 72 + f];
            __half b = u2l[((pa[pr] + 1) * 32 + node) * 72 + f];
            TgP[(size_t)pr * slab + t] = __halves2half2(a, b);
        }
        __half2 lo = __halves2half2(u2l[(4 * 32 + node) * 72 + f],
                                    u2l[(5 * 32 + node) * 72 + f]);
        __half2 hi = __halves2half2(u2l[(6 * 32 + node) * 72 + f], __float2half(0.f));
        uint2 pk;
        pk.x = *(unsigned int*)&lo;
        pk.y = *(unsigned int*)&hi;
        Tg456[t] = pk;
    }
}

// ---------------------------------------------------------------------------
// CSR sort of edges by src: histogram -> scan -> ranked placement.
// ---------------------------------------------------------------------------
__global__ __launch_bounds__(256) void k_hist(
    const int* __restrict__ pair, int* __restrict__ count, int E)
{
    int e = blockIdx.x * 256 + threadIdx.x;
    if (e < E) atomicAdd(&count[pair[e]], 1);
}

__global__ __launch_bounds__(1024) void k_scan(
    const int* __restrict__ count, int* __restrict__ off,
    int* __restrict__ cursor, int N, int E)
{
    __shared__ int s[1024];
    __shared__ int s_carry;
    int tid = threadIdx.x;
    if (tid == 0) s_carry = 0;
    __syncthreads();
    const int CH = 32;
    for (int base = 0; base < N; base += 1024 * CH) {
        int b0 = base + tid * CH;
        int local[CH]; int sum = 0;
#pragma unroll
        for (int i = 0; i < CH; ++i) {
            int idx = b0 + i;
            int v = (idx < N) ? count[idx] : 0;
            local[i] = sum; sum += v;
        }
        s[tid] = sum;
        __syncthreads();
        for (int d = 1; d < 1024; d <<= 1) {
            int t2 = (tid >= d) ? s[tid - d] : 0;
            __syncthreads();
            s[tid] += t2;
            __syncthreads();
        }
        int excl0 = s_carry + s[tid] - sum;
#pragma unroll
        for (int i = 0; i < CH; ++i) {
            int idx = b0 + i;
            if (idx < N) { int e = excl0 + local[i]; off[idx] = e; cursor[idx] = e; }
        }
        __syncthreads();
        if (tid == 1023) s_carry += s[1023];
        __syncthreads();
    }
    if (tid == 0) off[N] = E;
}

// Packed edge record per sorted position: {src, dst*64, eOrig, C bits}
__global__ __launch_bounds__(256) void k_scatter_sort(
    const int* __restrict__ pair, const float* __restrict__ d_ij,
    int* __restrict__ cursor, uint4* __restrict__ esd, int E)
{
    int e = blockIdx.x * 256 + threadIdx.x;
    if (e < E) {
        int s = pair[e];
        int d = pair[(size_t)E + e];
        float dd = d_ij[e];
        float C = (dd < 5.0f) ? 0.5f * (cosf((float)M_PI * dd * 0.2f) + 1.0f) : 0.0f;
        int pos = atomicAdd(&cursor[s], 1);
        uint4 v;
        v.x = (unsigned int)s;
        v.y = (unsigned int)(d * 64);
        v.z = (unsigned int)e;
        v.w = __float_as_uint(C);
        esd[pos] = v;
    }
}

// ---------------------------------------------------------------------------
// K2: fused edge MLP on MFMA + 4-stream message pass with packed-fp16
// accumulation. Full blocks: unguarded fully-unrolled loop, 32-bit gather
// indices, prefetch depth 3. Partial blocks: guarded depth-2 path.
// ---------------------------------------------------------------------------
__global__ __launch_bounds__(256) void k_edge_sorted(
    const float* __restrict__ radial, const uint4* __restrict__ esd,
    const __half* __restrict__ Wf,
    const float* __restrict__ b1, const float* __restrict__ b2,
    const float* __restrict__ b3,
    const __half2* __restrict__ TgP, const uint2* __restrict__ Tg456,
    __half2* __restrict__ msgP, int E, int N)
{
    __shared__ __half s_act[64 * AROW];
    __shared__ float s_C[64];
    __shared__ int s_e[64];
    __shared__ int s_src[64];    // padded entries = -3
    __shared__ int s_dst[68];    // PRE-MULTIPLIED by 64; [64..67] = 0 pad
    __shared__ int s_prevs, s_nexts;
    int tid = threadIdx.x;
    int p0 = blockIdx.x * 64;

    if (tid < 64) {
        int p = p0 + tid;
        int e = -1, s = -3, d64 = 0; float C = 0.f;
        if (p < E) {
            uint4 v = esd[p];
            s = (int)v.x; d64 = (int)v.y; e = (int)v.z; C = __uint_as_float(v.w);
        }
        s_e[tid] = e; s_src[tid] = s; s_dst[tid] = d64; s_C[tid] = C;
        if (tid < 4) s_dst[64 + tid] = 0;
        if (tid == 0) {
            s_prevs = (p0 > 0) ? (int)esd[p0 - 1].x : -2;
            s_nexts = (p0 + 64 < E) ? (int)esd[p0 + 64].x : -2;
        }
    }
    __syncthreads();

    {   // stage rbf: s_act[j][k], fp16
        int j = tid >> 2;
        int kk = (tid & 3) * 8;
        int e = s_e[j];
        float4 v0 = make_float4(0.f, 0.f, 0.f, 0.f), v1 = v0;
        if (e >= 0) {
            v0 = *(const float4*)(radial + (size_t)e * 32 + kk);
            v1 = *(const float4*)(radial + (size_t)e * 32 + kk + 4);
        }
        __half2* dst = (__half2*)&s_act[j * AROW + kk];
        dst[0] = __floats2half2_rn(v0.x, v0.y);
        dst[1] = __floats2half2_rn(v0.z, v0.w);
        dst[2] = __floats2half2_rn(v1.x, v1.y);
        dst[3] = __floats2half2_rn(v1.z, v1.w);
    }
    __syncthreads();

    int w = tid >> 6;
    int lane = tid & 63;
    int l15 = lane & 15, lg = lane >> 4;
    const int row0 = w * 16;
    const int arow = (row0 + l15) * AROW;
    const int orow = (row0 + lg * 4) * AROW;
    const f16x8* WF = (const f16x8*)Wf;
    const f32x4 zacc = {0.f, 0.f, 0.f, 0.f};

    // ---- layer 1: 32 -> 64
    {
        f16x8 a = *(const f16x8*)&s_act[arow + lg * 8];
        f32x4 acc[4];
#pragma unroll
        for (int ct = 0; ct < 4; ++ct)
            acc[ct] = __builtin_amdgcn_mfma_f32_16x16x32_f16(a, WF[ct * 64 + lane], zacc, 0, 0, 0);
        __syncthreads();
#pragma unroll
        for (int ct = 0; ct < 4; ++ct) {
            int o = ct * 16 + l15;
            float bias = b1[o];
#pragma unroll
            for (int r = 0; r < 4; ++r)
                s_act[orow + r * AROW + o] = __float2half(silu_f(acc[ct][r] + bias));
        }
        __syncthreads();
    }

    // ---- layer 2: 64 -> 128
    {
        f16x8 a0 = *(const f16x8*)&s_act[arow + 0 * 32 + lg * 8];
        f16x8 a1 = *(const f16x8*)&s_act[arow + 1 * 32 + lg * 8];
        f32x4 acc[8];
#pragma unroll
        for (int ct = 0; ct < 8; ++ct) {
            acc[ct] = __builtin_amdgcn_mfma_f32_16x16x32_f16(a0, WF[(4 + ct * 2 + 0) * 64 + lane], zacc, 0, 0, 0);
            acc[ct] = __builtin_amdgcn_mfma_f32_16x16x32_f16(a1, WF[(4 + ct * 2 + 1) * 64 + lane], acc[ct], 0, 0, 0);
        }
        __syncthreads();
#pragma unroll
        for (int ct = 0; ct < 8; ++ct) {
            int o = ct * 16 + l15;
            float bias = b2[o];
#pragma unroll
            for (int r = 0; r < 4; ++r)
                s_act[orow + r * AROW + o] = __float2half(silu_f(acc[ct][r] + bias));
        }
        __syncthreads();
    }

    // ---- layer 3: 128 -> 192 (raw col o -> stored col (o%3)*64 + o/3)
    {
        f16x8 a[4];
#pragma unroll
        for (int ks = 0; ks < 4; ++ks)
            a[ks] = *(const f16x8*)&s_act[arow + ks * 32 + lg * 8];
        float Cr[4];
#pragma unroll
        for (int r = 0; r < 4; ++r) Cr[r] = s_C[row0 + lg * 4 + r];
        __syncthreads();
#pragma unroll
        for (int ct = 0; ct < 12; ++ct) {
            f32x4 acc = zacc;
#pragma unroll
            for (int ks = 0; ks < 4; ++ks)
                acc = __builtin_amdgcn_mfma_f32_16x16x32_f16(a[ks], WF[(20 + ct * 4 + ks) * 64 + lane], acc, 0, 0, 0);
            int o = ct * 16 + l15;
            float bias = b3[o];
            int f = o / 3;
            int cmp = o - f * 3;
            int col = cmp * 64 + f;
#pragma unroll
            for (int r = 0; r < 4; ++r)
                s_act[orow + r * AROW + col] = __float2half(silu_f(acc[r] + bias) * Cr[r]);
        }
        __syncthreads();
    }

    // ---- message pass: 4 streams/wave, fp16 pk-fma accum
    {
        int wv = __builtin_amdgcn_readfirstlane(w);
        size_t slab = (size_t)N * 64;
        int jmax = min(64, E - p0);
        const __half2 Zh = __floats2half2_rn(0.f, 0.f);
        unsigned ulane = (unsigned)lane;

        if (wv == 2) {
            const uint2* T4 = Tg456;
            auto flush3 = [&](int cur, int js, int je, __half2 a45, __half2 a6) {
                bool lb = (js == 0) ? (s_prevs != cur) : (s_src[js - 1] != cur);
                bool rb = (je == 64) ? (s_nexts != cur) : (s_src[je] != cur);
                size_t b = (size_t)cur * 64 + lane;
                if (lb && rb) {
                    msgP[3 * slab + b] = a45;
                    msgP[4 * slab + b] = a6;
                } else {
                    pk_add_f16(&msgP[3 * slab + b], a45);
                    pk_add_f16(&msgP[4 * slab + b], a6);
                }
            };
            __half2 A00 = Zh, A01 = Zh, A10 = Zh, A11 = Zh;
            __half2 A20 = Zh, A21 = Zh, A30 = Zh, A31 = Zh;
            int cur0 = -1, cur1 = -1, cur2 = -1, cur3 = -1;
            int js0 = 0, js1 = 0, js2 = 0, js3 = 0;
            uint2 ta0 = make_uint2(0, 0), ta1 = ta0, ta2 = ta0, ta3 = ta0;
            uint2 tb0 = ta0, tb1 = ta0, tb2 = ta0, tb3 = ta0;
            uint2 tc0 = ta0, tc1 = ta0, tc2 = ta0, tc3 = ta0;

            if (jmax == 64) {
                // ---- full-block path: depth-3 prefetch, full unroll
                ta0 = T4[(unsigned)s_dst[0]  + ulane];
                ta1 = T4[(unsigned)s_dst[16] + ulane];
                ta2 = T4[(unsigned)s_dst[32] + ulane];
                ta3 = T4[(unsigned)s_dst[48] + ulane];
                tb0 = T4[(unsigned)s_dst[1]  + ulane];
                tb1 = T4[(unsigned)s_dst[17] + ulane];
                tb2 = T4[(unsigned)s_dst[33] + ulane];
                tb3 = T4[(unsigned)s_dst[49] + ulane];
                tc0 = T4[(unsigned)s_dst[2]  + ulane];
                tc1 = T4[(unsigned)s_dst[18] + ulane];
                tc2 = T4[(unsigned)s_dst[34] + ulane];
                tc3 = T4[(unsigned)s_dst[50] + ulane];
#define MS3F(BASE, CUR, JS, A45, A6, TVA, TVB, TVC) { \
                int j = (BASE) + t; \
                uint2 tvc = TVA; TVA = TVB; TVB = TVC; \
                if (t < 13) TVC = T4[(unsigned)s_dst[j + 3] + ulane]; \
                int s = __builtin_amdgcn_readfirstlane(s_src[j]); \
                if (s != CUR) { if (CUR >= 0) flush3(CUR, JS, j, A45, A6); \
                                CUR = s; JS = j; A45 = Zh; A6 = Zh; } \
                __half rfh = s_act[j * AROW + 128 + lane]; \
                __half2 rf2 = __halves2half2(rfh, rfh); \
                A45 = __hfma2(rf2, *(__half2*)&tvc.x, A45); \
                A6  = __hfma2(rf2, *(__half2*)&tvc.y, A6); }
#pragma unroll
                for (int t = 0; t < 16; ++t) {
                    MS3F(0,  cur0, js0, A00, A01, ta0, tb0, tc0)
                    MS3F(16, cur1, js1, A10, A11, ta1, tb1, tc1)
                    MS3F(32, cur2, js2, A20, A21, ta2, tb2, tc2)
                    MS3F(48, cur3, js3, A30, A31, ta3, tb3, tc3)
                }
#undef MS3F
                if (cur0 >= 0) flush3(cur0, js0, 16, A00, A01);
                if (cur1 >= 0) flush3(cur1, js1, 32, A10, A11);
                if (cur2 >= 0) flush3(cur2, js2, 48, A20, A21);
                if (cur3 >= 0) flush3(cur3, js3, 64, A30, A31);
            } else {
                // ---- partial-block path (guarded, depth 2)
                if (0 < jmax)  ta0 = T4[(size_t)s_dst[0]  + lane];
                if (16 < jmax) ta1 = T4[(size_t)s_dst[16] + lane];
                if (32 < jmax) ta2 = T4[(size_t)s_dst[32] + lane];
                if (48 < jmax) ta3 = T4[(size_t)s_dst[48] + lane];
                if (1 < jmax)  tb0 = T4[(size_t)s_dst[1]  + lane];
                if (17 < jmax) tb1 = T4[(size_t)s_dst[17] + lane];
                if (33 < jmax) tb2 = T4[(size_t)s_dst[33] + lane];
                if (49 < jmax) tb3 = T4[(size_t)s_dst[49] + lane];
#define MS3(BASE, CUR, JS, A45, A6, TVA, TVB) { \
                int j = (BASE) + t; \
                if (j < jmax) { \
                    uint2 tvc = TVA; TVA = TVB; \
                    int jn = j + 2; \
                    if (jn < (BASE) + 16 && jn < jmax) \
                        TVB = T4[(size_t)s_dst[jn] + lane]; \
                    int s = __builtin_amdgcn_readfirstlane(s_src[j]); \
                    if (s != CUR) { if (CUR >= 0) flush3(CUR, JS, j, A45, A6); \
                                    CUR = s; JS = j; A45 = Zh; A6 = Zh; } \
                    __half rfh = s_act[j * AROW + 128 + lane]; \
                    __half2 rf2 = __halves2half2(rfh, rfh); \
                    A45 = __hfma2(rf2, *(__half2*)&tvc.x, A45); \
                    A6  = __hfma2(rf2, *(__half2*)&tvc.y, A6); \
                } }
#pragma unroll 4
                for (int t = 0; t < 16; ++t) {
                    MS3(0,  cur0, js0, A00, A01, ta0, tb0)
                    MS3(16, cur1, js1, A10, A11, ta1, tb1)
                    MS3(32, cur2, js2, A20, A21, ta2, tb2)
                    MS3(48, cur3, js3, A30, A31, ta3, tb3)
                }
#undef MS3
                if (cur0 >= 0) flush3(cur0, js0, min(16, jmax), A00, A01);
                if (cur1 >= 0) flush3(cur1, js1, min(32, jmax), A10, A11);
                if (cur2 >= 0) flush3(cur2, js2, min(48, jmax), A20, A21);
                if (cur3 >= 0) flush3(cur3, js3, min(64, jmax), A30, A31);
            }
        } else {
            int sl = (wv == 0) ? 0 : ((wv == 1) ? 1 : 2);
            int offA = (wv == 0) ? lane : ((wv == 1) ? (64 + lane) : (128 + lane));
            int offB = 64 + lane;     // only used by wave0
            bool W0 = (wv == 0);
            const unsigned int* TP = (const unsigned int*)TgP + (size_t)sl * slab;
            auto flush2 = [&](int cur, int js, int je, __half2 a) {
                bool lb = (js == 0) ? (s_prevs != cur) : (s_src[js - 1] != cur);
                bool rb = (je == 64) ? (s_nexts != cur) : (s_src[je] != cur);
                size_t b = (size_t)cur * 64 + lane;
                if (lb && rb) {
                    msgP[(size_t)sl * slab + b] = a;
                } else {
                    pk_add_f16(&msgP[(size_t)sl * slab + b], a);
                }
            };
            __half2 A0 = Zh, A1 = Zh, A2 = Zh, A3 = Zh;
            int cur0 = -1, cur1 = -1, cur2 = -1, cur3 = -1;
            int js0 = 0, js1 = 0, js2 = 0, js3 = 0;
            unsigned int ta0 = 0, ta1 = 0, ta2 = 0, ta3 = 0;
            unsigned int tb0 = 0, tb1 = 0, tb2 = 0, tb3 = 0;
            unsigned int tc0 = 0, tc1 = 0, tc2 = 0, tc3 = 0;

            if (jmax == 64) {
                // ---- full-block path: depth-3 prefetch, full unroll
                ta0 = TP[(unsigned)s_dst[0]  + ulane];
                ta1 = TP[(unsigned)s_dst[16] + ulane];
                ta2 = TP[(unsigned)s_dst[32] + ulane];
                ta3 = TP[(unsigned)s_dst[48] + ulane];
                tb0 = TP[(unsigned)s_dst[1]  + ulane];
                tb1 = TP[(unsigned)s_dst[17] + ulane];
                tb2 = TP[(unsigned)s_dst[33] + ulane];
                tb3 = TP[(unsigned)s_dst[49] + ulane];
                tc0 = TP[(unsigned)s_dst[2]  + ulane];
                tc1 = TP[(unsigned)s_dst[18] + ulane];
                tc2 = TP[(unsigned)s_dst[34] + ulane];
                tc3 = TP[(unsigned)s_dst[50] + ulane];
#define MS2F(BASE, CUR, JS, A, TVA, TVB, TVC) { \
                int j = (BASE) + t; \
                unsigned int tvc = TVA; TVA = TVB; TVB = TVC; \
                if (t < 13) TVC = TP[(unsigned)s_dst[j + 3] + ulane]; \
                int s = __builtin_amdgcn_readfirstlane(s_src[j]); \
                if (s != CUR) { if (CUR >= 0) flush2(CUR, JS, j, A); \
                                CUR = s; JS = j; A = Zh; } \
                __half rfa = s_act[j * AROW + offA]; \
                __half rfb = W0 ? s_act[j * AROW + offB] : rfa; \
                A = __hfma2(__halves2half2(rfa, rfb), *(__half2*)&tvc, A); }
#pragma unroll
                for (int t = 0; t < 16; ++t) {
                    MS2F(0,  cur0, js0, A0, ta0, tb0, tc0)
                    MS2F(16, cur1, js1, A1, ta1, tb1, tc1)
                    MS2F(32, cur2, js2, A2, ta2, tb2, tc2)
                    MS2F(48, cur3, js3, A3, ta3, tb3, tc3)
                }
#undef MS2F
                if (cur0 >= 0) flush2(cur0, js0, 16, A0);
                if (cur1 >= 0) flush2(cur1, js1, 32, A1);
                if (cur2 >= 0) flush2(cur2, js2, 48, A2);
                if (cur3 >= 0) flush2(cur3, js3, 64, A3);
            } else {
                // ---- partial-block path (guarded, depth 2)
                if (0 < jmax)  ta0 = TP[(size_t)s_dst[0]  + lane];
                if (16 < jmax) ta1 = TP[(size_t)s_dst[16] + lane];
                if (32 < jmax) ta2 = TP[(size_t)s_dst[32] + lane];
                if (48 < jmax) ta3 = TP[(size_t)s_dst[48] + lane];
                if (1 < jmax)  tb0 = TP[(size_t)s_dst[1]  + lane];
                if (17 < jmax) tb1 = TP[(size_t)s_dst[17] + lane];
                if (33 < jmax) tb2 = TP[(size_t)s_dst[33] + lane];
                if (49 < jmax) tb3 = TP[(size_t)s_dst[49] + lane];
#define MS2(BASE, CUR, JS, A, TVA, TVB) { \
                int j = (BASE) + t; \
                if (j < jmax) { \
                    unsigned int tvc = TVA; TVA = TVB; \
                    int jn = j + 2; \
                    if (jn < (BASE) + 16 && jn < jmax) \
                        TVB = TP[(size_t)s_dst[jn] + lane]; \
                    int s = __builtin_amdgcn_readfirstlane(s_src[j]); \
                    if (s != CUR) { if (CUR >= 0) flush2(CUR, JS, j, A); \
                                    CUR = s; JS = j; A = Zh; } \
                    __half rfa = s_act[j * AROW + offA]; \
                    __half rfb = W0 ? s_act[j * AROW + offB] : rfa; \
                    A = __hfma2(__halves2half2(rfa, rfb), *(__half2*)&tvc, A); \
                } }
#pragma unroll 4
                for (int t = 0; t < 16; ++t) {
                    MS2(0,  cur0, js0, A0, ta0, tb0)
                    MS2(16, cur1, js1, A1, ta1, tb1)
                    MS2(32, cur2, js2, A2, ta2, tb2)
                    MS2(48, cur3, js3, A3, ta3, tb3)
                }
#undef MS2
                if (cur0 >= 0) flush2(cur0, js0, min(16, jmax), A0);
                if (cur1 >= 0) flush2(cur1, js1, min(32, jmax), A1);
                if (cur2 >= 0) flush2(cur2, js2, min(48, jmax), A2);
                if (cur3 >= 0) flush2(cur3, js3, min(64, jmax), A3);
            }
        }
    }
}

// ---------------------------------------------------------------------------
// K_TAIL: fused node_mix + comp-GEMM#2 + out. 32 nodes per block.
// msg read from fp16 pair slabs; Y from TgP/Tg456.
// ---------------------------------------------------------------------------
__global__ __launch_bounds__(256) void k_tail(
    const __half2* __restrict__ msgP,
    const __half2* __restrict__ TgP, const uint2* __restrict__ Tg456,
    const float* __restrict__ X, const float* __restrict__ charges,
    const __half* __restrict__ Wfrag, float* __restrict__ out, int N)
{
    __shared__ __half u2l[9 * 32 * 72];   // 41.5 KB
    __shared__ float s_sc[32];
    int tid = threadIdx.x;
    int n0 = blockIdx.x * 32;
    size_t slab = (size_t)N * 64;

    if (tid < 32) {
        int n = n0 + tid;
        s_sc[tid] = (n < N) ? 1.0f + 0.1f * charges[n] : 0.f;
    }
    __syncthreads();

    // ---- phase 1: node mix
    for (int e = 0; e < 8; ++e) {
        int idx = e * 256 + tid;          // 0..2047
        int node = idx >> 6;
        int n = n0 + node;
        float um[9], uy[9];
        if (n < N) {
            size_t t = (size_t)n0 * 64 + idx;
            float2 m01 = __half22float2(msgP[0 * slab + t]);
            float2 m23 = __half22float2(msgP[1 * slab + t]);
            float2 m78 = __half22float2(msgP[2 * slab + t]);
            float2 m45 = __half22float2(msgP[3 * slab + t]);
            float2 m6_ = __half22float2(msgP[4 * slab + t]);
            um[0] = m01.x; um[1] = m01.y;
            um[2] = m23.x; um[3] = m23.y;
            um[4] = m45.x; um[5] = m45.y;
            um[6] = m6_.x;
            um[7] = m78.x; um[8] = m78.y;
            float2 p0 = __half22float2(TgP[0 * slab + t]);
            float2 p1 = __half22float2(TgP[1 * slab + t]);
            float2 p2 = __half22float2(TgP[2 * slab + t]);
            uint2 q = Tg456[t];
            float2 q0 = __half22float2(*(__half2*)&q.x);
            __half2 q1 = *(__half2*)&q.y;
            uy[0] = p0.x; uy[1] = p0.y;
            uy[2] = p1.x; uy[3] = p1.y;
            uy[4] = q0.x; uy[5] = q0.y;
            uy[6] = __half2float(q1.x);
            uy[7] = p2.x; uy[8] = p2.y;
        } else {
#pragma unroll
            for (int c = 0; c < 9; ++c) { um[c] = 0.f; uy[c] = 0.f; }
        }
        float M[9], Y[9];
        recon(um, M);
        recon(uy, Y);
        float P[9];
#pragma unroll
        for (int i = 0; i < 3; ++i)
#pragma unroll
            for (int j = 0; j < 3; ++j) {
                float s = 0.f;
#pragma unroll
                for (int k = 0; k < 3; ++k)
                    s += M[i * 3 + k] * Y[k * 3 + j] + Y[i * 3 + k] * M[k * 3 + j];
                P[i * 3 + j] = s;
            }
        float sc = s_sc[node];
        float nrm = 0.f;
#pragma unroll
        for (int i = 0; i < 9; ++i) { P[i] *= sc; nrm += P[i] * P[i]; }
        float inv = 1.0f / (nrm + 1.0f);
        float lam = (P[0] + P[4] + P[8]) * (1.f / 3.f);
        int f = idx & 63;
        u2l[(0 * 32 + node) * 72 + f] = __float2half(lam * inv);
        u2l[(1 * 32 + node) * 72 + f] = __float2half(0.5f * (P[1] - P[3]) * inv);
        u2l[(2 * 32 + node) * 72 + f] = __float2half(0.5f * (P[2] - P[6]) * inv);
        u2l[(3 * 32 + node) * 72 + f] = __float2half(0.5f * (P[5] - P[7]) * inv);
        u2l[(4 * 32 + node) * 72 + f] = __float2half((P[0] - lam) * inv);
        u2l[(5 * 32 + node) * 72 + f] = __float2half(0.5f * (P[1] + P[3]) * inv);
        u2l[(6 * 32 + node) * 72 + f] = __float2half(0.5f * (P[2] + P[6]) * inv);
        u2l[(7 * 32 + node) * 72 + f] = __float2half((P[4] - lam) * inv);
        u2l[(8 * 32 + node) * 72 + f] = __float2half(0.5f * (P[5] + P[7]) * inv);
    }
    __syncthreads();

    // ---- phase 2: GEMM (18 combos)
    int w = tid >> 6, lane = tid & 63;
    int l15 = lane & 15, lg = lane >> 4;
    const f32x4 z = {0.f, 0.f, 0.f, 0.f};
    f32x4 acc[5][4];
#pragma unroll
    for (int q = 0; q < 5; ++q) {
        int cm = w + q * 4;
        if (cm < 18) {
            int c = cm >> 1, rt = cm & 1;
            int gsel = (c == 0) ? 0 : (c < 4 ? 1 : 2);
            const f16x8* WFc = (const f16x8*)(Wfrag + gsel * WLFRAG);
            int abase = (c * 32 + rt * 16 + l15) * 72;
            f16x8 a0 = *(const f16x8*)&u2l[abase + lg * 8];
            f16x8 a1 = *(const f16x8*)&u2l[abase + 32 + lg * 8];
#pragma unroll
            for (int ct = 0; ct < 4; ++ct) {
                acc[q][ct] = __builtin_amdgcn_mfma_f32_16x16x32_f16(a0, WFc[(ct * 2 + 0) * 64 + lane], z, 0, 0, 0);
                acc[q][ct] = __builtin_amdgcn_mfma_f32_16x16x32_f16(a1, WFc[(ct * 2 + 1) * 64 + lane], acc[q][ct], 0, 0, 0);
            }
        }
    }
    __syncthreads();
#pragma unroll
    for (int q = 0; q < 5; ++q) {
        int cm = w + q * 4;
        if (cm < 18) {
            int c = cm >> 1, rt = cm & 1;
#pragma unroll
            for (int ct = 0; ct < 4; ++ct)
#pragma unroll
                for (int r = 0; r < 4; ++r)
                    u2l[(c * 32 + rt * 16 + lg * 4 + r) * 72 + ct * 16 + l15] =
                        __float2half(acc[q][ct][r]);
        }
    }
    __syncthreads();

    // ---- phase 3: out = Xn + dX + sc*dX@dX
    for (int e = 0; e < 8; ++e) {
        int idx = e * 256 + tid;
        int node = idx >> 6;
        int n = n0 + node;
        if (n >= N) continue;
        int f = idx & 63;
        float v[9];
#pragma unroll
        for (int c = 0; c < 9; ++c)
            v[c] = __half2float(u2l[(c * 32 + node) * 72 + f]);
        float dX[9];
        recon(v, dX);
        const float* xp = X + (size_t)n * 576 + f * 9;
        float m[9]; float n2 = 0.f;
#pragma unroll
        for (int i = 0; i < 9; ++i) { m[i] = xp[i]; n2 += m[i] * m[i]; }
        float invn = 1.0f / (n2 + 1.0f);
#pragma unroll
        for (int i = 0; i < 9; ++i) m[i] *= invn;
        float sc = s_sc[node];
        float* op = out + (size_t)n * 576 + f * 9;
#pragma unroll
        for (int i = 0; i < 3; ++i)
#pragma unroll
            for (int j = 0; j < 3; ++j) {
                float s = 0.f;
#pragma unroll
                for (int k = 0; k < 3; ++k) s += dX[i * 3 + k] * dX[k * 3 + j];
                op[i * 3 + j] = m[i * 3 + j] + dX[i * 3 + j] + sc * s;
            }
    }
}

// ---------------------------------------------------------------------------
extern "C" void kernel_launch(void* const* d_in, const int* in_sizes, int n_in,
                              void* d_out, int out_size, void* d_ws, size_t ws_size,
                              hipStream_t stream)
{
    const float* X       = (const float*)d_in[0];
    const int*   pair    = (const int*)d_in[1];
    const float* dij     = (const float*)d_in[2];
    const float* radial  = (const float*)d_in[3];
    const float* charges = (const float*)d_in[4];
    const float* W1  = (const float*)d_in[5];
    const float* b1  = (const float*)d_in[6];
    const float* W2  = (const float*)d_in[7];
    const float* b2  = (const float*)d_in[8];
    const float* W3  = (const float*)d_in[9];
    const float* b3  = (const float*)d_in[10];
    const float* Wl0 = (const float*)d_in[11];
    const float* Wl1 = (const float*)d_in[12];
    const float* Wl2 = (const float*)d_in[13];
    const float* Wl3 = (const float*)d_in[14];
    const float* Wl4 = (const float*)d_in[15];
    const float* Wl5 = (const float*)d_in[16];

    int N = in_sizes[4];
    int E = in_sizes[2];
    int nb_edge = (E + 63) / 64;
    int nb_node32 = (N + 31) / 32;
    size_t slab = (size_t)N * 64;

    __half2* msgP = (__half2*)d_ws;            // 5 slabs half2 (fp16 pairs)
    __half2* TgP  = msgP + 5 * slab;           // 3 slabs half2
    uint2* Tg456  = (uint2*)(TgP + 3 * slab);  // 1 slab uint2
    __half* Wf    = (__half*)(Tg456 + slab);   // 59392 halfs
    uint4* esd    = (uint4*)(Wf + MLPFRAGS + 6 * WLFRAG);
    int* ints   = (int*)(esd + E);
    int* count  = ints;
    int* off    = count + N;
    int* cursor = off + N + 1;

    hipMemsetAsync(count, 0, (size_t)N * sizeof(int), stream);
    hipMemsetAsync(msgP, 0, 5 * slab * sizeof(__half2), stream);

    int nWf = MLPFRAGS + 6 * WLFRAG;
    k_wcvt<<<(nWf + 255) / 256, 256, 0, stream>>>(W1, W2, W3,
                                                  Wl0, Wl1, Wl2, Wl3, Wl4, Wl5, Wf);
    k_head<<<nb_node32, 256, 0, stream>>>(X, Wf + MLPFRAGS, TgP, Tg456, N);

    k_hist<<<(E + 255) / 256, 256, 0, stream>>>(pair, count, E);
    k_scan<<<1, 1024, 0, stream>>>(count, off, cursor, N, E);
    k_scatter_sort<<<(E + 255) / 256, 256, 0, stream>>>(pair, dij, cursor, esd, E);

    k_edge_sorted<<<nb_edge, 256, 0, stream>>>(radial, esd,
                                               Wf, b1, b2, b3, TgP, Tg456,
                                               msgP, E, N);

    k_tail<<<nb_node32, 256, 0, stream>>>(msgP, TgP, Tg456, X, charges,
                                          Wf + MLPFRAGS + 3 * WLFRAG,
                                          (float*)d_out, N);
}